// Round 2
// baseline (1060.451 us; speedup 1.0000x reference)
//
#include <hip/hip_runtime.h>

typedef unsigned short ushort_t;
typedef unsigned int uint_t;

typedef __attribute__((ext_vector_type(8))) short bf16x8;
typedef __attribute__((ext_vector_type(4))) float f32x4;

#define GLOAD16(g, l) __builtin_amdgcn_global_load_lds( \
    (const __attribute__((address_space(1))) unsigned int*)(g), \
    (__attribute__((address_space(3))) unsigned int*)(l), 16, 0, 0)

__device__ __forceinline__ ushort_t f2bf(float f) {
  union { float f; uint_t u; } c; c.f = f;
  uint_t u = c.u;
  return (ushort_t)((u + 0x7FFFu + ((u >> 16) & 1u)) >> 16);
}

// ---------------- prep: x -> bf16, colsum, sumsq ----------------
__global__ __launch_bounds__(256) void prep_x(const float* __restrict__ x,
                                              ushort_t* __restrict__ xbf,
                                              float* __restrict__ colsum,
                                              double* __restrict__ accs) {
  const int tid = threadIdx.x;
  const int r0 = blockIdx.x * 32;
  float cs0 = 0.f, cs1 = 0.f, cs2 = 0.f;
  double ss = 0.0;
  for (int r = 0; r < 32; ++r) {
    const float* xr = x + (size_t)(r0 + r) * 768;
    ushort_t* xo = xbf + (size_t)(r0 + r) * 768;
    float v0 = xr[tid], v1 = xr[tid + 256], v2 = xr[tid + 512];
    xo[tid] = f2bf(v0); xo[tid + 256] = f2bf(v1); xo[tid + 512] = f2bf(v2);
    cs0 += v0; cs1 += v1; cs2 += v2;
    ss += (double)v0 * v0 + (double)v1 * v1 + (double)v2 * v2;
  }
  atomicAdd(&colsum[tid], cs0);
  atomicAdd(&colsum[tid + 256], cs1);
  atomicAdd(&colsum[tid + 512], cs2);
  for (int o = 32; o > 0; o >>= 1) ss += __shfl_down(ss, o);
  __shared__ double wsum[4];
  if ((tid & 63) == 0) wsum[tid >> 6] = ss;
  __syncthreads();
  if (tid == 0) atomicAdd(&accs[5], wsum[0] + wsum[1] + wsum[2] + wsum[3]);
}

// ---------------- generic f32 -> bf16 convert ----------------
__global__ __launch_bounds__(256) void conv_bf16(const float* __restrict__ in,
                                                 ushort_t* __restrict__ out, int n) {
  int i = (blockIdx.x * 256 + threadIdx.x) * 4;
  if (i + 3 < n) {
    float4 v = *(const float4*)(in + i);
    uint_t a = (uint_t)f2bf(v.x) | ((uint_t)f2bf(v.y) << 16);
    uint_t b = (uint_t)f2bf(v.z) | ((uint_t)f2bf(v.w) << 16);
    *(uint2*)(out + i) = make_uint2(a, b);
  }
}

// ---------------- W_skip transpose -> bf16 [D][K] ----------------
__global__ __launch_bounds__(256) void conv_skipT(const float* __restrict__ in,
                                                  ushort_t* __restrict__ out) {
  int d = blockIdx.x * 256 + threadIdx.x;   // 0..767
  int k = blockIdx.y;                        // 0..767
  if (d < 768) out[(size_t)d * 768 + k] = f2bf(in[(size_t)k * 768 + d]);
}

// ---------------- bf16 GEMM: C[M,N] = A[M,K] * B[N,K]^T + bias ----------------
// m97-style: 128x128 tile, BK=32, 4 waves 2x2, global_load_lds staging.
template <bool BF16_OUT>
__global__ __launch_bounds__(256) void gemm_bt(const ushort_t* __restrict__ Ag,
                                               const ushort_t* __restrict__ Bg,
                                               void* __restrict__ Cg,
                                               const float* __restrict__ bias,
                                               int K, int ldc) {
  __shared__ __align__(16) char smem[34816];
  const int tid = threadIdx.x;
  const int lane = tid & 63, wid = tid >> 6;
  const int wr = wid >> 1, wc = wid & 1;
  const int lo = lane & 15, hi = lane >> 4;
  const int arow0 = blockIdx.y * 128, brow0 = blockIdx.x * 128;

  const int rr0 = (lane >> 2);
  const int kb = (lane & 3) * 8;

  f32x4 acc[4][4] = {};
  const int NT = K >> 5;

  // initial stage into buffer 0 (A at 0, B at 16384)
  for (int c = 0; c < 2; ++c) {
    int rr = (wid * 2 + c) * 16 + rr0;
    GLOAD16(Ag + (size_t)(arow0 + rr) * K + kb, smem + (wid * 2 + c) * 1024);
    GLOAD16(Bg + (size_t)(brow0 + rr) * K + kb, smem + 16384 + (wid * 2 + c) * 1024);
  }
  __syncthreads();

  for (int kt = 0; kt < NT; ++kt) {
    const int cur = (kt & 1) * 8192;
    const int nxt = 8192 - cur;
    if (kt + 1 < NT) {
      const int k0 = (kt + 1) << 5;
      for (int c = 0; c < 2; ++c) {
        int rr = (wid * 2 + c) * 16 + rr0;
        GLOAD16(Ag + (size_t)(arow0 + rr) * K + k0 + kb, smem + nxt + (wid * 2 + c) * 1024);
        GLOAD16(Bg + (size_t)(brow0 + rr) * K + k0 + kb, smem + 16384 + nxt + (wid * 2 + c) * 1024);
      }
    }
    const char* As = smem + cur;
    const char* Bs = smem + 16384 + cur;
    bf16x8 af[4], bfr[4];
#pragma unroll
    for (int m = 0; m < 4; ++m)
      af[m] = *(const bf16x8*)(As + ((wr * 64 + m * 16 + lo) * 64 + hi * 16));
#pragma unroll
    for (int n = 0; n < 4; ++n)
      bfr[n] = *(const bf16x8*)(Bs + ((wc * 64 + n * 16 + lo) * 64 + hi * 16));
#pragma unroll
    for (int m = 0; m < 4; ++m)
#pragma unroll
      for (int n = 0; n < 4; ++n)
        acc[m][n] = __builtin_amdgcn_mfma_f32_16x16x32_bf16(af[m], bfr[n], acc[m][n], 0, 0, 0);
    __syncthreads();
  }

  if (BF16_OUT) {
    // repack to LDS (row stride 136 ushorts = 272B), then coalesced copy-out
    ushort_t* ot = (ushort_t*)smem;
#pragma unroll
    for (int n = 0; n < 4; ++n) {
      const int col = wc * 64 + n * 16 + lo;
      const float bv = bias[brow0 + col];
#pragma unroll
      for (int m = 0; m < 4; ++m) {
#pragma unroll
        for (int r = 0; r < 4; ++r) {
          const int row = wr * 64 + m * 16 + hi * 4 + r;
          ot[row * 136 + col] = f2bf(acc[m][n][r] + bv);
        }
      }
    }
    __syncthreads();
    ushort_t* C = (ushort_t*)Cg;
    const int cc = tid & 15;
#pragma unroll
    for (int p = 0; p < 8; ++p) {
      const int row = p * 16 + (tid >> 4);
      ushort_t* dst = C + (size_t)(arow0 + row) * (size_t)ldc + brow0 + cc * 8;
      *(uint4*)dst = *(const uint4*)(ot + row * 136 + cc * 8);
    }
  } else {
    float* C = (float*)Cg;
#pragma unroll
    for (int n = 0; n < 4; ++n) {
      const int col = wc * 64 + n * 16 + lo;
      const float bv = bias[brow0 + col];
#pragma unroll
      for (int m = 0; m < 4; ++m) {
#pragma unroll
        for (int r = 0; r < 4; ++r) {
          const int row = wr * 64 + m * 16 + hi * 4 + r;
          C[(size_t)(arow0 + row) * (size_t)ldc + brow0 + col] = acc[m][n][r] + bv;
        }
      }
    }
  }
}

// ---------------- top-k per row (exact stable top-128 / top-32 on bf16 pre) ----------------
__global__ __launch_bounds__(256) void topk_kernel(const ushort_t* __restrict__ pre,
                                                   int* __restrict__ oidx,
                                                   float* __restrict__ oval,
                                                   double* __restrict__ accs) {
  __shared__ ushort_t rowk[12288];
  __shared__ uint_t hist[4096];
  __shared__ uint_t cand[1024];
  __shared__ uint_t csum[256];
  __shared__ uint_t sh[4];
  __shared__ float vtmp[128];
  const int tid = threadIdx.x;
  const size_t row = blockIdx.x;
  const ushort_t* pr = pre + row * 12288;

  // load + monotone key transform (bf16 -> ordered u16)
  for (int i = tid; i < 6144; i += 256) {
    uint_t u2 = ((const uint_t*)pr)[i];
    uint_t lo16 = u2 & 0xFFFFu, hi16 = u2 >> 16;
    uint_t klo = (lo16 & 0x8000u) ? (~lo16 & 0xFFFFu) : (lo16 | 0x8000u);
    uint_t khi = (hi16 & 0x8000u) ? (~hi16 & 0xFFFFu) : (hi16 | 0x8000u);
    ((uint_t*)rowk)[i] = klo | (khi << 16);
  }
  for (int i = tid; i < 4096; i += 256) hist[i] = 0;
  if (tid == 0) sh[2] = 0;
  __syncthreads();
  for (int i = tid; i < 12288; i += 256) atomicAdd(&hist[rowk[i] >> 4], 1u);
  __syncthreads();
  // per-thread chunk (16 bins) sums
  uint_t cs = 0;
  for (int b = 0; b < 16; ++b) cs += hist[tid * 16 + b];
  csum[tid] = cs;
  __syncthreads();
  // Kogge-Stone suffix sums
  for (int d = 1; d < 256; d <<= 1) {
    uint_t v = (tid + d < 256) ? csum[tid + d] : 0u;
    __syncthreads();
    csum[tid] += v;
    __syncthreads();
  }
  {
    uint_t me = csum[tid];
    uint_t nxt = (tid < 255) ? csum[tid + 1] : 0u;
    if (me >= 128u && nxt < 128u) sh[0] = (uint_t)tid;
  }
  __syncthreads();
  if (tid == 0) {
    int tc = (int)sh[0];
    uint_t running = (tc < 255) ? csum[tc + 1] : 0u;
    int b = tc * 16 + 15;
    for (; b >= tc * 16; --b) {
      running += hist[b];
      if (running >= 128u) break;
    }
    sh[0] = (uint_t)b;
    sh[1] = running;
  }
  __syncthreads();
  const uint_t tbin = sh[0];
  const int n_cand = (int)min(sh[1], 1024u);
  // collect candidates: key in high bits (inverted for val-desc), idx low
  for (int i = tid; i < 12288; i += 256) {
    uint_t k = rowk[i];
    if ((k >> 4) >= tbin) {
      uint_t pos = atomicAdd(&sh[2], 1u);
      if (pos < 1024u) cand[pos] = ((0xFFFFu - k) << 16) | (uint_t)i;
    }
  }
  __syncthreads();
  int n_sort = 128;
  while (n_sort < n_cand) n_sort <<= 1;
  for (int i = n_cand + tid; i < n_sort; i += 256) cand[i] = 0xFFFFFFFFu;
  __syncthreads();
  // bitonic sort ascending (=> val desc, idx asc)
  for (int k = 2; k <= n_sort; k <<= 1) {
    for (int j = k >> 1; j > 0; j >>= 1) {
      for (int i = tid; i < n_sort; i += 256) {
        int p = i ^ j;
        if (p > i) {
          uint_t a = cand[i], b = cand[p];
          bool up = ((i & k) == 0);
          if (up ? (a > b) : (a < b)) { cand[i] = b; cand[p] = a; }
        }
      }
      __syncthreads();
    }
  }
  if (tid < 128) {
    uint_t Kv = cand[tid];
    uint_t idx = Kv & 0xFFFFu;
    uint_t key = 0xFFFFu - (Kv >> 16);
    uint_t ub = (key & 0x8000u) ? (key & 0x7FFFu) : (~key & 0xFFFFu);
    float v = __uint_as_float(ub << 16);
    v = fmaxf(v, 0.f);
    oidx[row * 128 + tid] = (int)idx;
    oval[row * 128 + tid] = v;
    vtmp[tid] = v;
  }
  __syncthreads();
  if (tid == 0) {
    float s1 = 0.f, s2 = 0.f;
    for (int i = 0; i < 32; ++i) s1 += vtmp[i];
    for (int i = 0; i < 128; ++i) s2 += vtmp[i];
    atomicAdd(&accs[0], (double)s1);
    atomicAdd(&accs[1], (double)s2);
  }
}

// ---------------- sparse decode + loss + means ----------------
__global__ __launch_bounds__(256) void decode_loss(const int* __restrict__ oidx,
                                                   const float* __restrict__ oval,
                                                   const float* __restrict__ skip,
                                                   const float* __restrict__ mlp,
                                                   const float* __restrict__ Wdec,
                                                   double* __restrict__ accs) {
  __shared__ int lidx[128];
  __shared__ float lval[128];
  __shared__ double wred[4][3];
  const int tid = threadIdx.x;
  const size_t row = blockIdx.x;
  if (tid < 128) {
    lidx[tid] = oidx[row * 128 + tid];
    lval[tid] = oval[row * 128 + tid];
  }
  __syncthreads();
  const float* sr = skip + row * 768;
  const float* mr = mlp + row * 768;
  float s0 = sr[tid], s1 = sr[tid + 256], s2 = sr[tid + 512];
  float m0 = mr[tid], m1 = mr[tid + 256], m2 = mr[tid + 512];
  float a0 = 0.f, a1 = 0.f, a2 = 0.f;
#pragma unroll 4
  for (int j = 0; j < 32; ++j) {
    float v = lval[j];
    const float* w = Wdec + (size_t)lidx[j] * 768;
    a0 = fmaf(v, w[tid], a0);
    a1 = fmaf(v, w[tid + 256], a1);
    a2 = fmaf(v, w[tid + 512], a2);
  }
  float d0 = a0 + s0, d1 = a1 + s1, d2 = a2 + s2;
  float e0 = m0 - d0, e1 = m1 - d1, e2 = m2 - d2;
  float l1 = e0 * e0 + e1 * e1 + e2 * e2;
  float dsum = d0 + d1 + d2;
#pragma unroll 4
  for (int j = 32; j < 128; ++j) {
    float v = lval[j];
    const float* w = Wdec + (size_t)lidx[j] * 768;
    a0 = fmaf(v, w[tid], a0);
    a1 = fmaf(v, w[tid + 256], a1);
    a2 = fmaf(v, w[tid + 512], a2);
  }
  d0 = a0 + s0; d1 = a1 + s1; d2 = a2 + s2;
  e0 = m0 - d0; e1 = m1 - d1; e2 = m2 - d2;
  float l2 = e0 * e0 + e1 * e1 + e2 * e2;
  dsum += d0 + d1 + d2;

  double r0 = (double)l1, r1 = (double)l2, r2 = (double)dsum;
  for (int o = 32; o > 0; o >>= 1) {
    r0 += __shfl_down(r0, o);
    r1 += __shfl_down(r1, o);
    r2 += __shfl_down(r2, o);
  }
  const int w = tid >> 6;
  if ((tid & 63) == 0) { wred[w][0] = r0; wred[w][1] = r1; wred[w][2] = r2; }
  __syncthreads();
  if (tid == 0) {
    double t0 = 0, t1 = 0, t2 = 0;
    for (int i = 0; i < 4; ++i) { t0 += wred[i][0]; t1 += wred[i][1]; t2 += wred[i][2]; }
    atomicAdd(&accs[3], t0);
    atomicAdd(&accs[4], t1);
    atomicAdd(&accs[2], t2);
  }
}

// ---------------- finalize ----------------
__global__ __launch_bounds__(256) void finalize_kernel(const double* __restrict__ accs,
                                                       const float* __restrict__ colsum,
                                                       float* __restrict__ out) {
  __shared__ double wred[4];
  const int tid = threadIdx.x;
  double c2 = 0.0;
  for (int i = tid; i < 768; i += 256) { double c = (double)colsum[i]; c2 += c * c; }
  for (int o = 32; o > 0; o >>= 1) c2 += __shfl_down(c2, o);
  if ((tid & 63) == 0) wred[tid >> 6] = c2;
  __syncthreads();
  if (tid == 0) {
    double csq = wred[0] + wred[1] + wred[2] + wred[3];
    double tv = accs[5] - csq / 8192.0;
    out[0] = (float)((accs[0] + accs[1]) / (8192.0 * 12288.0));
    out[1] = (float)(accs[2] / (8192.0 * 768.0));
    out[2] = (float)(accs[3] / tv + accs[4] / (8.0 * tv));
  }
}

extern "C" void kernel_launch(void* const* d_in, const int* in_sizes, int n_in,
                              void* d_out, int out_size, void* d_ws, size_t ws_size,
                              hipStream_t stream) {
  const float* x    = (const float*)d_in[0];
  const float* mlp  = (const float*)d_in[1];
  const float* Wenc = (const float*)d_in[2];
  const float* benc = (const float*)d_in[3];
  const float* Wdec = (const float*)d_in[4];
  const float* bdec = (const float*)d_in[5];
  const float* Wskip= (const float*)d_in[6];

  char* ws = (char*)d_ws;
  const size_t OFF_COL  = 1024;
  const size_t OFF_XBF  = 8192;
  const size_t OFF_WENC = OFF_XBF  + (size_t)8192 * 768 * 2;
  const size_t OFF_WSK  = OFF_WENC + (size_t)12288 * 768 * 2;
  const size_t OFF_SKIP = OFF_WSK  + (size_t)768 * 768 * 2;
  const size_t OFF_TIDX = OFF_SKIP + (size_t)8192 * 768 * 4;
  const size_t OFF_TVAL = OFF_TIDX + (size_t)8192 * 128 * 4;
  const size_t OFF_PRE  = OFF_TVAL + (size_t)8192 * 128 * 4;

  double*   accs   = (double*)ws;
  float*    colsum = (float*)(ws + OFF_COL);
  ushort_t* xbf    = (ushort_t*)(ws + OFF_XBF);
  ushort_t* wencbf = (ushort_t*)(ws + OFF_WENC);
  ushort_t* wskT   = (ushort_t*)(ws + OFF_WSK);
  float*    skip   = (float*)(ws + OFF_SKIP);
  int*      tidx   = (int*)(ws + OFF_TIDX);
  float*    tval   = (float*)(ws + OFF_TVAL);
  ushort_t* pre    = (ushort_t*)(ws + OFF_PRE);

  (void)hipMemsetAsync(d_ws, 0, 8192, stream);

  prep_x<<<256, 256, 0, stream>>>(x, xbf, colsum, accs);
  conv_bf16<<<(12288 * 768 / 4) / 256, 256, 0, stream>>>(Wenc, wencbf, 12288 * 768);
  conv_skipT<<<dim3(3, 768), 256, 0, stream>>>(Wskip, wskT);

  gemm_bt<true><<<dim3(96, 64), 256, 0, stream>>>(xbf, wencbf, (void*)pre, benc, 768, 12288);
  gemm_bt<false><<<dim3(6, 64), 256, 0, stream>>>(xbf, wskT, (void*)skip, bdec, 768, 768);

  topk_kernel<<<8192, 256, 0, stream>>>(pre, tidx, tval, accs);
  decode_loss<<<8192, 256, 0, stream>>>(tidx, tval, skip, mlp, Wdec, accs);
  finalize_kernel<<<1, 256, 0, stream>>>(accs, colsum, (float*)d_out);
}

// Round 3
// 931.154 us; speedup vs baseline: 1.1389x; 1.1389x over previous
//
#include <hip/hip_runtime.h>

typedef unsigned short ushort_t;
typedef unsigned int uint_t;

typedef __attribute__((ext_vector_type(8))) short bf16x8;
typedef __attribute__((ext_vector_type(4))) float f32x4;

#define GLOAD16(g, l) __builtin_amdgcn_global_load_lds( \
    (const __attribute__((address_space(1))) unsigned int*)(g), \
    (__attribute__((address_space(3))) unsigned int*)(l), 16, 0, 0)

__device__ __forceinline__ ushort_t f2bf(float f) {
  union { float f; uint_t u; } c; c.f = f;
  uint_t u = c.u;
  return (ushort_t)((u + 0x7FFFu + ((u >> 16) & 1u)) >> 16);
}

__device__ __forceinline__ float bf2f(ushort_t b) {
  union { uint_t u; float f; } c; c.u = ((uint_t)b) << 16;
  return c.f;
}

// ---------------- prep: x -> bf16, colsum, sumsq ----------------
__global__ __launch_bounds__(256) void prep_x(const float* __restrict__ x,
                                              ushort_t* __restrict__ xbf,
                                              float* __restrict__ colsum,
                                              double* __restrict__ accs) {
  const int tid = threadIdx.x;
  const int r0 = blockIdx.x * 32;
  float cs0 = 0.f, cs1 = 0.f, cs2 = 0.f;
  double ss = 0.0;
  for (int r = 0; r < 32; ++r) {
    const float* xr = x + (size_t)(r0 + r) * 768;
    ushort_t* xo = xbf + (size_t)(r0 + r) * 768;
    float v0 = xr[tid], v1 = xr[tid + 256], v2 = xr[tid + 512];
    xo[tid] = f2bf(v0); xo[tid + 256] = f2bf(v1); xo[tid + 512] = f2bf(v2);
    cs0 += v0; cs1 += v1; cs2 += v2;
    ss += (double)v0 * v0 + (double)v1 * v1 + (double)v2 * v2;
  }
  atomicAdd(&colsum[tid], cs0);
  atomicAdd(&colsum[tid + 256], cs1);
  atomicAdd(&colsum[tid + 512], cs2);
  for (int o = 32; o > 0; o >>= 1) ss += __shfl_down(ss, o);
  __shared__ double wsum[4];
  if ((tid & 63) == 0) wsum[tid >> 6] = ss;
  __syncthreads();
  if (tid == 0) atomicAdd(&accs[5], wsum[0] + wsum[1] + wsum[2] + wsum[3]);
}

// ---------------- generic f32 -> bf16 convert ----------------
__global__ __launch_bounds__(256) void conv_bf16(const float* __restrict__ in,
                                                 ushort_t* __restrict__ out, int n) {
  int i = (blockIdx.x * 256 + threadIdx.x) * 4;
  if (i + 3 < n) {
    float4 v = *(const float4*)(in + i);
    uint_t a = (uint_t)f2bf(v.x) | ((uint_t)f2bf(v.y) << 16);
    uint_t b = (uint_t)f2bf(v.z) | ((uint_t)f2bf(v.w) << 16);
    *(uint2*)(out + i) = make_uint2(a, b);
  }
}

// ---------------- W_skip transpose -> bf16 [D][K] ----------------
__global__ __launch_bounds__(256) void conv_skipT(const float* __restrict__ in,
                                                  ushort_t* __restrict__ out) {
  int d = blockIdx.x * 256 + threadIdx.x;   // 0..767
  int k = blockIdx.y;                        // 0..767
  if (d < 768) out[(size_t)d * 768 + k] = f2bf(in[(size_t)k * 768 + d]);
}

// ---------------- bf16 GEMM: C[M,N] = A[M,K] * B[N,K]^T + bias ----------------
// m97-style: 128x128 tile, BK=32, 4 waves 2x2, global_load_lds staging.
template <bool BF16_OUT>
__global__ __launch_bounds__(256) void gemm_bt(const ushort_t* __restrict__ Ag,
                                               const ushort_t* __restrict__ Bg,
                                               void* __restrict__ Cg,
                                               const float* __restrict__ bias,
                                               int K, int ldc) {
  __shared__ __align__(16) char smem[34816];
  const int tid = threadIdx.x;
  const int lane = tid & 63, wid = tid >> 6;
  const int wr = wid >> 1, wc = wid & 1;
  const int lo = lane & 15, hi = lane >> 4;
  const int arow0 = blockIdx.y * 128, brow0 = blockIdx.x * 128;

  const int rr0 = (lane >> 2);
  const int kb = (lane & 3) * 8;

  f32x4 acc[4][4] = {};
  const int NT = K >> 5;

  // initial stage into buffer 0 (A at 0, B at 16384)
  for (int c = 0; c < 2; ++c) {
    int rr = (wid * 2 + c) * 16 + rr0;
    GLOAD16(Ag + (size_t)(arow0 + rr) * K + kb, smem + (wid * 2 + c) * 1024);
    GLOAD16(Bg + (size_t)(brow0 + rr) * K + kb, smem + 16384 + (wid * 2 + c) * 1024);
  }
  __syncthreads();

  for (int kt = 0; kt < NT; ++kt) {
    const int cur = (kt & 1) * 8192;
    const int nxt = 8192 - cur;
    if (kt + 1 < NT) {
      const int k0 = (kt + 1) << 5;
      for (int c = 0; c < 2; ++c) {
        int rr = (wid * 2 + c) * 16 + rr0;
        GLOAD16(Ag + (size_t)(arow0 + rr) * K + k0 + kb, smem + nxt + (wid * 2 + c) * 1024);
        GLOAD16(Bg + (size_t)(brow0 + rr) * K + k0 + kb, smem + 16384 + nxt + (wid * 2 + c) * 1024);
      }
    }
    const char* As = smem + cur;
    const char* Bs = smem + 16384 + cur;
    bf16x8 af[4], bfr[4];
#pragma unroll
    for (int m = 0; m < 4; ++m)
      af[m] = *(const bf16x8*)(As + ((wr * 64 + m * 16 + lo) * 64 + hi * 16));
#pragma unroll
    for (int n = 0; n < 4; ++n)
      bfr[n] = *(const bf16x8*)(Bs + ((wc * 64 + n * 16 + lo) * 64 + hi * 16));
#pragma unroll
    for (int m = 0; m < 4; ++m)
#pragma unroll
      for (int n = 0; n < 4; ++n)
        acc[m][n] = __builtin_amdgcn_mfma_f32_16x16x32_bf16(af[m], bfr[n], acc[m][n], 0, 0, 0);
    __syncthreads();
  }

  if (BF16_OUT) {
    // repack to LDS (row stride 136 ushorts = 272B), then coalesced copy-out
    ushort_t* ot = (ushort_t*)smem;
#pragma unroll
    for (int n = 0; n < 4; ++n) {
      const int col = wc * 64 + n * 16 + lo;
      const float bv = bias[brow0 + col];
#pragma unroll
      for (int m = 0; m < 4; ++m) {
#pragma unroll
        for (int r = 0; r < 4; ++r) {
          const int row = wr * 64 + m * 16 + hi * 4 + r;
          ot[row * 136 + col] = f2bf(acc[m][n][r] + bv);
        }
      }
    }
    __syncthreads();
    ushort_t* C = (ushort_t*)Cg;
    const int cc = tid & 15;
#pragma unroll
    for (int p = 0; p < 8; ++p) {
      const int row = p * 16 + (tid >> 4);
      ushort_t* dst = C + (size_t)(arow0 + row) * (size_t)ldc + brow0 + cc * 8;
      *(uint4*)dst = *(const uint4*)(ot + row * 136 + cc * 8);
    }
  } else {
    float* C = (float*)Cg;
#pragma unroll
    for (int n = 0; n < 4; ++n) {
      const int col = wc * 64 + n * 16 + lo;
      const float bv = bias[brow0 + col];
#pragma unroll
      for (int m = 0; m < 4; ++m) {
#pragma unroll
        for (int r = 0; r < 4; ++r) {
          const int row = wr * 64 + m * 16 + hi * 4 + r;
          C[(size_t)(arow0 + row) * (size_t)ldc + brow0 + col] = acc[m][n][r] + bv;
        }
      }
    }
  }
}

// ---------------- top-k per row (exact stable top-128 / top-32 on bf16 pre) ----------------
__global__ __launch_bounds__(256) void topk_kernel(const ushort_t* __restrict__ pre,
                                                   int* __restrict__ oidx,
                                                   float* __restrict__ oval,
                                                   double* __restrict__ accs) {
  __shared__ ushort_t rowk[12288];
  __shared__ uint_t hist[4096];
  __shared__ uint_t cand[1024];
  __shared__ uint_t csum[256];
  __shared__ uint_t sh[4];
  __shared__ float vtmp[128];
  const int tid = threadIdx.x;
  const size_t row = blockIdx.x;
  const ushort_t* pr = pre + row * 12288;

  // load + monotone key transform (bf16 -> ordered u16)
  for (int i = tid; i < 6144; i += 256) {
    uint_t u2 = ((const uint_t*)pr)[i];
    uint_t lo16 = u2 & 0xFFFFu, hi16 = u2 >> 16;
    uint_t klo = (lo16 & 0x8000u) ? (~lo16 & 0xFFFFu) : (lo16 | 0x8000u);
    uint_t khi = (hi16 & 0x8000u) ? (~hi16 & 0xFFFFu) : (hi16 | 0x8000u);
    ((uint_t*)rowk)[i] = klo | (khi << 16);
  }
  for (int i = tid; i < 4096; i += 256) hist[i] = 0;
  if (tid == 0) sh[2] = 0;
  __syncthreads();
  for (int i = tid; i < 12288; i += 256) atomicAdd(&hist[rowk[i] >> 4], 1u);
  __syncthreads();
  // per-thread chunk (16 bins) sums
  uint_t cs = 0;
  for (int b = 0; b < 16; ++b) cs += hist[tid * 16 + b];
  csum[tid] = cs;
  __syncthreads();
  // Kogge-Stone suffix sums
  for (int d = 1; d < 256; d <<= 1) {
    uint_t v = (tid + d < 256) ? csum[tid + d] : 0u;
    __syncthreads();
    csum[tid] += v;
    __syncthreads();
  }
  {
    uint_t me = csum[tid];
    uint_t nxt = (tid < 255) ? csum[tid + 1] : 0u;
    if (me >= 128u && nxt < 128u) sh[0] = (uint_t)tid;
  }
  __syncthreads();
  if (tid == 0) {
    int tc = (int)sh[0];
    uint_t running = (tc < 255) ? csum[tc + 1] : 0u;
    int b = tc * 16 + 15;
    for (; b >= tc * 16; --b) {
      running += hist[b];
      if (running >= 128u) break;
    }
    sh[0] = (uint_t)b;
    sh[1] = running;
  }
  __syncthreads();
  const uint_t tbin = sh[0];
  const int n_cand = (int)min(sh[1], 1024u);
  // collect candidates: key in high bits (inverted for val-desc), idx low
  for (int i = tid; i < 12288; i += 256) {
    uint_t k = rowk[i];
    if ((k >> 4) >= tbin) {
      uint_t pos = atomicAdd(&sh[2], 1u);
      if (pos < 1024u) cand[pos] = ((0xFFFFu - k) << 16) | (uint_t)i;
    }
  }
  __syncthreads();
  int n_sort = 128;
  while (n_sort < n_cand) n_sort <<= 1;
  for (int i = n_cand + tid; i < n_sort; i += 256) cand[i] = 0xFFFFFFFFu;
  __syncthreads();
  // bitonic sort ascending (=> val desc, idx asc)
  for (int k = 2; k <= n_sort; k <<= 1) {
    for (int j = k >> 1; j > 0; j >>= 1) {
      for (int i = tid; i < n_sort; i += 256) {
        int p = i ^ j;
        if (p > i) {
          uint_t a = cand[i], b = cand[p];
          bool up = ((i & k) == 0);
          if (up ? (a > b) : (a < b)) { cand[i] = b; cand[p] = a; }
        }
      }
      __syncthreads();
    }
  }
  if (tid < 128) {
    uint_t Kv = cand[tid];
    uint_t idx = Kv & 0xFFFFu;
    uint_t key = 0xFFFFu - (Kv >> 16);
    uint_t ub = (key & 0x8000u) ? (key & 0x7FFFu) : (~key & 0xFFFFu);
    float v = __uint_as_float(ub << 16);
    v = fmaxf(v, 0.f);
    oidx[row * 128 + tid] = (int)idx;
    oval[row * 128 + tid] = v;
    vtmp[tid] = v;
  }
  __syncthreads();
  if (tid == 0) {
    float s1 = 0.f, s2 = 0.f;
    for (int i = 0; i < 32; ++i) s1 += vtmp[i];
    for (int i = 0; i < 128; ++i) s2 += vtmp[i];
    atomicAdd(&accs[0], (double)s1);
    atomicAdd(&accs[1], (double)s2);
  }
}

// ---------------- sparse decode + loss + means (bf16 W_dec) ----------------
__global__ __launch_bounds__(256) void decode_loss(const int* __restrict__ oidx,
                                                   const float* __restrict__ oval,
                                                   const float* __restrict__ skip,
                                                   const float* __restrict__ mlp,
                                                   const ushort_t* __restrict__ Wdec,
                                                   double* __restrict__ accs) {
  __shared__ int lidx[128];
  __shared__ float lval[128];
  __shared__ double wred[4][3];
  const int tid = threadIdx.x;
  const size_t row = blockIdx.x;
  if (tid < 128) {
    lidx[tid] = oidx[row * 128 + tid];
    lval[tid] = oval[row * 128 + tid];
  }
  __syncthreads();
  const float* sr = skip + row * 768;
  const float* mr = mlp + row * 768;
  float s0 = sr[tid], s1 = sr[tid + 256], s2 = sr[tid + 512];
  float m0 = mr[tid], m1 = mr[tid + 256], m2 = mr[tid + 512];
  float a0 = 0.f, a1 = 0.f, a2 = 0.f;
#pragma unroll 8
  for (int j = 0; j < 32; ++j) {
    float v = lval[j];
    const ushort_t* w = Wdec + (size_t)lidx[j] * 768;
    a0 = fmaf(v, bf2f(w[tid]), a0);
    a1 = fmaf(v, bf2f(w[tid + 256]), a1);
    a2 = fmaf(v, bf2f(w[tid + 512]), a2);
  }
  float d0 = a0 + s0, d1 = a1 + s1, d2 = a2 + s2;
  float e0 = m0 - d0, e1 = m1 - d1, e2 = m2 - d2;
  float l1 = e0 * e0 + e1 * e1 + e2 * e2;
  float dsum = d0 + d1 + d2;
#pragma unroll 8
  for (int j = 32; j < 128; ++j) {
    float v = lval[j];
    const ushort_t* w = Wdec + (size_t)lidx[j] * 768;
    a0 = fmaf(v, bf2f(w[tid]), a0);
    a1 = fmaf(v, bf2f(w[tid + 256]), a1);
    a2 = fmaf(v, bf2f(w[tid + 512]), a2);
  }
  d0 = a0 + s0; d1 = a1 + s1; d2 = a2 + s2;
  e0 = m0 - d0; e1 = m1 - d1; e2 = m2 - d2;
  float l2 = e0 * e0 + e1 * e1 + e2 * e2;
  dsum += d0 + d1 + d2;

  double r0 = (double)l1, r1 = (double)l2, r2 = (double)dsum;
  for (int o = 32; o > 0; o >>= 1) {
    r0 += __shfl_down(r0, o);
    r1 += __shfl_down(r1, o);
    r2 += __shfl_down(r2, o);
  }
  const int w = tid >> 6;
  if ((tid & 63) == 0) { wred[w][0] = r0; wred[w][1] = r1; wred[w][2] = r2; }
  __syncthreads();
  if (tid == 0) {
    double t0 = 0, t1 = 0, t2 = 0;
    for (int i = 0; i < 4; ++i) { t0 += wred[i][0]; t1 += wred[i][1]; t2 += wred[i][2]; }
    atomicAdd(&accs[3], t0);
    atomicAdd(&accs[4], t1);
    atomicAdd(&accs[2], t2);
  }
}

// ---------------- finalize ----------------
__global__ __launch_bounds__(256) void finalize_kernel(const double* __restrict__ accs,
                                                       const float* __restrict__ colsum,
                                                       float* __restrict__ out) {
  __shared__ double wred[4];
  const int tid = threadIdx.x;
  double c2 = 0.0;
  for (int i = tid; i < 768; i += 256) { double c = (double)colsum[i]; c2 += c * c; }
  for (int o = 32; o > 0; o >>= 1) c2 += __shfl_down(c2, o);
  if ((tid & 63) == 0) wred[tid >> 6] = c2;
  __syncthreads();
  if (tid == 0) {
    double csq = wred[0] + wred[1] + wred[2] + wred[3];
    double tv = accs[5] - csq / 8192.0;
    out[0] = (float)((accs[0] + accs[1]) / (8192.0 * 12288.0));
    out[1] = (float)(accs[2] / (8192.0 * 768.0));
    out[2] = (float)(accs[3] / tv + accs[4] / (8.0 * tv));
  }
}

extern "C" void kernel_launch(void* const* d_in, const int* in_sizes, int n_in,
                              void* d_out, int out_size, void* d_ws, size_t ws_size,
                              hipStream_t stream) {
  const float* x    = (const float*)d_in[0];
  const float* mlp  = (const float*)d_in[1];
  const float* Wenc = (const float*)d_in[2];
  const float* benc = (const float*)d_in[3];
  const float* Wdec = (const float*)d_in[4];
  const float* bdec = (const float*)d_in[5];
  const float* Wskip= (const float*)d_in[6];

  char* ws = (char*)d_ws;
  const size_t OFF_COL  = 1024;
  const size_t OFF_XBF  = 8192;
  const size_t OFF_WENC = OFF_XBF  + (size_t)8192 * 768 * 2;
  const size_t OFF_WSK  = OFF_WENC + (size_t)12288 * 768 * 2;
  const size_t OFF_SKIP = OFF_WSK  + (size_t)768 * 768 * 2;
  const size_t OFF_TIDX = OFF_SKIP + (size_t)8192 * 768 * 4;
  const size_t OFF_TVAL = OFF_TIDX + (size_t)8192 * 128 * 4;
  const size_t OFF_PRE  = OFF_TVAL + (size_t)8192 * 128 * 4;

  double*   accs   = (double*)ws;
  float*    colsum = (float*)(ws + OFF_COL);
  ushort_t* xbf    = (ushort_t*)(ws + OFF_XBF);
  ushort_t* wencbf = (ushort_t*)(ws + OFF_WENC);  // reused for bf16 W_dec after enc GEMM
  ushort_t* wskT   = (ushort_t*)(ws + OFF_WSK);
  float*    skip   = (float*)(ws + OFF_SKIP);
  int*      tidx   = (int*)(ws + OFF_TIDX);
  float*    tval   = (float*)(ws + OFF_TVAL);
  ushort_t* pre    = (ushort_t*)(ws + OFF_PRE);

  (void)hipMemsetAsync(d_ws, 0, 8192, stream);

  prep_x<<<256, 256, 0, stream>>>(x, xbf, colsum, accs);
  conv_bf16<<<(12288 * 768 / 4) / 256, 256, 0, stream>>>(Wenc, wencbf, 12288 * 768);
  conv_skipT<<<dim3(3, 768), 256, 0, stream>>>(Wskip, wskT);

  gemm_bt<true><<<dim3(96, 64), 256, 0, stream>>>(xbf, wencbf, (void*)pre, benc, 768, 12288);
  gemm_bt<false><<<dim3(6, 64), 256, 0, stream>>>(xbf, wskT, (void*)skip, bdec, 768, 768);

  // W_enc staging buffer is dead now -> reuse it for bf16 W_dec (stream-ordered)
  ushort_t* wdecbf = wencbf;
  conv_bf16<<<(12288 * 768 / 4) / 256, 256, 0, stream>>>(Wdec, wdecbf, 12288 * 768);

  topk_kernel<<<8192, 256, 0, stream>>>(pre, tidx, tval, accs);
  decode_loss<<<8192, 256, 0, stream>>>(tidx, tval, skip, mlp, wdecbf, accs);
  finalize_kernel<<<1, 256, 0, stream>>>(accs, colsum, (float*)d_out);
}

// Round 4
// 909.186 us; speedup vs baseline: 1.1664x; 1.0242x over previous
//
#include <hip/hip_runtime.h>

typedef unsigned short ushort_t;
typedef unsigned int uint_t;

typedef __attribute__((ext_vector_type(8))) short bf16x8;
typedef __attribute__((ext_vector_type(4))) float f32x4;
typedef __attribute__((ext_vector_type(2))) float f32x2;

#define GLOAD16(g, l) __builtin_amdgcn_global_load_lds( \
    (const __attribute__((address_space(1))) unsigned int*)(g), \
    (__attribute__((address_space(3))) unsigned int*)(l), 16, 0, 0)

__device__ __forceinline__ ushort_t f2bf(float f) {
  union { float f; uint_t u; } c; c.f = f;
  uint_t u = c.u;
  return (ushort_t)((u + 0x7FFFu + ((u >> 16) & 1u)) >> 16);
}

__device__ __forceinline__ float bf2f(ushort_t b) {
  union { uint_t u; float f; } c; c.u = ((uint_t)b) << 16;
  return c.f;
}

// ---------------- prep: x -> bf16, colsum, sumsq ----------------
__global__ __launch_bounds__(256) void prep_x(const float* __restrict__ x,
                                              ushort_t* __restrict__ xbf,
                                              float* __restrict__ colsum,
                                              double* __restrict__ accs) {
  const int tid = threadIdx.x;
  const int r0 = blockIdx.x * 32;
  float cs0 = 0.f, cs1 = 0.f, cs2 = 0.f;
  double ss = 0.0;
  for (int r = 0; r < 32; ++r) {
    const float* xr = x + (size_t)(r0 + r) * 768;
    ushort_t* xo = xbf + (size_t)(r0 + r) * 768;
    float v0 = xr[tid], v1 = xr[tid + 256], v2 = xr[tid + 512];
    xo[tid] = f2bf(v0); xo[tid + 256] = f2bf(v1); xo[tid + 512] = f2bf(v2);
    cs0 += v0; cs1 += v1; cs2 += v2;
    ss += (double)v0 * v0 + (double)v1 * v1 + (double)v2 * v2;
  }
  atomicAdd(&colsum[tid], cs0);
  atomicAdd(&colsum[tid + 256], cs1);
  atomicAdd(&colsum[tid + 512], cs2);
  for (int o = 32; o > 0; o >>= 1) ss += __shfl_down(ss, o);
  __shared__ double wsum[4];
  if ((tid & 63) == 0) wsum[tid >> 6] = ss;
  __syncthreads();
  if (tid == 0) atomicAdd(&accs[5], wsum[0] + wsum[1] + wsum[2] + wsum[3]);
}

// ---------------- generic f32 -> bf16 convert ----------------
__global__ __launch_bounds__(256) void conv_bf16(const float* __restrict__ in,
                                                 ushort_t* __restrict__ out, int n) {
  int i = (blockIdx.x * 256 + threadIdx.x) * 4;
  if (i + 3 < n) {
    float4 v = *(const float4*)(in + i);
    uint_t a = (uint_t)f2bf(v.x) | ((uint_t)f2bf(v.y) << 16);
    uint_t b = (uint_t)f2bf(v.z) | ((uint_t)f2bf(v.w) << 16);
    *(uint2*)(out + i) = make_uint2(a, b);
  }
}

// ---------------- W_dec f32 -> fp8 e4m3 (x16 scale), 4 cols per uint ----------------
__global__ __launch_bounds__(256) void conv_fp8(const float* __restrict__ in,
                                                uint_t* __restrict__ out, int n4) {
  int i = blockIdx.x * 256 + threadIdx.x;
  if (i < n4) {
    float4 v = ((const float4*)in)[i];
    int w = 0;
    w = __builtin_amdgcn_cvt_pk_fp8_f32(v.x * 16.f, v.y * 16.f, w, false);
    w = __builtin_amdgcn_cvt_pk_fp8_f32(v.z * 16.f, v.w * 16.f, w, true);
    out[i] = (uint_t)w;
  }
}

// ---------------- W_skip transpose -> bf16 [D][K] ----------------
__global__ __launch_bounds__(256) void conv_skipT(const float* __restrict__ in,
                                                  ushort_t* __restrict__ out) {
  int d = blockIdx.x * 256 + threadIdx.x;   // 0..767
  int k = blockIdx.y;                        // 0..767
  if (d < 768) out[(size_t)d * 768 + k] = f2bf(in[(size_t)k * 768 + d]);
}

// ---------------- bf16 GEMM: C[M,N] = A[M,K] * B[N,K]^T + bias ----------------
// m97-style: 128x128 tile, BK=32, 4 waves 2x2, global_load_lds staging.
template <bool BF16_OUT>
__global__ __launch_bounds__(256) void gemm_bt(const ushort_t* __restrict__ Ag,
                                               const ushort_t* __restrict__ Bg,
                                               void* __restrict__ Cg,
                                               const float* __restrict__ bias,
                                               int K, int ldc) {
  __shared__ __align__(16) char smem[34816];
  const int tid = threadIdx.x;
  const int lane = tid & 63, wid = tid >> 6;
  const int wr = wid >> 1, wc = wid & 1;
  const int lo = lane & 15, hi = lane >> 4;
  const int arow0 = blockIdx.y * 128, brow0 = blockIdx.x * 128;

  const int rr0 = (lane >> 2);
  const int kb = (lane & 3) * 8;

  f32x4 acc[4][4] = {};
  const int NT = K >> 5;

  // initial stage into buffer 0 (A at 0, B at 16384)
  for (int c = 0; c < 2; ++c) {
    int rr = (wid * 2 + c) * 16 + rr0;
    GLOAD16(Ag + (size_t)(arow0 + rr) * K + kb, smem + (wid * 2 + c) * 1024);
    GLOAD16(Bg + (size_t)(brow0 + rr) * K + kb, smem + 16384 + (wid * 2 + c) * 1024);
  }
  __syncthreads();

  for (int kt = 0; kt < NT; ++kt) {
    const int cur = (kt & 1) * 8192;
    const int nxt = 8192 - cur;
    if (kt + 1 < NT) {
      const int k0 = (kt + 1) << 5;
      for (int c = 0; c < 2; ++c) {
        int rr = (wid * 2 + c) * 16 + rr0;
        GLOAD16(Ag + (size_t)(arow0 + rr) * K + k0 + kb, smem + nxt + (wid * 2 + c) * 1024);
        GLOAD16(Bg + (size_t)(brow0 + rr) * K + k0 + kb, smem + 16384 + nxt + (wid * 2 + c) * 1024);
      }
    }
    const char* As = smem + cur;
    const char* Bs = smem + 16384 + cur;
    bf16x8 af[4], bfr[4];
#pragma unroll
    for (int m = 0; m < 4; ++m)
      af[m] = *(const bf16x8*)(As + ((wr * 64 + m * 16 + lo) * 64 + hi * 16));
#pragma unroll
    for (int n = 0; n < 4; ++n)
      bfr[n] = *(const bf16x8*)(Bs + ((wc * 64 + n * 16 + lo) * 64 + hi * 16));
#pragma unroll
    for (int m = 0; m < 4; ++m)
#pragma unroll
      for (int n = 0; n < 4; ++n)
        acc[m][n] = __builtin_amdgcn_mfma_f32_16x16x32_bf16(af[m], bfr[n], acc[m][n], 0, 0, 0);
    __syncthreads();
  }

  if (BF16_OUT) {
    // repack to LDS (row stride 136 ushorts = 272B), then coalesced copy-out
    ushort_t* ot = (ushort_t*)smem;
#pragma unroll
    for (int n = 0; n < 4; ++n) {
      const int col = wc * 64 + n * 16 + lo;
      const float bv = bias[brow0 + col];
#pragma unroll
      for (int m = 0; m < 4; ++m) {
#pragma unroll
        for (int r = 0; r < 4; ++r) {
          const int row = wr * 64 + m * 16 + hi * 4 + r;
          ot[row * 136 + col] = f2bf(acc[m][n][r] + bv);
        }
      }
    }
    __syncthreads();
    ushort_t* C = (ushort_t*)Cg;
    const int cc = tid & 15;
#pragma unroll
    for (int p = 0; p < 8; ++p) {
      const int row = p * 16 + (tid >> 4);
      ushort_t* dst = C + (size_t)(arow0 + row) * (size_t)ldc + brow0 + cc * 8;
      *(uint4*)dst = *(const uint4*)(ot + row * 136 + cc * 8);
    }
  } else {
    float* C = (float*)Cg;
#pragma unroll
    for (int n = 0; n < 4; ++n) {
      const int col = wc * 64 + n * 16 + lo;
      const float bv = bias[brow0 + col];
#pragma unroll
      for (int m = 0; m < 4; ++m) {
#pragma unroll
        for (int r = 0; r < 4; ++r) {
          const int row = wr * 64 + m * 16 + hi * 4 + r;
          C[(size_t)(arow0 + row) * (size_t)ldc + brow0 + col] = acc[m][n][r] + bv;
        }
      }
    }
  }
}

// ---------------- top-k per row (exact stable top-128 / top-32 on bf16 pre) ----------------
__global__ __launch_bounds__(256) void topk_kernel(const ushort_t* __restrict__ pre,
                                                   int* __restrict__ oidx,
                                                   float* __restrict__ oval,
                                                   double* __restrict__ accs) {
  __shared__ ushort_t rowk[12288];
  __shared__ uint_t hist[4096];
  __shared__ uint_t cand[1024];
  __shared__ uint_t csum[256];
  __shared__ uint_t sh[4];
  __shared__ float vtmp[128];
  const int tid = threadIdx.x;
  const size_t row = blockIdx.x;
  const ushort_t* pr = pre + row * 12288;

  // load + monotone key transform (bf16 -> ordered u16)
  for (int i = tid; i < 6144; i += 256) {
    uint_t u2 = ((const uint_t*)pr)[i];
    uint_t lo16 = u2 & 0xFFFFu, hi16 = u2 >> 16;
    uint_t klo = (lo16 & 0x8000u) ? (~lo16 & 0xFFFFu) : (lo16 | 0x8000u);
    uint_t khi = (hi16 & 0x8000u) ? (~hi16 & 0xFFFFu) : (hi16 | 0x8000u);
    ((uint_t*)rowk)[i] = klo | (khi << 16);
  }
  for (int i = tid; i < 4096; i += 256) hist[i] = 0;
  if (tid == 0) sh[2] = 0;
  __syncthreads();
  for (int i = tid; i < 12288; i += 256) atomicAdd(&hist[rowk[i] >> 4], 1u);
  __syncthreads();
  // per-thread chunk (16 bins) sums
  uint_t cs = 0;
  for (int b = 0; b < 16; ++b) cs += hist[tid * 16 + b];
  csum[tid] = cs;
  __syncthreads();
  // Kogge-Stone suffix sums
  for (int d = 1; d < 256; d <<= 1) {
    uint_t v = (tid + d < 256) ? csum[tid + d] : 0u;
    __syncthreads();
    csum[tid] += v;
    __syncthreads();
  }
  {
    uint_t me = csum[tid];
    uint_t nxt = (tid < 255) ? csum[tid + 1] : 0u;
    if (me >= 128u && nxt < 128u) sh[0] = (uint_t)tid;
  }
  __syncthreads();
  if (tid == 0) {
    int tc = (int)sh[0];
    uint_t running = (tc < 255) ? csum[tc + 1] : 0u;
    int b = tc * 16 + 15;
    for (; b >= tc * 16; --b) {
      running += hist[b];
      if (running >= 128u) break;
    }
    sh[0] = (uint_t)b;
    sh[1] = running;
  }
  __syncthreads();
  const uint_t tbin = sh[0];
  const int n_cand = (int)min(sh[1], 1024u);
  // collect candidates: key in high bits (inverted for val-desc), idx low
  for (int i = tid; i < 12288; i += 256) {
    uint_t k = rowk[i];
    if ((k >> 4) >= tbin) {
      uint_t pos = atomicAdd(&sh[2], 1u);
      if (pos < 1024u) cand[pos] = ((0xFFFFu - k) << 16) | (uint_t)i;
    }
  }
  __syncthreads();
  int n_sort = 128;
  while (n_sort < n_cand) n_sort <<= 1;
  for (int i = n_cand + tid; i < n_sort; i += 256) cand[i] = 0xFFFFFFFFu;
  __syncthreads();
  // bitonic sort ascending (=> val desc, idx asc)
  for (int k = 2; k <= n_sort; k <<= 1) {
    for (int j = k >> 1; j > 0; j >>= 1) {
      for (int i = tid; i < n_sort; i += 256) {
        int p = i ^ j;
        if (p > i) {
          uint_t a = cand[i], b = cand[p];
          bool up = ((i & k) == 0);
          if (up ? (a > b) : (a < b)) { cand[i] = b; cand[p] = a; }
        }
      }
      __syncthreads();
    }
  }
  if (tid < 128) {
    uint_t Kv = cand[tid];
    uint_t idx = Kv & 0xFFFFu;
    uint_t key = 0xFFFFu - (Kv >> 16);
    uint_t ub = (key & 0x8000u) ? (key & 0x7FFFu) : (~key & 0xFFFFu);
    float v = __uint_as_float(ub << 16);
    v = fmaxf(v, 0.f);
    oidx[row * 128 + tid] = (int)idx;
    oval[row * 128 + tid] = v;
    vtmp[tid] = v;
  }
  __syncthreads();
  if (tid == 0) {
    float s1 = 0.f, s2 = 0.f;
    for (int i = 0; i < 32; ++i) s1 += vtmp[i];
    for (int i = 0; i < 128; ++i) s2 += vtmp[i];
    atomicAdd(&accs[0], (double)s1);
    atomicAdd(&accs[1], (double)s2);
  }
}

// ---------------- sparse decode + loss + means (fp8 W_dec, x16 scale) ----------------
// 192 threads; thread t owns columns 4t..4t+3; one uint gather = 4 fp8 weights.
__global__ __launch_bounds__(192) void decode_loss(const int* __restrict__ oidx,
                                                   const float* __restrict__ oval,
                                                   const float* __restrict__ skip,
                                                   const float* __restrict__ mlp,
                                                   const uint_t* __restrict__ Wd8,
                                                   double* __restrict__ accs) {
  __shared__ int lidx[128];
  __shared__ float lval[128];
  __shared__ double wred[3][3];
  const int tid = threadIdx.x;
  const size_t row = blockIdx.x;
  if (tid < 128) {
    lidx[tid] = oidx[row * 128 + tid];
    lval[tid] = oval[row * 128 + tid];
  }
  __syncthreads();
  const float4 s4 = ((const float4*)(skip + row * 768))[tid];
  const float4 m4 = ((const float4*)(mlp + row * 768))[tid];
  float a0 = 0.f, a1 = 0.f, a2 = 0.f, a3 = 0.f;
#pragma unroll 8
  for (int j = 0; j < 32; ++j) {
    const float vs = lval[j] * 0.0625f;
    const uint_t wb = Wd8[(size_t)lidx[j] * 192 + tid];
    f32x2 lo = __builtin_amdgcn_cvt_pk_f32_fp8(wb, false);
    f32x2 hi = __builtin_amdgcn_cvt_pk_f32_fp8(wb, true);
    a0 = fmaf(vs, lo[0], a0);
    a1 = fmaf(vs, lo[1], a1);
    a2 = fmaf(vs, hi[0], a2);
    a3 = fmaf(vs, hi[1], a3);
  }
  float d0 = a0 + s4.x, d1 = a1 + s4.y, d2 = a2 + s4.z, d3 = a3 + s4.w;
  float e0 = m4.x - d0, e1 = m4.y - d1, e2 = m4.z - d2, e3 = m4.w - d3;
  float l1 = e0 * e0 + e1 * e1 + e2 * e2 + e3 * e3;
  float dsum = d0 + d1 + d2 + d3;
#pragma unroll 8
  for (int j = 32; j < 128; ++j) {
    const float vs = lval[j] * 0.0625f;
    const uint_t wb = Wd8[(size_t)lidx[j] * 192 + tid];
    f32x2 lo = __builtin_amdgcn_cvt_pk_f32_fp8(wb, false);
    f32x2 hi = __builtin_amdgcn_cvt_pk_f32_fp8(wb, true);
    a0 = fmaf(vs, lo[0], a0);
    a1 = fmaf(vs, lo[1], a1);
    a2 = fmaf(vs, hi[0], a2);
    a3 = fmaf(vs, hi[1], a3);
  }
  d0 = a0 + s4.x; d1 = a1 + s4.y; d2 = a2 + s4.z; d3 = a3 + s4.w;
  e0 = m4.x - d0; e1 = m4.y - d1; e2 = m4.z - d2; e3 = m4.w - d3;
  float l2 = e0 * e0 + e1 * e1 + e2 * e2 + e3 * e3;
  dsum += d0 + d1 + d2 + d3;

  double r0 = (double)l1, r1 = (double)l2, r2 = (double)dsum;
  for (int o = 32; o > 0; o >>= 1) {
    r0 += __shfl_down(r0, o);
    r1 += __shfl_down(r1, o);
    r2 += __shfl_down(r2, o);
  }
  const int w = tid >> 6;
  if ((tid & 63) == 0) { wred[w][0] = r0; wred[w][1] = r1; wred[w][2] = r2; }
  __syncthreads();
  if (tid == 0) {
    double t0 = 0, t1 = 0, t2 = 0;
    for (int i = 0; i < 3; ++i) { t0 += wred[i][0]; t1 += wred[i][1]; t2 += wred[i][2]; }
    atomicAdd(&accs[3], t0);
    atomicAdd(&accs[4], t1);
    atomicAdd(&accs[2], t2);
  }
}

// ---------------- finalize ----------------
__global__ __launch_bounds__(256) void finalize_kernel(const double* __restrict__ accs,
                                                       const float* __restrict__ colsum,
                                                       float* __restrict__ out) {
  __shared__ double wred[4];
  const int tid = threadIdx.x;
  double c2 = 0.0;
  for (int i = tid; i < 768; i += 256) { double c = (double)colsum[i]; c2 += c * c; }
  for (int o = 32; o > 0; o >>= 1) c2 += __shfl_down(c2, o);
  if ((tid & 63) == 0) wred[tid >> 6] = c2;
  __syncthreads();
  if (tid == 0) {
    double csq = wred[0] + wred[1] + wred[2] + wred[3];
    double tv = accs[5] - csq / 8192.0;
    out[0] = (float)((accs[0] + accs[1]) / (8192.0 * 12288.0));
    out[1] = (float)(accs[2] / (8192.0 * 768.0));
    out[2] = (float)(accs[3] / tv + accs[4] / (8.0 * tv));
  }
}

extern "C" void kernel_launch(void* const* d_in, const int* in_sizes, int n_in,
                              void* d_out, int out_size, void* d_ws, size_t ws_size,
                              hipStream_t stream) {
  const float* x    = (const float*)d_in[0];
  const float* mlp  = (const float*)d_in[1];
  const float* Wenc = (const float*)d_in[2];
  const float* benc = (const float*)d_in[3];
  const float* Wdec = (const float*)d_in[4];
  const float* bdec = (const float*)d_in[5];
  const float* Wskip= (const float*)d_in[6];

  char* ws = (char*)d_ws;
  const size_t OFF_COL  = 1024;
  const size_t OFF_XBF  = 8192;
  const size_t OFF_WENC = OFF_XBF  + (size_t)8192 * 768 * 2;
  const size_t OFF_WSK  = OFF_WENC + (size_t)12288 * 768 * 2;
  const size_t OFF_SKIP = OFF_WSK  + (size_t)768 * 768 * 2;
  const size_t OFF_TIDX = OFF_SKIP + (size_t)8192 * 768 * 4;
  const size_t OFF_TVAL = OFF_TIDX + (size_t)8192 * 128 * 4;
  const size_t OFF_PRE  = OFF_TVAL + (size_t)8192 * 128 * 4;

  double*   accs   = (double*)ws;
  float*    colsum = (float*)(ws + OFF_COL);
  ushort_t* xbf    = (ushort_t*)(ws + OFF_XBF);
  ushort_t* wencbf = (ushort_t*)(ws + OFF_WENC);  // reused for fp8 W_dec after enc GEMM
  ushort_t* wskT   = (ushort_t*)(ws + OFF_WSK);
  float*    skip   = (float*)(ws + OFF_SKIP);
  int*      tidx   = (int*)(ws + OFF_TIDX);
  float*    tval   = (float*)(ws + OFF_TVAL);
  ushort_t* pre    = (ushort_t*)(ws + OFF_PRE);

  (void)hipMemsetAsync(d_ws, 0, 8192, stream);

  prep_x<<<256, 256, 0, stream>>>(x, xbf, colsum, accs);
  conv_bf16<<<(12288 * 768 / 4) / 256, 256, 0, stream>>>(Wenc, wencbf, 12288 * 768);
  conv_skipT<<<dim3(3, 768), 256, 0, stream>>>(Wskip, wskT);

  gemm_bt<true><<<dim3(96, 64), 256, 0, stream>>>(xbf, wencbf, (void*)pre, benc, 768, 12288);
  gemm_bt<false><<<dim3(6, 64), 256, 0, stream>>>(xbf, wskT, (void*)skip, bdec, 768, 768);

  // W_enc staging buffer is dead now -> reuse it for fp8 W_dec (stream-ordered)
  uint_t* wdec8 = (uint_t*)wencbf;
  conv_fp8<<<(12288 * 768 / 4 + 255) / 256, 256, 0, stream>>>(Wdec, wdec8, 12288 * 768 / 4);

  topk_kernel<<<8192, 256, 0, stream>>>(pre, tidx, tval, accs);
  decode_loss<<<8192, 192, 0, stream>>>(tidx, tval, skip, mlp, wdec8, accs);
  finalize_kernel<<<1, 256, 0, stream>>>(accs, colsum, (float*)d_out);
}

// Round 5
// 885.324 us; speedup vs baseline: 1.1978x; 1.0270x over previous
//
#include <hip/hip_runtime.h>

typedef unsigned short ushort_t;
typedef unsigned int uint_t;

typedef __attribute__((ext_vector_type(8))) short bf16x8;
typedef __attribute__((ext_vector_type(4))) float f32x4;
typedef __attribute__((ext_vector_type(2))) float f32x2;

#define GLOAD16(g, l) __builtin_amdgcn_global_load_lds( \
    (const __attribute__((address_space(1))) unsigned int*)(g), \
    (__attribute__((address_space(3))) unsigned int*)(l), 16, 0, 0)

__device__ __forceinline__ ushort_t f2bf(float f) {
  union { float f; uint_t u; } c; c.f = f;
  uint_t u = c.u;
  return (ushort_t)((u + 0x7FFFu + ((u >> 16) & 1u)) >> 16);
}

__device__ __forceinline__ float bf2f(ushort_t b) {
  union { uint_t u; float f; } c; c.u = ((uint_t)b) << 16;
  return c.f;
}

// ---------------- prep: x -> bf16, colsum, sumsq ----------------
__global__ __launch_bounds__(256) void prep_x(const float* __restrict__ x,
                                              ushort_t* __restrict__ xbf,
                                              float* __restrict__ colsum,
                                              double* __restrict__ accs) {
  const int tid = threadIdx.x;
  const int r0 = blockIdx.x * 32;
  float cs0 = 0.f, cs1 = 0.f, cs2 = 0.f;
  double ss = 0.0;
  for (int r = 0; r < 32; ++r) {
    const float* xr = x + (size_t)(r0 + r) * 768;
    ushort_t* xo = xbf + (size_t)(r0 + r) * 768;
    float v0 = xr[tid], v1 = xr[tid + 256], v2 = xr[tid + 512];
    xo[tid] = f2bf(v0); xo[tid + 256] = f2bf(v1); xo[tid + 512] = f2bf(v2);
    cs0 += v0; cs1 += v1; cs2 += v2;
    ss += (double)v0 * v0 + (double)v1 * v1 + (double)v2 * v2;
  }
  atomicAdd(&colsum[tid], cs0);
  atomicAdd(&colsum[tid + 256], cs1);
  atomicAdd(&colsum[tid + 512], cs2);
  for (int o = 32; o > 0; o >>= 1) ss += __shfl_down(ss, o);
  __shared__ double wsum[4];
  if ((tid & 63) == 0) wsum[tid >> 6] = ss;
  __syncthreads();
  if (tid == 0) atomicAdd(&accs[5], wsum[0] + wsum[1] + wsum[2] + wsum[3]);
}

// ---------------- generic f32 -> bf16 convert ----------------
__global__ __launch_bounds__(256) void conv_bf16(const float* __restrict__ in,
                                                 ushort_t* __restrict__ out, int n) {
  int i = (blockIdx.x * 256 + threadIdx.x) * 4;
  if (i + 3 < n) {
    float4 v = *(const float4*)(in + i);
    uint_t a = (uint_t)f2bf(v.x) | ((uint_t)f2bf(v.y) << 16);
    uint_t b = (uint_t)f2bf(v.z) | ((uint_t)f2bf(v.w) << 16);
    *(uint2*)(out + i) = make_uint2(a, b);
  }
}

// ---------------- W_dec f32 -> fp8 e4m3 (x16 scale), 4 cols per uint ----------------
__global__ __launch_bounds__(256) void conv_fp8(const float* __restrict__ in,
                                                uint_t* __restrict__ out, int n4) {
  int i = blockIdx.x * 256 + threadIdx.x;
  if (i < n4) {
    float4 v = ((const float4*)in)[i];
    int w = 0;
    w = __builtin_amdgcn_cvt_pk_fp8_f32(v.x * 16.f, v.y * 16.f, w, false);
    w = __builtin_amdgcn_cvt_pk_fp8_f32(v.z * 16.f, v.w * 16.f, w, true);
    out[i] = (uint_t)w;
  }
}

// ---------------- W_skip transpose -> bf16 [D][K] ----------------
__global__ __launch_bounds__(256) void conv_skipT(const float* __restrict__ in,
                                                  ushort_t* __restrict__ out) {
  int d = blockIdx.x * 256 + threadIdx.x;   // 0..767
  int k = blockIdx.y;                        // 0..767
  if (d < 768) out[(size_t)d * 768 + k] = f2bf(in[(size_t)k * 768 + d]);
}

// ---------------- bf16 GEMM: C[M,N] = A[M,K] * B[N,K]^T + bias ----------------
template <bool BF16_OUT>
__global__ __launch_bounds__(256) void gemm_bt(const ushort_t* __restrict__ Ag,
                                               const ushort_t* __restrict__ Bg,
                                               void* __restrict__ Cg,
                                               const float* __restrict__ bias,
                                               int K, int ldc) {
  __shared__ __align__(16) char smem[34816];
  const int tid = threadIdx.x;
  const int lane = tid & 63, wid = tid >> 6;
  const int wr = wid >> 1, wc = wid & 1;
  const int lo = lane & 15, hi = lane >> 4;
  const int arow0 = blockIdx.y * 128, brow0 = blockIdx.x * 128;

  const int rr0 = (lane >> 2);
  const int kb = (lane & 3) * 8;

  f32x4 acc[4][4] = {};
  const int NT = K >> 5;

  for (int c = 0; c < 2; ++c) {
    int rr = (wid * 2 + c) * 16 + rr0;
    GLOAD16(Ag + (size_t)(arow0 + rr) * K + kb, smem + (wid * 2 + c) * 1024);
    GLOAD16(Bg + (size_t)(brow0 + rr) * K + kb, smem + 16384 + (wid * 2 + c) * 1024);
  }
  __syncthreads();

  for (int kt = 0; kt < NT; ++kt) {
    const int cur = (kt & 1) * 8192;
    const int nxt = 8192 - cur;
    if (kt + 1 < NT) {
      const int k0 = (kt + 1) << 5;
      for (int c = 0; c < 2; ++c) {
        int rr = (wid * 2 + c) * 16 + rr0;
        GLOAD16(Ag + (size_t)(arow0 + rr) * K + k0 + kb, smem + nxt + (wid * 2 + c) * 1024);
        GLOAD16(Bg + (size_t)(brow0 + rr) * K + k0 + kb, smem + 16384 + nxt + (wid * 2 + c) * 1024);
      }
    }
    const char* As = smem + cur;
    const char* Bs = smem + 16384 + cur;
    bf16x8 af[4], bfr[4];
#pragma unroll
    for (int m = 0; m < 4; ++m)
      af[m] = *(const bf16x8*)(As + ((wr * 64 + m * 16 + lo) * 64 + hi * 16));
#pragma unroll
    for (int n = 0; n < 4; ++n)
      bfr[n] = *(const bf16x8*)(Bs + ((wc * 64 + n * 16 + lo) * 64 + hi * 16));
#pragma unroll
    for (int m = 0; m < 4; ++m)
#pragma unroll
      for (int n = 0; n < 4; ++n)
        acc[m][n] = __builtin_amdgcn_mfma_f32_16x16x32_bf16(af[m], bfr[n], acc[m][n], 0, 0, 0);
    __syncthreads();
  }

  if (BF16_OUT) {
    ushort_t* ot = (ushort_t*)smem;
#pragma unroll
    for (int n = 0; n < 4; ++n) {
      const int col = wc * 64 + n * 16 + lo;
      const float bv = bias[brow0 + col];
#pragma unroll
      for (int m = 0; m < 4; ++m) {
#pragma unroll
        for (int r = 0; r < 4; ++r) {
          const int row = wr * 64 + m * 16 + hi * 4 + r;
          ot[row * 136 + col] = f2bf(acc[m][n][r] + bv);
        }
      }
    }
    __syncthreads();
    ushort_t* C = (ushort_t*)Cg;
    const int cc = tid & 15;
#pragma unroll
    for (int p = 0; p < 8; ++p) {
      const int row = p * 16 + (tid >> 4);
      ushort_t* dst = C + (size_t)(arow0 + row) * (size_t)ldc + brow0 + cc * 8;
      *(uint4*)dst = *(const uint4*)(ot + row * 136 + cc * 8);
    }
  } else {
    float* C = (float*)Cg;
#pragma unroll
    for (int n = 0; n < 4; ++n) {
      const int col = wc * 64 + n * 16 + lo;
      const float bv = bias[brow0 + col];
#pragma unroll
      for (int m = 0; m < 4; ++m) {
#pragma unroll
        for (int r = 0; r < 4; ++r) {
          const int row = wr * 64 + m * 16 + hi * 4 + r;
          C[(size_t)(arow0 + row) * (size_t)ldc + brow0 + col] = acc[m][n][r] + bv;
        }
      }
    }
  }
}

// ---------------- top-k: exact top-32/top-128 sets via histogram select ----------------
// One row per block. Keys cached in registers (24 packed uints/thread).
// No block-wide sort: threshold refine (4096-bin hist -> 16-bin sub-hist -> idx
// tie-break via 64-lane shuffle bitonic). Slots 0..31 = top-32 set, 32..127 = rest.
__global__ __launch_bounds__(256) void topk_kernel(const ushort_t* __restrict__ pre,
                                                   int* __restrict__ oidx,
                                                   float* __restrict__ oval,
                                                   double* __restrict__ accs) {
  __shared__ uint_t hist[2048];          // 4096 bins packed 2 x u16
  __shared__ uint_t sub32[16], sub128[16];
  __shared__ uint_t list32[64], list128[64];
  __shared__ uint_t wtot[4];
  __shared__ int ctl[16];
  __shared__ float fred[8];
  const int tid = threadIdx.x;
  const int lane = tid & 63, wid = tid >> 6;
  const size_t row = blockIdx.x;
  const uint_t* pr = (const uint_t*)(pre + row * 12288);

  for (int i = tid; i < 2048; i += 256) hist[i] = 0;
  if (tid < 16) { sub32[tid] = 0; sub128[tid] = 0; ctl[tid] = 0; }
  __syncthreads();

  // pass 1: load row (once), monotone key transform, histogram
  uint_t k2[24];
#pragma unroll
  for (int i = 0; i < 24; ++i) {
    uint_t u2 = pr[i * 256 + tid];
    uint_t lo16 = u2 & 0xFFFFu, hi16 = u2 >> 16;
    uint_t klo = (lo16 & 0x8000u) ? (~lo16 & 0xFFFFu) : (lo16 | 0x8000u);
    uint_t khi = (hi16 & 0x8000u) ? (~hi16 & 0xFFFFu) : (hi16 | 0x8000u);
    k2[i] = klo | (khi << 16);
    uint_t b0 = klo >> 4, b1 = khi >> 4;
    atomicAdd(&hist[b0 >> 1], (b0 & 1) ? 65536u : 1u);
    atomicAdd(&hist[b1 >> 1], (b1 & 1) ? 65536u : 1u);
  }
  __syncthreads();

  // chunk sums (16 bins = 8 packed words per thread) + wave suffix scan
  uint_t cs = 0;
#pragma unroll
  for (int wq = 0; wq < 8; ++wq) {
    uint_t hw = hist[tid * 8 + wq];
    cs += (hw & 0xFFFFu) + (hw >> 16);
  }
  uint_t s = cs;
#pragma unroll
  for (int off = 1; off < 64; off <<= 1) {
    uint_t v = (uint_t)__shfl_down((int)s, off);
    if (lane + off < 64) s += v;
  }
  if (lane == 0) wtot[wid] = s;
  __syncthreads();
  uint_t above = 0;
  for (int w = wid + 1; w < 4; ++w) above += wtot[w];
  const uint_t Sg = s + above;         // suffix count over bins >= 16*tid
  const uint_t Snx = Sg - cs;
  // crossing threads walk their 16-bin chunk for K=32 and K=128
#pragma unroll
  for (int which = 0; which < 2; ++which) {
    const uint_t K = which ? 128u : 32u;
    if (Sg >= K && Snx < K) {
      uint_t running = Snx;
      for (int b = tid * 16 + 15; b >= tid * 16; --b) {
        uint_t c = (hist[b >> 1] >> ((b & 1) * 16)) & 0xFFFFu;
        if (running + c >= K) { ctl[which * 2] = b; ctl[which * 2 + 1] = (int)running; break; }
        running += c;
      }
    }
  }
  __syncthreads();
  const uint_t b32 = (uint_t)ctl[0], b128 = (uint_t)ctl[2];

  // pass 2 (regs): sub-histogram over low 4 key bits of the threshold bins
#pragma unroll
  for (int i = 0; i < 24; ++i) {
    uint_t kk = k2[i];
#pragma unroll
    for (int h = 0; h < 2; ++h) {
      uint_t key = (h ? (kk >> 16) : kk) & 0xFFFFu;
      uint_t bin = key >> 4;
      if (bin == b32) atomicAdd(&sub32[key & 15], 1u);
      if (bin == b128) atomicAdd(&sub128[key & 15], 1u);
    }
  }
  __syncthreads();

  // exact 16-bit key threshold + tie count r
  if (tid < 2) {
    const uint_t* sub = tid ? sub128 : sub32;
    const uint_t K = tid ? 128u : 32u;
    const uint_t chi = (uint_t)ctl[tid * 2 + 1];
    const uint_t bK = (uint_t)ctl[tid * 2];
    const uint_t need = K - chi;
    uint_t running = 0;
    for (int sb = 15; sb >= 0; --sb) {
      uint_t c = sub[sb];
      if (running + c >= need) {
        ctl[4 + tid * 2] = (int)((bK << 4) | (uint_t)sb);
        ctl[5 + tid * 2] = (int)(need - running);
        break;
      }
      running += c;
    }
  }
  __syncthreads();
  const uint_t kt32 = (uint_t)ctl[4], kt128 = (uint_t)ctl[6];

  // pass 3 (regs): collect indices tied at the exact threshold key
#pragma unroll
  for (int i = 0; i < 24; ++i) {
    uint_t kk = k2[i];
#pragma unroll
    for (int h = 0; h < 2; ++h) {
      uint_t key = (h ? (kk >> 16) : kk) & 0xFFFFu;
      uint_t idx = (uint_t)(i * 512 + tid * 2 + h);
      if (key == kt32) {
        uint_t p = atomicAdd((uint_t*)&ctl[8], 1u);
        if (p < 64) list32[p] = idx;
      }
      if (key == kt128) {
        uint_t p = atomicAdd((uint_t*)&ctl[9], 1u);
        if (p < 64) list128[p] = idx;
      }
    }
  }
  __syncthreads();

  // waves 0/1: in-wave bitonic sort of tie indices, pick r-th smallest
  if (wid < 2) {
    const int n = min(ctl[8 + wid], 64);
    const int r = ctl[5 + wid * 2];
    uint_t v = (lane < n) ? (wid ? list128[lane] : list32[lane]) : 0xFFFFFFFFu;
#pragma unroll
    for (int k = 2; k <= 64; k <<= 1) {
#pragma unroll
      for (int j = k >> 1; j > 0; j >>= 1) {
        uint_t p = (uint_t)__shfl_xor((int)v, j);
        bool asc = ((lane & k) == 0);
        bool lower = ((lane & j) == 0);
        v = (asc == lower) ? min(v, p) : max(v, p);
      }
    }
    uint_t idxt = (uint_t)__shfl((int)v, r - 1);
    if (lane == 0) ctl[10 + wid] = (int)idxt;
  }
  __syncthreads();
  const uint_t idxt32 = (uint_t)ctl[10], idxt128 = (uint_t)ctl[11];

  // pass 4 (regs): exact membership, write sets, accumulate sums
  float s1 = 0.f, s2 = 0.f;
  int* rowIdx = oidx + row * 128;
  float* rowVal = oval + row * 128;
#pragma unroll
  for (int i = 0; i < 24; ++i) {
    uint_t kk = k2[i];
#pragma unroll
    for (int h = 0; h < 2; ++h) {
      uint_t key = (h ? (kk >> 16) : kk) & 0xFFFFu;
      uint_t idx = (uint_t)(i * 512 + tid * 2 + h);
      bool in32 = (key > kt32) || (key == kt32 && idx <= idxt32);
      bool in128 = (key > kt128) || (key == kt128 && idx <= idxt128);
      if (in128) {
        uint_t ub = (key & 0x8000u) ? (key & 0x7FFFu) : (~key & 0xFFFFu);
        float v = fmaxf(__uint_as_float(ub << 16), 0.f);
        int slot;
        if (in32) { slot = (int)atomicAdd((uint_t*)&ctl[12], 1u); s1 += v; }
        else      { slot = 32 + (int)atomicAdd((uint_t*)&ctl[13], 1u); }
        s2 += v;
        rowIdx[slot] = (int)idx;
        rowVal[slot] = v;
      }
    }
  }
  for (int o = 32; o > 0; o >>= 1) { s1 += __shfl_down(s1, o); s2 += __shfl_down(s2, o); }
  if (lane == 0) { fred[wid] = s1; fred[4 + wid] = s2; }
  __syncthreads();
  if (tid == 0) {
    atomicAdd(&accs[0], (double)(fred[0] + fred[1] + fred[2] + fred[3]));
    atomicAdd(&accs[1], (double)(fred[4] + fred[5] + fred[6] + fred[7]));
  }
}

// ---------------- sparse decode + loss + means (fp8 W_dec, x16 scale) ----------------
__global__ __launch_bounds__(192) void decode_loss(const int* __restrict__ oidx,
                                                   const float* __restrict__ oval,
                                                   const float* __restrict__ skip,
                                                   const float* __restrict__ mlp,
                                                   const uint_t* __restrict__ Wd8,
                                                   double* __restrict__ accs) {
  __shared__ int lidx[128];
  __shared__ float lval[128];
  __shared__ double wred[3][3];
  const int tid = threadIdx.x;
  const size_t row = blockIdx.x;
  if (tid < 128) {
    lidx[tid] = oidx[row * 128 + tid];
    lval[tid] = oval[row * 128 + tid];
  }
  __syncthreads();
  const float4 s4 = ((const float4*)(skip + row * 768))[tid];
  const float4 m4 = ((const float4*)(mlp + row * 768))[tid];
  float a0 = 0.f, a1 = 0.f, a2 = 0.f, a3 = 0.f;
#pragma unroll 8
  for (int j = 0; j < 32; ++j) {
    const float vs = lval[j] * 0.0625f;
    const uint_t wb = Wd8[(size_t)lidx[j] * 192 + tid];
    f32x2 lo = __builtin_amdgcn_cvt_pk_f32_fp8(wb, false);
    f32x2 hi = __builtin_amdgcn_cvt_pk_f32_fp8(wb, true);
    a0 = fmaf(vs, lo[0], a0);
    a1 = fmaf(vs, lo[1], a1);
    a2 = fmaf(vs, hi[0], a2);
    a3 = fmaf(vs, hi[1], a3);
  }
  float d0 = a0 + s4.x, d1 = a1 + s4.y, d2 = a2 + s4.z, d3 = a3 + s4.w;
  float e0 = m4.x - d0, e1 = m4.y - d1, e2 = m4.z - d2, e3 = m4.w - d3;
  float l1 = e0 * e0 + e1 * e1 + e2 * e2 + e3 * e3;
  float dsum = d0 + d1 + d2 + d3;
#pragma unroll 8
  for (int j = 32; j < 128; ++j) {
    const float vs = lval[j] * 0.0625f;
    const uint_t wb = Wd8[(size_t)lidx[j] * 192 + tid];
    f32x2 lo = __builtin_amdgcn_cvt_pk_f32_fp8(wb, false);
    f32x2 hi = __builtin_amdgcn_cvt_pk_f32_fp8(wb, true);
    a0 = fmaf(vs, lo[0], a0);
    a1 = fmaf(vs, lo[1], a1);
    a2 = fmaf(vs, hi[0], a2);
    a3 = fmaf(vs, hi[1], a3);
  }
  d0 = a0 + s4.x; d1 = a1 + s4.y; d2 = a2 + s4.z; d3 = a3 + s4.w;
  e0 = m4.x - d0; e1 = m4.y - d1; e2 = m4.z - d2; e3 = m4.w - d3;
  float l2 = e0 * e0 + e1 * e1 + e2 * e2 + e3 * e3;
  dsum += d0 + d1 + d2 + d3;

  double r0 = (double)l1, r1 = (double)l2, r2 = (double)dsum;
  for (int o = 32; o > 0; o >>= 1) {
    r0 += __shfl_down(r0, o);
    r1 += __shfl_down(r1, o);
    r2 += __shfl_down(r2, o);
  }
  const int w = tid >> 6;
  if ((tid & 63) == 0) { wred[w][0] = r0; wred[w][1] = r1; wred[w][2] = r2; }
  __syncthreads();
  if (tid == 0) {
    double t0 = 0, t1 = 0, t2 = 0;
    for (int i = 0; i < 3; ++i) { t0 += wred[i][0]; t1 += wred[i][1]; t2 += wred[i][2]; }
    atomicAdd(&accs[3], t0);
    atomicAdd(&accs[4], t1);
    atomicAdd(&accs[2], t2);
  }
}

// ---------------- finalize ----------------
__global__ __launch_bounds__(256) void finalize_kernel(const double* __restrict__ accs,
                                                       const float* __restrict__ colsum,
                                                       float* __restrict__ out) {
  __shared__ double wred[4];
  const int tid = threadIdx.x;
  double c2 = 0.0;
  for (int i = tid; i < 768; i += 256) { double c = (double)colsum[i]; c2 += c * c; }
  for (int o = 32; o > 0; o >>= 1) c2 += __shfl_down(c2, o);
  if ((tid & 63) == 0) wred[tid >> 6] = c2;
  __syncthreads();
  if (tid == 0) {
    double csq = wred[0] + wred[1] + wred[2] + wred[3];
    double tv = accs[5] - csq / 8192.0;
    out[0] = (float)((accs[0] + accs[1]) / (8192.0 * 12288.0));
    out[1] = (float)(accs[2] / (8192.0 * 768.0));
    out[2] = (float)(accs[3] / tv + accs[4] / (8.0 * tv));
  }
}

extern "C" void kernel_launch(void* const* d_in, const int* in_sizes, int n_in,
                              void* d_out, int out_size, void* d_ws, size_t ws_size,
                              hipStream_t stream) {
  const float* x    = (const float*)d_in[0];
  const float* mlp  = (const float*)d_in[1];
  const float* Wenc = (const float*)d_in[2];
  const float* benc = (const float*)d_in[3];
  const float* Wdec = (const float*)d_in[4];
  const float* bdec = (const float*)d_in[5];
  const float* Wskip= (const float*)d_in[6];

  char* ws = (char*)d_ws;
  const size_t OFF_COL  = 1024;
  const size_t OFF_XBF  = 8192;
  const size_t OFF_WENC = OFF_XBF  + (size_t)8192 * 768 * 2;
  const size_t OFF_WSK  = OFF_WENC + (size_t)12288 * 768 * 2;
  const size_t OFF_SKIP = OFF_WSK  + (size_t)768 * 768 * 2;
  const size_t OFF_TIDX = OFF_SKIP + (size_t)8192 * 768 * 4;
  const size_t OFF_TVAL = OFF_TIDX + (size_t)8192 * 128 * 4;
  const size_t OFF_PRE  = OFF_TVAL + (size_t)8192 * 128 * 4;

  double*   accs   = (double*)ws;
  float*    colsum = (float*)(ws + OFF_COL);
  ushort_t* xbf    = (ushort_t*)(ws + OFF_XBF);
  ushort_t* wencbf = (ushort_t*)(ws + OFF_WENC);  // reused for fp8 W_dec after enc GEMM
  ushort_t* wskT   = (ushort_t*)(ws + OFF_WSK);
  float*    skip   = (float*)(ws + OFF_SKIP);
  int*      tidx   = (int*)(ws + OFF_TIDX);
  float*    tval   = (float*)(ws + OFF_TVAL);
  ushort_t* pre    = (ushort_t*)(ws + OFF_PRE);

  (void)hipMemsetAsync(d_ws, 0, 8192, stream);

  prep_x<<<256, 256, 0, stream>>>(x, xbf, colsum, accs);
  conv_bf16<<<(12288 * 768 / 4) / 256, 256, 0, stream>>>(Wenc, wencbf, 12288 * 768);
  conv_skipT<<<dim3(3, 768), 256, 0, stream>>>(Wskip, wskT);

  gemm_bt<true><<<dim3(96, 64), 256, 0, stream>>>(xbf, wencbf, (void*)pre, benc, 768, 12288);
  gemm_bt<false><<<dim3(6, 64), 256, 0, stream>>>(xbf, wskT, (void*)skip, bdec, 768, 768);

  // W_enc staging buffer is dead now -> reuse it for fp8 W_dec (stream-ordered)
  uint_t* wdec8 = (uint_t*)wencbf;
  conv_fp8<<<(12288 * 768 / 4 + 255) / 256, 256, 0, stream>>>(Wdec, wdec8, 12288 * 768 / 4);

  topk_kernel<<<8192, 256, 0, stream>>>(pre, tidx, tval, accs);
  decode_loss<<<8192, 192, 0, stream>>>(tidx, tval, skip, mlp, wdec8, accs);
  finalize_kernel<<<1, 256, 0, stream>>>(accs, colsum, (float*)d_out);
}

// Round 6
// 847.004 us; speedup vs baseline: 1.2520x; 1.0452x over previous
//
#include <hip/hip_runtime.h>

typedef unsigned short ushort_t;
typedef unsigned int uint_t;

typedef __attribute__((ext_vector_type(8))) short bf16x8;
typedef __attribute__((ext_vector_type(4))) float f32x4;
typedef __attribute__((ext_vector_type(2))) float f32x2;

#define GLOAD16(g, l) __builtin_amdgcn_global_load_lds( \
    (const __attribute__((address_space(1))) unsigned int*)(g), \
    (__attribute__((address_space(3))) unsigned int*)(l), 16, 0, 0)

__device__ __forceinline__ ushort_t f2bf(float f) {
  union { float f; uint_t u; } c; c.f = f;
  uint_t u = c.u;
  return (ushort_t)((u + 0x7FFFu + ((u >> 16) & 1u)) >> 16);
}

// ---------------- prep: x -> bf16, colsum, sumsq ----------------
__global__ __launch_bounds__(256) void prep_x(const float* __restrict__ x,
                                              ushort_t* __restrict__ xbf,
                                              float* __restrict__ colsum,
                                              double* __restrict__ accs) {
  const int tid = threadIdx.x;
  const int r0 = blockIdx.x * 32;
  float cs0 = 0.f, cs1 = 0.f, cs2 = 0.f;
  double ss = 0.0;
  for (int r = 0; r < 32; ++r) {
    const float* xr = x + (size_t)(r0 + r) * 768;
    ushort_t* xo = xbf + (size_t)(r0 + r) * 768;
    float v0 = xr[tid], v1 = xr[tid + 256], v2 = xr[tid + 512];
    xo[tid] = f2bf(v0); xo[tid + 256] = f2bf(v1); xo[tid + 512] = f2bf(v2);
    cs0 += v0; cs1 += v1; cs2 += v2;
    ss += (double)v0 * v0 + (double)v1 * v1 + (double)v2 * v2;
  }
  atomicAdd(&colsum[tid], cs0);
  atomicAdd(&colsum[tid + 256], cs1);
  atomicAdd(&colsum[tid + 512], cs2);
  for (int o = 32; o > 0; o >>= 1) ss += __shfl_down(ss, o);
  __shared__ double wsum[4];
  if ((tid & 63) == 0) wsum[tid >> 6] = ss;
  __syncthreads();
  if (tid == 0) atomicAdd(&accs[5], wsum[0] + wsum[1] + wsum[2] + wsum[3]);
}

// ---------------- generic f32 -> bf16 convert ----------------
__global__ __launch_bounds__(256) void conv_bf16(const float* __restrict__ in,
                                                 ushort_t* __restrict__ out, int n) {
  int i = (blockIdx.x * 256 + threadIdx.x) * 4;
  if (i + 3 < n) {
    float4 v = *(const float4*)(in + i);
    uint_t a = (uint_t)f2bf(v.x) | ((uint_t)f2bf(v.y) << 16);
    uint_t b = (uint_t)f2bf(v.z) | ((uint_t)f2bf(v.w) << 16);
    *(uint2*)(out + i) = make_uint2(a, b);
  }
}

// ---------------- W_dec f32 -> fp8 e4m3 (x16 scale), 4 cols per uint ----------------
__global__ __launch_bounds__(256) void conv_fp8(const float* __restrict__ in,
                                                uint_t* __restrict__ out, int n4) {
  int i = blockIdx.x * 256 + threadIdx.x;
  if (i < n4) {
    float4 v = ((const float4*)in)[i];
    int w = 0;
    w = __builtin_amdgcn_cvt_pk_fp8_f32(v.x * 16.f, v.y * 16.f, w, false);
    w = __builtin_amdgcn_cvt_pk_fp8_f32(v.z * 16.f, v.w * 16.f, w, true);
    out[i] = (uint_t)w;
  }
}

// ---------------- W_skip transpose -> bf16 [D][K] ----------------
__global__ __launch_bounds__(256) void conv_skipT(const float* __restrict__ in,
                                                  ushort_t* __restrict__ out) {
  int d = blockIdx.x * 256 + threadIdx.x;   // 0..767
  int k = blockIdx.y;                        // 0..767
  if (d < 768) out[(size_t)d * 768 + k] = f2bf(in[(size_t)k * 768 + d]);
}

// ---------------- bf16 GEMM: C[M,N] = A[M,K] * B[N,K]^T + bias ----------------
template <bool BF16_OUT>
__global__ __launch_bounds__(256) void gemm_bt(const ushort_t* __restrict__ Ag,
                                               const ushort_t* __restrict__ Bg,
                                               void* __restrict__ Cg,
                                               const float* __restrict__ bias,
                                               int K, int ldc) {
  __shared__ __align__(16) char smem[34816];
  const int tid = threadIdx.x;
  const int lane = tid & 63, wid = tid >> 6;
  const int wr = wid >> 1, wc = wid & 1;
  const int lo = lane & 15, hi = lane >> 4;
  const int arow0 = blockIdx.y * 128, brow0 = blockIdx.x * 128;

  const int rr0 = (lane >> 2);
  const int kb = (lane & 3) * 8;

  f32x4 acc[4][4] = {};
  const int NT = K >> 5;

  for (int c = 0; c < 2; ++c) {
    int rr = (wid * 2 + c) * 16 + rr0;
    GLOAD16(Ag + (size_t)(arow0 + rr) * K + kb, smem + (wid * 2 + c) * 1024);
    GLOAD16(Bg + (size_t)(brow0 + rr) * K + kb, smem + 16384 + (wid * 2 + c) * 1024);
  }
  __syncthreads();

  for (int kt = 0; kt < NT; ++kt) {
    const int cur = (kt & 1) * 8192;
    const int nxt = 8192 - cur;
    if (kt + 1 < NT) {
      const int k0 = (kt + 1) << 5;
      for (int c = 0; c < 2; ++c) {
        int rr = (wid * 2 + c) * 16 + rr0;
        GLOAD16(Ag + (size_t)(arow0 + rr) * K + k0 + kb, smem + nxt + (wid * 2 + c) * 1024);
        GLOAD16(Bg + (size_t)(brow0 + rr) * K + k0 + kb, smem + 16384 + nxt + (wid * 2 + c) * 1024);
      }
    }
    const char* As = smem + cur;
    const char* Bs = smem + 16384 + cur;
    bf16x8 af[4], bfr[4];
#pragma unroll
    for (int m = 0; m < 4; ++m)
      af[m] = *(const bf16x8*)(As + ((wr * 64 + m * 16 + lo) * 64 + hi * 16));
#pragma unroll
    for (int n = 0; n < 4; ++n)
      bfr[n] = *(const bf16x8*)(Bs + ((wc * 64 + n * 16 + lo) * 64 + hi * 16));
#pragma unroll
    for (int m = 0; m < 4; ++m)
#pragma unroll
      for (int n = 0; n < 4; ++n)
        acc[m][n] = __builtin_amdgcn_mfma_f32_16x16x32_bf16(af[m], bfr[n], acc[m][n], 0, 0, 0);
    __syncthreads();
  }

  if (BF16_OUT) {
    ushort_t* ot = (ushort_t*)smem;
#pragma unroll
    for (int n = 0; n < 4; ++n) {
      const int col = wc * 64 + n * 16 + lo;
      const float bv = bias[brow0 + col];
#pragma unroll
      for (int m = 0; m < 4; ++m) {
#pragma unroll
        for (int r = 0; r < 4; ++r) {
          const int row = wr * 64 + m * 16 + hi * 4 + r;
          ot[row * 136 + col] = f2bf(acc[m][n][r] + bv);
        }
      }
    }
    __syncthreads();
    ushort_t* C = (ushort_t*)Cg;
    const int cc = tid & 15;
#pragma unroll
    for (int p = 0; p < 8; ++p) {
      const int row = p * 16 + (tid >> 4);
      ushort_t* dst = C + (size_t)(arow0 + row) * (size_t)ldc + brow0 + cc * 8;
      *(uint4*)dst = *(const uint4*)(ot + row * 136 + cc * 8);
    }
  } else {
    float* C = (float*)Cg;
#pragma unroll
    for (int n = 0; n < 4; ++n) {
      const int col = wc * 64 + n * 16 + lo;
      const float bv = bias[brow0 + col];
#pragma unroll
      for (int m = 0; m < 4; ++m) {
#pragma unroll
        for (int r = 0; r < 4; ++r) {
          const int row = wr * 64 + m * 16 + hi * 4 + r;
          C[(size_t)(arow0 + row) * (size_t)ldc + brow0 + col] = acc[m][n][r] + bv;
        }
      }
    }
  }
}

// ---------------- top-k: exact top-32/top-128 sets via histogram select ----------------
// uint4 row loads; u32 histogram in padded [256][17] layout (bank-conflict-free
// chunk sums). Slots 0..31 = top-32 set, 32..127 = rest.
#define EIDX(c, h) ((uint_t)(((c) >> 2) * 2048 + tid * 8 + (((c) & 3) << 1) + (h)))
#define HW(b) (((b) >> 4) * 17 + ((b) & 15))
__global__ __launch_bounds__(256) void topk_kernel(const ushort_t* __restrict__ pre,
                                                   int* __restrict__ oidx,
                                                   float* __restrict__ oval,
                                                   double* __restrict__ accs) {
  __shared__ uint_t hist[4352];          // 256 chunks x 17 (16 bins + pad)
  __shared__ uint_t sub32[16], sub128[16];
  __shared__ uint_t list32[64], list128[64];
  __shared__ uint_t wtot[4];
  __shared__ int ctl[16];
  __shared__ float fred[8];
  const int tid = threadIdx.x;
  const int lane = tid & 63, wid = tid >> 6;
  const size_t row = blockIdx.x;
  const uint4* pr4 = (const uint4*)(pre + row * 12288);

  for (int i = tid; i < 4352; i += 256) hist[i] = 0;
  if (tid < 16) { sub32[tid] = 0; sub128[tid] = 0; ctl[tid] = 0; }
  __syncthreads();

  // pass 1: load row (uint4), monotone key transform, histogram
  uint_t k2[24];
#pragma unroll
  for (int i = 0; i < 6; ++i) {
    uint4 q = pr4[i * 256 + tid];
    uint_t qq[4] = { q.x, q.y, q.z, q.w };
#pragma unroll
    for (int w = 0; w < 4; ++w) {
      uint_t u2 = qq[w];
      uint_t lo16 = u2 & 0xFFFFu, hi16 = u2 >> 16;
      uint_t klo = (lo16 & 0x8000u) ? (~lo16 & 0xFFFFu) : (lo16 | 0x8000u);
      uint_t khi = (hi16 & 0x8000u) ? (~hi16 & 0xFFFFu) : (hi16 | 0x8000u);
      k2[i * 4 + w] = klo | (khi << 16);
      atomicAdd(&hist[HW(klo >> 4)], 1u);
      atomicAdd(&hist[HW(khi >> 4)], 1u);
    }
  }
  __syncthreads();

  // chunk sums (16 bins per thread, padded rows) + wave suffix scan
  uint_t cs = 0;
#pragma unroll
  for (int b = 0; b < 16; ++b) cs += hist[tid * 17 + b];
  uint_t s = cs;
#pragma unroll
  for (int off = 1; off < 64; off <<= 1) {
    uint_t v = (uint_t)__shfl_down((int)s, off);
    if (lane + off < 64) s += v;
  }
  if (lane == 0) wtot[wid] = s;
  __syncthreads();
  uint_t above = 0;
  for (int w = wid + 1; w < 4; ++w) above += wtot[w];
  const uint_t Sg = s + above;         // suffix count over bins >= 16*tid
  const uint_t Snx = Sg - cs;
#pragma unroll
  for (int which = 0; which < 2; ++which) {
    const uint_t K = which ? 128u : 32u;
    if (Sg >= K && Snx < K) {
      uint_t running = Snx;
      for (int b = 15; b >= 0; --b) {
        uint_t c = hist[tid * 17 + b];
        if (running + c >= K) { ctl[which * 2] = tid * 16 + b; ctl[which * 2 + 1] = (int)running; break; }
        running += c;
      }
    }
  }
  __syncthreads();
  const uint_t b32 = (uint_t)ctl[0], b128 = (uint_t)ctl[2];

  // pass 2 (regs): sub-histogram over low 4 key bits of the threshold bins
#pragma unroll
  for (int c = 0; c < 24; ++c) {
    uint_t kk = k2[c];
#pragma unroll
    for (int h = 0; h < 2; ++h) {
      uint_t key = (h ? (kk >> 16) : kk) & 0xFFFFu;
      uint_t bin = key >> 4;
      if (bin == b32) atomicAdd(&sub32[key & 15], 1u);
      if (bin == b128) atomicAdd(&sub128[key & 15], 1u);
    }
  }
  __syncthreads();

  // exact 16-bit key threshold + tie count r
  if (tid < 2) {
    const uint_t* sub = tid ? sub128 : sub32;
    const uint_t K = tid ? 128u : 32u;
    const uint_t chi = (uint_t)ctl[tid * 2 + 1];
    const uint_t bK = (uint_t)ctl[tid * 2];
    const uint_t need = K - chi;
    uint_t running = 0;
    for (int sb = 15; sb >= 0; --sb) {
      uint_t c = sub[sb];
      if (running + c >= need) {
        ctl[4 + tid * 2] = (int)((bK << 4) | (uint_t)sb);
        ctl[5 + tid * 2] = (int)(need - running);
        break;
      }
      running += c;
    }
  }
  __syncthreads();
  const uint_t kt32 = (uint_t)ctl[4], kt128 = (uint_t)ctl[6];

  // pass 3 (regs): collect indices tied at the exact threshold key
#pragma unroll
  for (int c = 0; c < 24; ++c) {
    uint_t kk = k2[c];
#pragma unroll
    for (int h = 0; h < 2; ++h) {
      uint_t key = (h ? (kk >> 16) : kk) & 0xFFFFu;
      uint_t idx = EIDX(c, h);
      if (key == kt32) {
        uint_t p = atomicAdd((uint_t*)&ctl[8], 1u);
        if (p < 64) list32[p] = idx;
      }
      if (key == kt128) {
        uint_t p = atomicAdd((uint_t*)&ctl[9], 1u);
        if (p < 64) list128[p] = idx;
      }
    }
  }
  __syncthreads();

  // waves 0/1: in-wave bitonic sort of tie indices, pick r-th smallest
  if (wid < 2) {
    const int n = min(ctl[8 + wid], 64);
    const int r = ctl[5 + wid * 2];
    uint_t v = (lane < n) ? (wid ? list128[lane] : list32[lane]) : 0xFFFFFFFFu;
#pragma unroll
    for (int k = 2; k <= 64; k <<= 1) {
#pragma unroll
      for (int j = k >> 1; j > 0; j >>= 1) {
        uint_t p = (uint_t)__shfl_xor((int)v, j);
        bool asc = ((lane & k) == 0);
        bool lower = ((lane & j) == 0);
        v = (asc == lower) ? min(v, p) : max(v, p);
      }
    }
    uint_t idxt = (uint_t)__shfl((int)v, r - 1);
    if (lane == 0) ctl[10 + wid] = (int)idxt;
  }
  __syncthreads();
  const uint_t idxt32 = (uint_t)ctl[10], idxt128 = (uint_t)ctl[11];

  // pass 4 (regs): exact membership, write sets, accumulate sums
  float s1 = 0.f, s2 = 0.f;
  int* rowIdx = oidx + row * 128;
  float* rowVal = oval + row * 128;
#pragma unroll
  for (int c = 0; c < 24; ++c) {
    uint_t kk = k2[c];
#pragma unroll
    for (int h = 0; h < 2; ++h) {
      uint_t key = (h ? (kk >> 16) : kk) & 0xFFFFu;
      uint_t idx = EIDX(c, h);
      bool in32 = (key > kt32) || (key == kt32 && idx <= idxt32);
      bool in128 = (key > kt128) || (key == kt128 && idx <= idxt128);
      if (in128) {
        uint_t ub = (key & 0x8000u) ? (key & 0x7FFFu) : (~key & 0xFFFFu);
        float v = fmaxf(__uint_as_float(ub << 16), 0.f);
        int slot;
        if (in32) { slot = (int)atomicAdd((uint_t*)&ctl[12], 1u); s1 += v; }
        else      { slot = 32 + (int)atomicAdd((uint_t*)&ctl[13], 1u); }
        s2 += v;
        rowIdx[slot] = (int)idx;
        rowVal[slot] = v;
      }
    }
  }
  for (int o = 32; o > 0; o >>= 1) { s1 += __shfl_down(s1, o); s2 += __shfl_down(s2, o); }
  if (lane == 0) { fred[wid] = s1; fred[4 + wid] = s2; }
  __syncthreads();
  if (tid == 0) {
    atomicAdd(&accs[0], (double)(fred[0] + fred[1] + fred[2] + fred[3]));
    atomicAdd(&accs[1], (double)(fred[4] + fred[5] + fred[6] + fred[7]));
  }
}

// ---------------- sparse decode + loss + means (fp8 W_dec, x16 scale) ----------------
// 192 threads, 4 cols/thread. Explicit 8-deep register staging -> MLP 8.
__global__ __launch_bounds__(192) void decode_loss(const int* __restrict__ oidx,
                                                   const float* __restrict__ oval,
                                                   const float* __restrict__ skip,
                                                   const float* __restrict__ mlp,
                                                   const uint_t* __restrict__ Wd8,
                                                   double* __restrict__ accs) {
  __shared__ int lidx[128];
  __shared__ float lval[128];
  __shared__ double wred[3][3];
  const int tid = threadIdx.x;
  const size_t row = blockIdx.x;
  if (tid < 128) {
    lidx[tid] = oidx[row * 128 + tid];
    lval[tid] = oval[row * 128 + tid];
  }
  __syncthreads();
  const float4 s4 = ((const float4*)(skip + row * 768))[tid];
  const float4 m4 = ((const float4*)(mlp + row * 768))[tid];
  const uint_t* Wt = Wd8 + tid;
  float a0 = 0.f, a1 = 0.f, a2 = 0.f, a3 = 0.f;
  float l1 = 0.f, dsum = 0.f;

#pragma unroll 1
  for (int g = 0; g < 16; ++g) {
    uint_t wb[8];
    float vv[8];
#pragma unroll
    for (int b = 0; b < 8; ++b) {
      wb[b] = Wt[(size_t)lidx[g * 8 + b] * 192];
      vv[b] = lval[g * 8 + b];
    }
#pragma unroll
    for (int b = 0; b < 8; ++b) {
      const float vs = vv[b] * 0.0625f;
      f32x2 lo = __builtin_amdgcn_cvt_pk_f32_fp8(wb[b], false);
      f32x2 hi = __builtin_amdgcn_cvt_pk_f32_fp8(wb[b], true);
      a0 = fmaf(vs, lo[0], a0);
      a1 = fmaf(vs, lo[1], a1);
      a2 = fmaf(vs, hi[0], a2);
      a3 = fmaf(vs, hi[1], a3);
    }
    if (g == 3) {   // after j<32: first decode's loss/mean contribution
      float d0 = a0 + s4.x, d1 = a1 + s4.y, d2 = a2 + s4.z, d3 = a3 + s4.w;
      float e0 = m4.x - d0, e1 = m4.y - d1, e2 = m4.z - d2, e3 = m4.w - d3;
      l1 = e0 * e0 + e1 * e1 + e2 * e2 + e3 * e3;
      dsum = d0 + d1 + d2 + d3;
    }
  }
  float d0 = a0 + s4.x, d1 = a1 + s4.y, d2 = a2 + s4.z, d3 = a3 + s4.w;
  float e0 = m4.x - d0, e1 = m4.y - d1, e2 = m4.z - d2, e3 = m4.w - d3;
  float l2 = e0 * e0 + e1 * e1 + e2 * e2 + e3 * e3;
  dsum += d0 + d1 + d2 + d3;

  double r0 = (double)l1, r1 = (double)l2, r2 = (double)dsum;
  for (int o = 32; o > 0; o >>= 1) {
    r0 += __shfl_down(r0, o);
    r1 += __shfl_down(r1, o);
    r2 += __shfl_down(r2, o);
  }
  const int w = tid >> 6;
  if ((tid & 63) == 0) { wred[w][0] = r0; wred[w][1] = r1; wred[w][2] = r2; }
  __syncthreads();
  if (tid == 0) {
    double t0 = 0, t1 = 0, t2 = 0;
    for (int i = 0; i < 3; ++i) { t0 += wred[i][0]; t1 += wred[i][1]; t2 += wred[i][2]; }
    atomicAdd(&accs[3], t0);
    atomicAdd(&accs[4], t1);
    atomicAdd(&accs[2], t2);
  }
}

// ---------------- finalize ----------------
__global__ __launch_bounds__(256) void finalize_kernel(const double* __restrict__ accs,
                                                       const float* __restrict__ colsum,
                                                       float* __restrict__ out) {
  __shared__ double wred[4];
  const int tid = threadIdx.x;
  double c2 = 0.0;
  for (int i = tid; i < 768; i += 256) { double c = (double)colsum[i]; c2 += c * c; }
  for (int o = 32; o > 0; o >>= 1) c2 += __shfl_down(c2, o);
  if ((tid & 63) == 0) wred[tid >> 6] = c2;
  __syncthreads();
  if (tid == 0) {
    double csq = wred[0] + wred[1] + wred[2] + wred[3];
    double tv = accs[5] - csq / 8192.0;
    out[0] = (float)((accs[0] + accs[1]) / (8192.0 * 12288.0));
    out[1] = (float)(accs[2] / (8192.0 * 768.0));
    out[2] = (float)(accs[3] / tv + accs[4] / (8.0 * tv));
  }
}

extern "C" void kernel_launch(void* const* d_in, const int* in_sizes, int n_in,
                              void* d_out, int out_size, void* d_ws, size_t ws_size,
                              hipStream_t stream) {
  const float* x    = (const float*)d_in[0];
  const float* mlp  = (const float*)d_in[1];
  const float* Wenc = (const float*)d_in[2];
  const float* benc = (const float*)d_in[3];
  const float* Wdec = (const float*)d_in[4];
  const float* bdec = (const float*)d_in[5];
  const float* Wskip= (const float*)d_in[6];

  char* ws = (char*)d_ws;
  const size_t OFF_COL  = 1024;
  const size_t OFF_XBF  = 8192;
  const size_t OFF_WENC = OFF_XBF  + (size_t)8192 * 768 * 2;
  const size_t OFF_WSK  = OFF_WENC + (size_t)12288 * 768 * 2;
  const size_t OFF_SKIP = OFF_WSK  + (size_t)768 * 768 * 2;
  const size_t OFF_TIDX = OFF_SKIP + (size_t)8192 * 768 * 4;
  const size_t OFF_TVAL = OFF_TIDX + (size_t)8192 * 128 * 4;
  const size_t OFF_PRE  = OFF_TVAL + (size_t)8192 * 128 * 4;

  double*   accs   = (double*)ws;
  float*    colsum = (float*)(ws + OFF_COL);
  ushort_t* xbf    = (ushort_t*)(ws + OFF_XBF);
  ushort_t* wencbf = (ushort_t*)(ws + OFF_WENC);  // reused for fp8 W_dec after enc GEMM
  ushort_t* wskT   = (ushort_t*)(ws + OFF_WSK);
  float*    skip   = (float*)(ws + OFF_SKIP);
  int*      tidx   = (int*)(ws + OFF_TIDX);
  float*    tval   = (float*)(ws + OFF_TVAL);
  ushort_t* pre    = (ushort_t*)(ws + OFF_PRE);

  (void)hipMemsetAsync(d_ws, 0, 8192, stream);

  prep_x<<<256, 256, 0, stream>>>(x, xbf, colsum, accs);
  conv_bf16<<<(12288 * 768 / 4) / 256, 256, 0, stream>>>(Wenc, wencbf, 12288 * 768);
  conv_skipT<<<dim3(3, 768), 256, 0, stream>>>(Wskip, wskT);

  gemm_bt<true><<<dim3(96, 64), 256, 0, stream>>>(xbf, wencbf, (void*)pre, benc, 768, 12288);
  gemm_bt<false><<<dim3(6, 64), 256, 0, stream>>>(xbf, wskT, (void*)skip, bdec, 768, 768);

  // W_enc staging buffer is dead now -> reuse it for fp8 W_dec (stream-ordered)
  uint_t* wdec8 = (uint_t*)wencbf;
  conv_fp8<<<(12288 * 768 / 4 + 255) / 256, 256, 0, stream>>>(Wdec, wdec8, 12288 * 768 / 4);

  topk_kernel<<<8192, 256, 0, stream>>>(pre, tidx, tval, accs);
  decode_loss<<<8192, 192, 0, stream>>>(tidx, tval, skip, mlp, wdec8, accs);
  finalize_kernel<<<1, 256, 0, stream>>>(accs, colsum, (float*)d_out);
}

// Round 7
// 529.896 us; speedup vs baseline: 2.0012x; 1.5984x over previous
//
#include <hip/hip_runtime.h>

typedef unsigned short ushort_t;
typedef unsigned int uint_t;

typedef __attribute__((ext_vector_type(8))) short bf16x8;
typedef __attribute__((ext_vector_type(4))) float f32x4;
typedef __attribute__((ext_vector_type(2))) float f32x2;

#define GLOAD16(g, l) __builtin_amdgcn_global_load_lds( \
    (const __attribute__((address_space(1))) unsigned int*)(g), \
    (__attribute__((address_space(3))) unsigned int*)(l), 16, 0, 0)

__device__ __forceinline__ ushort_t f2bf(float f) {
  union { float f; uint_t u; } c; c.f = f;
  uint_t u = c.u;
  return (ushort_t)((u + 0x7FFFu + ((u >> 16) & 1u)) >> 16);
}

// ---------------- prep: x -> bf16, colsum, sumsq ----------------
__global__ __launch_bounds__(256) void prep_x(const float* __restrict__ x,
                                              ushort_t* __restrict__ xbf,
                                              float* __restrict__ colsum,
                                              double* __restrict__ accs) {
  const int tid = threadIdx.x;
  const int r0 = blockIdx.x * 32;
  float cs0 = 0.f, cs1 = 0.f, cs2 = 0.f;
  double ss = 0.0;
  for (int r = 0; r < 32; ++r) {
    const float* xr = x + (size_t)(r0 + r) * 768;
    ushort_t* xo = xbf + (size_t)(r0 + r) * 768;
    float v0 = xr[tid], v1 = xr[tid + 256], v2 = xr[tid + 512];
    xo[tid] = f2bf(v0); xo[tid + 256] = f2bf(v1); xo[tid + 512] = f2bf(v2);
    cs0 += v0; cs1 += v1; cs2 += v2;
    ss += (double)v0 * v0 + (double)v1 * v1 + (double)v2 * v2;
  }
  atomicAdd(&colsum[tid], cs0);
  atomicAdd(&colsum[tid + 256], cs1);
  atomicAdd(&colsum[tid + 512], cs2);
  for (int o = 32; o > 0; o >>= 1) ss += __shfl_down(ss, o);
  __shared__ double wsum[4];
  if ((tid & 63) == 0) wsum[tid >> 6] = ss;
  __syncthreads();
  if (tid == 0) atomicAdd(&accs[5], wsum[0] + wsum[1] + wsum[2] + wsum[3]);
}

// ---------------- generic f32 -> bf16 convert ----------------
__global__ __launch_bounds__(256) void conv_bf16(const float* __restrict__ in,
                                                 ushort_t* __restrict__ out, int n) {
  int i = (blockIdx.x * 256 + threadIdx.x) * 4;
  if (i + 3 < n) {
    float4 v = *(const float4*)(in + i);
    uint_t a = (uint_t)f2bf(v.x) | ((uint_t)f2bf(v.y) << 16);
    uint_t b = (uint_t)f2bf(v.z) | ((uint_t)f2bf(v.w) << 16);
    *(uint2*)(out + i) = make_uint2(a, b);
  }
}

// ---------------- W_dec f32 -> fp8 e4m3 (x16 scale), 4 cols per uint ----------------
__global__ __launch_bounds__(256) void conv_fp8(const float* __restrict__ in,
                                                uint_t* __restrict__ out, int n4) {
  int i = blockIdx.x * 256 + threadIdx.x;
  if (i < n4) {
    float4 v = ((const float4*)in)[i];
    int w = 0;
    w = __builtin_amdgcn_cvt_pk_fp8_f32(v.x * 16.f, v.y * 16.f, w, false);
    w = __builtin_amdgcn_cvt_pk_fp8_f32(v.z * 16.f, v.w * 16.f, w, true);
    out[i] = (uint_t)w;
  }
}

// ---------------- W_skip transpose -> bf16 [D][K] ----------------
__global__ __launch_bounds__(256) void conv_skipT(const float* __restrict__ in,
                                                  ushort_t* __restrict__ out) {
  int d = blockIdx.x * 256 + threadIdx.x;   // 0..767
  int k = blockIdx.y;                        // 0..767
  if (d < 768) out[(size_t)d * 768 + k] = f2bf(in[(size_t)k * 768 + d]);
}

// ---------------- bf16 GEMM: C[M,N] = A[M,K] * B[N,K]^T + bias ----------------
template <bool BF16_OUT>
__global__ __launch_bounds__(256) void gemm_bt(const ushort_t* __restrict__ Ag,
                                               const ushort_t* __restrict__ Bg,
                                               void* __restrict__ Cg,
                                               const float* __restrict__ bias,
                                               int K, int ldc) {
  __shared__ __align__(16) char smem[34816];
  const int tid = threadIdx.x;
  const int lane = tid & 63, wid = tid >> 6;
  const int wr = wid >> 1, wc = wid & 1;
  const int lo = lane & 15, hi = lane >> 4;
  const int arow0 = blockIdx.y * 128, brow0 = blockIdx.x * 128;

  const int rr0 = (lane >> 2);
  const int kb = (lane & 3) * 8;

  f32x4 acc[4][4] = {};
  const int NT = K >> 5;

  for (int c = 0; c < 2; ++c) {
    int rr = (wid * 2 + c) * 16 + rr0;
    GLOAD16(Ag + (size_t)(arow0 + rr) * K + kb, smem + (wid * 2 + c) * 1024);
    GLOAD16(Bg + (size_t)(brow0 + rr) * K + kb, smem + 16384 + (wid * 2 + c) * 1024);
  }
  __syncthreads();

  for (int kt = 0; kt < NT; ++kt) {
    const int cur = (kt & 1) * 8192;
    const int nxt = 8192 - cur;
    if (kt + 1 < NT) {
      const int k0 = (kt + 1) << 5;
      for (int c = 0; c < 2; ++c) {
        int rr = (wid * 2 + c) * 16 + rr0;
        GLOAD16(Ag + (size_t)(arow0 + rr) * K + k0 + kb, smem + nxt + (wid * 2 + c) * 1024);
        GLOAD16(Bg + (size_t)(brow0 + rr) * K + k0 + kb, smem + 16384 + nxt + (wid * 2 + c) * 1024);
      }
    }
    const char* As = smem + cur;
    const char* Bs = smem + 16384 + cur;
    bf16x8 af[4], bfr[4];
#pragma unroll
    for (int m = 0; m < 4; ++m)
      af[m] = *(const bf16x8*)(As + ((wr * 64 + m * 16 + lo) * 64 + hi * 16));
#pragma unroll
    for (int n = 0; n < 4; ++n)
      bfr[n] = *(const bf16x8*)(Bs + ((wc * 64 + n * 16 + lo) * 64 + hi * 16));
#pragma unroll
    for (int m = 0; m < 4; ++m)
#pragma unroll
      for (int n = 0; n < 4; ++n)
        acc[m][n] = __builtin_amdgcn_mfma_f32_16x16x32_bf16(af[m], bfr[n], acc[m][n], 0, 0, 0);
    __syncthreads();
  }

  if (BF16_OUT) {
    ushort_t* ot = (ushort_t*)smem;
#pragma unroll
    for (int n = 0; n < 4; ++n) {
      const int col = wc * 64 + n * 16 + lo;
      const float bv = bias[brow0 + col];
#pragma unroll
      for (int m = 0; m < 4; ++m) {
#pragma unroll
        for (int r = 0; r < 4; ++r) {
          const int row = wr * 64 + m * 16 + hi * 4 + r;
          ot[row * 136 + col] = f2bf(acc[m][n][r] + bv);
        }
      }
    }
    __syncthreads();
    ushort_t* C = (ushort_t*)Cg;
    const int cc = tid & 15;
#pragma unroll
    for (int p = 0; p < 8; ++p) {
      const int row = p * 16 + (tid >> 4);
      ushort_t* dst = C + (size_t)(arow0 + row) * (size_t)ldc + brow0 + cc * 8;
      *(uint4*)dst = *(const uint4*)(ot + row * 136 + cc * 8);
    }
  } else {
    float* C = (float*)Cg;
#pragma unroll
    for (int n = 0; n < 4; ++n) {
      const int col = wc * 64 + n * 16 + lo;
      const float bv = bias[brow0 + col];
#pragma unroll
      for (int m = 0; m < 4; ++m) {
#pragma unroll
        for (int r = 0; r < 4; ++r) {
          const int row = wr * 64 + m * 16 + hi * 4 + r;
          C[(size_t)(arow0 + row) * (size_t)ldc + brow0 + col] = acc[m][n][r] + bv;
        }
      }
    }
  }
}

// ---------------- top-k: exact top-32/top-128 sets via histogram select ----------------
#define EIDX(c, h) ((uint_t)(((c) >> 2) * 2048 + tid * 8 + (((c) & 3) << 1) + (h)))
#define HW(b) (((b) >> 4) * 17 + ((b) & 15))
__global__ __launch_bounds__(256) void topk_kernel(const ushort_t* __restrict__ pre,
                                                   int* __restrict__ oidx,
                                                   float* __restrict__ oval,
                                                   double* __restrict__ pS1,
                                                   double* __restrict__ pS2) {
  __shared__ uint_t hist[4352];          // 256 chunks x 17 (16 bins + pad)
  __shared__ uint_t sub32[16], sub128[16];
  __shared__ uint_t list32[64], list128[64];
  __shared__ uint_t wtot[4];
  __shared__ int ctl[16];
  __shared__ float fred[8];
  const int tid = threadIdx.x;
  const int lane = tid & 63, wid = tid >> 6;
  const size_t row = blockIdx.x;
  const uint4* pr4 = (const uint4*)(pre + row * 12288);

  for (int i = tid; i < 4352; i += 256) hist[i] = 0;
  if (tid < 16) { sub32[tid] = 0; sub128[tid] = 0; ctl[tid] = 0; }
  __syncthreads();

  // pass 1: load row (uint4), monotone key transform, histogram
  uint_t k2[24];
#pragma unroll
  for (int i = 0; i < 6; ++i) {
    uint4 q = pr4[i * 256 + tid];
    uint_t qq[4] = { q.x, q.y, q.z, q.w };
#pragma unroll
    for (int w = 0; w < 4; ++w) {
      uint_t u2 = qq[w];
      uint_t lo16 = u2 & 0xFFFFu, hi16 = u2 >> 16;
      uint_t klo = (lo16 & 0x8000u) ? (~lo16 & 0xFFFFu) : (lo16 | 0x8000u);
      uint_t khi = (hi16 & 0x8000u) ? (~hi16 & 0xFFFFu) : (hi16 | 0x8000u);
      k2[i * 4 + w] = klo | (khi << 16);
      atomicAdd(&hist[HW(klo >> 4)], 1u);
      atomicAdd(&hist[HW(khi >> 4)], 1u);
    }
  }
  __syncthreads();

  // chunk sums + wave suffix scan
  uint_t cs = 0;
#pragma unroll
  for (int b = 0; b < 16; ++b) cs += hist[tid * 17 + b];
  uint_t s = cs;
#pragma unroll
  for (int off = 1; off < 64; off <<= 1) {
    uint_t v = (uint_t)__shfl_down((int)s, off);
    if (lane + off < 64) s += v;
  }
  if (lane == 0) wtot[wid] = s;
  __syncthreads();
  uint_t above = 0;
  for (int w = wid + 1; w < 4; ++w) above += wtot[w];
  const uint_t Sg = s + above;
  const uint_t Snx = Sg - cs;
#pragma unroll
  for (int which = 0; which < 2; ++which) {
    const uint_t K = which ? 128u : 32u;
    if (Sg >= K && Snx < K) {
      uint_t running = Snx;
      for (int b = 15; b >= 0; --b) {
        uint_t c = hist[tid * 17 + b];
        if (running + c >= K) { ctl[which * 2] = tid * 16 + b; ctl[which * 2 + 1] = (int)running; break; }
        running += c;
      }
    }
  }
  __syncthreads();
  const uint_t b32 = (uint_t)ctl[0], b128 = (uint_t)ctl[2];

  // pass 2 (regs): sub-histogram over low 4 key bits of the threshold bins
#pragma unroll
  for (int c = 0; c < 24; ++c) {
    uint_t kk = k2[c];
#pragma unroll
    for (int h = 0; h < 2; ++h) {
      uint_t key = (h ? (kk >> 16) : kk) & 0xFFFFu;
      uint_t bin = key >> 4;
      if (bin == b32) atomicAdd(&sub32[key & 15], 1u);
      if (bin == b128) atomicAdd(&sub128[key & 15], 1u);
    }
  }
  __syncthreads();

  // exact 16-bit key threshold + tie count r
  if (tid < 2) {
    const uint_t* sub = tid ? sub128 : sub32;
    const uint_t K = tid ? 128u : 32u;
    const uint_t chi = (uint_t)ctl[tid * 2 + 1];
    const uint_t bK = (uint_t)ctl[tid * 2];
    const uint_t need = K - chi;
    uint_t running = 0;
    for (int sb = 15; sb >= 0; --sb) {
      uint_t c = sub[sb];
      if (running + c >= need) {
        ctl[4 + tid * 2] = (int)((bK << 4) | (uint_t)sb);
        ctl[5 + tid * 2] = (int)(need - running);
        break;
      }
      running += c;
    }
  }
  __syncthreads();
  const uint_t kt32 = (uint_t)ctl[4], kt128 = (uint_t)ctl[6];

  // pass 3 (regs): collect indices tied at the exact threshold key
#pragma unroll
  for (int c = 0; c < 24; ++c) {
    uint_t kk = k2[c];
#pragma unroll
    for (int h = 0; h < 2; ++h) {
      uint_t key = (h ? (kk >> 16) : kk) & 0xFFFFu;
      uint_t idx = EIDX(c, h);
      if (key == kt32) {
        uint_t p = atomicAdd((uint_t*)&ctl[8], 1u);
        if (p < 64) list32[p] = idx;
      }
      if (key == kt128) {
        uint_t p = atomicAdd((uint_t*)&ctl[9], 1u);
        if (p < 64) list128[p] = idx;
      }
    }
  }
  __syncthreads();

  // waves 0/1: in-wave bitonic sort of tie indices, pick r-th smallest
  if (wid < 2) {
    const int n = min(ctl[8 + wid], 64);
    const int r = ctl[5 + wid * 2];
    uint_t v = (lane < n) ? (wid ? list128[lane] : list32[lane]) : 0xFFFFFFFFu;
#pragma unroll
    for (int k = 2; k <= 64; k <<= 1) {
#pragma unroll
      for (int j = k >> 1; j > 0; j >>= 1) {
        uint_t p = (uint_t)__shfl_xor((int)v, j);
        bool asc = ((lane & k) == 0);
        bool lower = ((lane & j) == 0);
        v = (asc == lower) ? min(v, p) : max(v, p);
      }
    }
    uint_t idxt = (uint_t)__shfl((int)v, r - 1);
    if (lane == 0) ctl[10 + wid] = (int)idxt;
  }
  __syncthreads();
  const uint_t idxt32 = (uint_t)ctl[10], idxt128 = (uint_t)ctl[11];

  // pass 4 (regs): exact membership, write sets, accumulate sums
  float s1 = 0.f, s2 = 0.f;
  int* rowIdx = oidx + row * 128;
  float* rowVal = oval + row * 128;
#pragma unroll
  for (int c = 0; c < 24; ++c) {
    uint_t kk = k2[c];
#pragma unroll
    for (int h = 0; h < 2; ++h) {
      uint_t key = (h ? (kk >> 16) : kk) & 0xFFFFu;
      uint_t idx = EIDX(c, h);
      bool in32 = (key > kt32) || (key == kt32 && idx <= idxt32);
      bool in128 = (key > kt128) || (key == kt128 && idx <= idxt128);
      if (in128) {
        uint_t ub = (key & 0x8000u) ? (key & 0x7FFFu) : (~key & 0xFFFFu);
        float v = fmaxf(__uint_as_float(ub << 16), 0.f);
        int slot;
        if (in32) { slot = (int)atomicAdd((uint_t*)&ctl[12], 1u); s1 += v; }
        else      { slot = 32 + (int)atomicAdd((uint_t*)&ctl[13], 1u); }
        s2 += v;
        rowIdx[slot] = (int)idx;
        rowVal[slot] = v;
      }
    }
  }
  for (int o = 32; o > 0; o >>= 1) { s1 += __shfl_down(s1, o); s2 += __shfl_down(s2, o); }
  if (lane == 0) { fred[wid] = s1; fred[4 + wid] = s2; }
  __syncthreads();
  if (tid == 0) {
    pS1[row] = (double)(fred[0] + fred[1] + fred[2] + fred[3]);
    pS2[row] = (double)(fred[4] + fred[5] + fred[6] + fred[7]);
  }
}

// ---------------- sparse decode + loss + means (fp8 W_dec, x16 scale) ----------------
__global__ __launch_bounds__(192) void decode_loss(const int* __restrict__ oidx,
                                                   const float* __restrict__ oval,
                                                   const float* __restrict__ skip,
                                                   const float* __restrict__ mlp,
                                                   const uint_t* __restrict__ Wd8,
                                                   double* __restrict__ pL1,
                                                   double* __restrict__ pL2,
                                                   double* __restrict__ pDS) {
  __shared__ int lidx[128];
  __shared__ float lval[128];
  __shared__ double wred[3][3];
  const int tid = threadIdx.x;
  const size_t row = blockIdx.x;
  if (tid < 128) {
    lidx[tid] = oidx[row * 128 + tid];
    lval[tid] = oval[row * 128 + tid];
  }
  __syncthreads();
  const float4 s4 = ((const float4*)(skip + row * 768))[tid];
  const float4 m4 = ((const float4*)(mlp + row * 768))[tid];
  const uint_t* Wt = Wd8 + tid;
  float a0 = 0.f, a1 = 0.f, a2 = 0.f, a3 = 0.f;
  float l1 = 0.f, dsum = 0.f;

#pragma unroll 1
  for (int g = 0; g < 16; ++g) {
    uint_t wb[8];
    float vv[8];
#pragma unroll
    for (int b = 0; b < 8; ++b) {
      wb[b] = Wt[(size_t)lidx[g * 8 + b] * 192];
      vv[b] = lval[g * 8 + b];
    }
#pragma unroll
    for (int b = 0; b < 8; ++b) {
      const float vs = vv[b] * 0.0625f;
      f32x2 lo = __builtin_amdgcn_cvt_pk_f32_fp8(wb[b], false);
      f32x2 hi = __builtin_amdgcn_cvt_pk_f32_fp8(wb[b], true);
      a0 = fmaf(vs, lo[0], a0);
      a1 = fmaf(vs, lo[1], a1);
      a2 = fmaf(vs, hi[0], a2);
      a3 = fmaf(vs, hi[1], a3);
    }
    if (g == 3) {   // after j<32: first decode's loss/mean contribution
      float d0 = a0 + s4.x, d1 = a1 + s4.y, d2 = a2 + s4.z, d3 = a3 + s4.w;
      float e0 = m4.x - d0, e1 = m4.y - d1, e2 = m4.z - d2, e3 = m4.w - d3;
      l1 = e0 * e0 + e1 * e1 + e2 * e2 + e3 * e3;
      dsum = d0 + d1 + d2 + d3;
    }
  }
  float d0 = a0 + s4.x, d1 = a1 + s4.y, d2 = a2 + s4.z, d3 = a3 + s4.w;
  float e0 = m4.x - d0, e1 = m4.y - d1, e2 = m4.z - d2, e3 = m4.w - d3;
  float l2 = e0 * e0 + e1 * e1 + e2 * e2 + e3 * e3;
  dsum += d0 + d1 + d2 + d3;

  double r0 = (double)l1, r1 = (double)l2, r2 = (double)dsum;
  for (int o = 32; o > 0; o >>= 1) {
    r0 += __shfl_down(r0, o);
    r1 += __shfl_down(r1, o);
    r2 += __shfl_down(r2, o);
  }
  const int w = tid >> 6;
  if ((tid & 63) == 0) { wred[w][0] = r0; wred[w][1] = r1; wred[w][2] = r2; }
  __syncthreads();
  if (tid == 0) {
    pL1[row] = wred[0][0] + wred[1][0] + wred[2][0];
    pL2[row] = wred[0][1] + wred[1][1] + wred[2][1];
    pDS[row] = wred[0][2] + wred[1][2] + wred[2][2];
  }
}

// ---------------- finalize: reduce per-block partials ----------------
__global__ __launch_bounds__(256) void finalize_kernel(const double* __restrict__ accs,
                                                       const float* __restrict__ colsum,
                                                       const double* __restrict__ pL1,
                                                       const double* __restrict__ pL2,
                                                       const double* __restrict__ pDS,
                                                       const double* __restrict__ pS1,
                                                       const double* __restrict__ pS2,
                                                       float* __restrict__ out) {
  __shared__ double wred[4][6];
  const int tid = threadIdx.x;
  const int lane = tid & 63, wid = tid >> 6;
  double aL1 = 0, aL2 = 0, aDS = 0, aS1 = 0, aS2 = 0;
  for (int i = tid; i < 8192; i += 256) {
    aL1 += pL1[i]; aL2 += pL2[i]; aDS += pDS[i]; aS1 += pS1[i]; aS2 += pS2[i];
  }
  double c2 = 0.0;
  for (int i = tid; i < 768; i += 256) { double c = (double)colsum[i]; c2 += c * c; }
  for (int o = 32; o > 0; o >>= 1) {
    aL1 += __shfl_down(aL1, o);
    aL2 += __shfl_down(aL2, o);
    aDS += __shfl_down(aDS, o);
    aS1 += __shfl_down(aS1, o);
    aS2 += __shfl_down(aS2, o);
    c2  += __shfl_down(c2, o);
  }
  if (lane == 0) {
    wred[wid][0] = aL1; wred[wid][1] = aL2; wred[wid][2] = aDS;
    wred[wid][3] = aS1; wred[wid][4] = aS2; wred[wid][5] = c2;
  }
  __syncthreads();
  if (tid == 0) {
    double tL1 = 0, tL2 = 0, tDS = 0, tS1 = 0, tS2 = 0, csq = 0;
    for (int i = 0; i < 4; ++i) {
      tL1 += wred[i][0]; tL2 += wred[i][1]; tDS += wred[i][2];
      tS1 += wred[i][3]; tS2 += wred[i][4]; csq += wred[i][5];
    }
    double tv = accs[5] - csq / 8192.0;
    out[0] = (float)((tS1 + tS2) / (8192.0 * 12288.0));
    out[1] = (float)(tDS / (8192.0 * 768.0));
    out[2] = (float)(tL1 / tv + tL2 / (8.0 * tv));
  }
}

extern "C" void kernel_launch(void* const* d_in, const int* in_sizes, int n_in,
                              void* d_out, int out_size, void* d_ws, size_t ws_size,
                              hipStream_t stream) {
  const float* x    = (const float*)d_in[0];
  const float* mlp  = (const float*)d_in[1];
  const float* Wenc = (const float*)d_in[2];
  const float* benc = (const float*)d_in[3];
  const float* Wdec = (const float*)d_in[4];
  const float* bdec = (const float*)d_in[5];
  const float* Wskip= (const float*)d_in[6];

  char* ws = (char*)d_ws;
  const size_t OFF_COL  = 1024;
  const size_t OFF_XBF  = 8192;
  const size_t OFF_WENC = OFF_XBF  + (size_t)8192 * 768 * 2;
  const size_t OFF_WSK  = OFF_WENC + (size_t)12288 * 768 * 2;
  const size_t OFF_SKIP = OFF_WSK  + (size_t)768 * 768 * 2;
  const size_t OFF_TIDX = OFF_SKIP + (size_t)8192 * 768 * 4;
  const size_t OFF_TVAL = OFF_TIDX + (size_t)8192 * 128 * 4;
  const size_t OFF_PRE  = OFF_TVAL + (size_t)8192 * 128 * 4;

  double*   accs   = (double*)ws;
  float*    colsum = (float*)(ws + OFF_COL);
  ushort_t* xbf    = (ushort_t*)(ws + OFF_XBF);
  ushort_t* wencbf = (ushort_t*)(ws + OFF_WENC);  // reused for fp8 W_dec after enc GEMM
  ushort_t* wskT   = (ushort_t*)(ws + OFF_WSK);
  float*    skip   = (float*)(ws + OFF_SKIP);
  int*      tidx   = (int*)(ws + OFF_TIDX);
  float*    tval   = (float*)(ws + OFF_TVAL);
  ushort_t* pre    = (ushort_t*)(ws + OFF_PRE);

  // per-block partial arrays: reuse the xbf region (dead after both GEMMs)
  double* pL1 = (double*)(ws + OFF_XBF);
  double* pL2 = pL1 + 8192;
  double* pDS = pL1 + 16384;
  double* pS1 = pL1 + 24576;
  double* pS2 = pL1 + 32768;

  (void)hipMemsetAsync(d_ws, 0, 8192, stream);

  prep_x<<<256, 256, 0, stream>>>(x, xbf, colsum, accs);
  conv_bf16<<<(12288 * 768 / 4) / 256, 256, 0, stream>>>(Wenc, wencbf, 12288 * 768);
  conv_skipT<<<dim3(3, 768), 256, 0, stream>>>(Wskip, wskT);

  gemm_bt<true><<<dim3(96, 64), 256, 0, stream>>>(xbf, wencbf, (void*)pre, benc, 768, 12288);
  gemm_bt<false><<<dim3(6, 64), 256, 0, stream>>>(xbf, wskT, (void*)skip, bdec, 768, 768);

  // W_enc staging buffer is dead now -> reuse it for fp8 W_dec (stream-ordered)
  uint_t* wdec8 = (uint_t*)wencbf;
  conv_fp8<<<(12288 * 768 / 4 + 255) / 256, 256, 0, stream>>>(Wdec, wdec8, 12288 * 768 / 4);

  topk_kernel<<<8192, 256, 0, stream>>>(pre, tidx, tval, pS1, pS2);
  decode_loss<<<8192, 192, 0, stream>>>(tidx, tval, skip, mlp, wdec8, pL1, pL2, pDS);
  finalize_kernel<<<1, 256, 0, stream>>>(accs, colsum, pL1, pL2, pDS, pS1, pS2, (float*)d_out);
}

// Round 8
// 504.801 us; speedup vs baseline: 2.1007x; 1.0497x over previous
//
#include <hip/hip_runtime.h>

typedef unsigned short ushort_t;
typedef unsigned int uint_t;

typedef __attribute__((ext_vector_type(8))) short bf16x8;
typedef __attribute__((ext_vector_type(4))) float f32x4;
typedef __attribute__((ext_vector_type(2))) float f32x2;

#define GLOAD16(g, l) __builtin_amdgcn_global_load_lds( \
    (const __attribute__((address_space(1))) unsigned int*)(g), \
    (__attribute__((address_space(3))) unsigned int*)(l), 16, 0, 0)

#define VMCNT4 asm volatile("s_waitcnt vmcnt(4)" ::: "memory")
#define VMCNT2 asm volatile("s_waitcnt vmcnt(2)" ::: "memory")
#define VMCNT0 asm volatile("s_waitcnt vmcnt(0)" ::: "memory")
#define LGKM0  asm volatile("s_waitcnt lgkmcnt(0)" ::: "memory")
#define BARX   __builtin_amdgcn_s_barrier()

__device__ __forceinline__ ushort_t f2bf(float f) {
  union { float f; uint_t u; } c; c.f = f;
  uint_t u = c.u;
  return (ushort_t)((u + 0x7FFFu + ((u >> 16) & 1u)) >> 16);
}

// ---------------- prep: x -> bf16, colsum, sumsq ----------------
__global__ __launch_bounds__(256) void prep_x(const float* __restrict__ x,
                                              ushort_t* __restrict__ xbf,
                                              float* __restrict__ colsum,
                                              double* __restrict__ accs) {
  const int tid = threadIdx.x;
  const int r0 = blockIdx.x * 32;
  float cs0 = 0.f, cs1 = 0.f, cs2 = 0.f;
  double ss = 0.0;
  for (int r = 0; r < 32; ++r) {
    const float* xr = x + (size_t)(r0 + r) * 768;
    ushort_t* xo = xbf + (size_t)(r0 + r) * 768;
    float v0 = xr[tid], v1 = xr[tid + 256], v2 = xr[tid + 512];
    xo[tid] = f2bf(v0); xo[tid + 256] = f2bf(v1); xo[tid + 512] = f2bf(v2);
    cs0 += v0; cs1 += v1; cs2 += v2;
    ss += (double)v0 * v0 + (double)v1 * v1 + (double)v2 * v2;
  }
  atomicAdd(&colsum[tid], cs0);
  atomicAdd(&colsum[tid + 256], cs1);
  atomicAdd(&colsum[tid + 512], cs2);
  for (int o = 32; o > 0; o >>= 1) ss += __shfl_down(ss, o);
  __shared__ double wsum[4];
  if ((tid & 63) == 0) wsum[tid >> 6] = ss;
  __syncthreads();
  if (tid == 0) atomicAdd(&accs[5], wsum[0] + wsum[1] + wsum[2] + wsum[3]);
}

// ---------------- generic f32 -> bf16 convert ----------------
__global__ __launch_bounds__(256) void conv_bf16(const float* __restrict__ in,
                                                 ushort_t* __restrict__ out, int n) {
  int i = (blockIdx.x * 256 + threadIdx.x) * 4;
  if (i + 3 < n) {
    float4 v = *(const float4*)(in + i);
    uint_t a = (uint_t)f2bf(v.x) | ((uint_t)f2bf(v.y) << 16);
    uint_t b = (uint_t)f2bf(v.z) | ((uint_t)f2bf(v.w) << 16);
    *(uint2*)(out + i) = make_uint2(a, b);
  }
}

// ---------------- W_dec f32 -> fp8 e4m3 (x16 scale), 4 cols per uint ----------------
__global__ __launch_bounds__(256) void conv_fp8(const float* __restrict__ in,
                                                uint_t* __restrict__ out, int n4) {
  int i = blockIdx.x * 256 + threadIdx.x;
  if (i < n4) {
    float4 v = ((const float4*)in)[i];
    int w = 0;
    w = __builtin_amdgcn_cvt_pk_fp8_f32(v.x * 16.f, v.y * 16.f, w, false);
    w = __builtin_amdgcn_cvt_pk_fp8_f32(v.z * 16.f, v.w * 16.f, w, true);
    out[i] = (uint_t)w;
  }
}

// ---------------- W_skip transpose -> bf16 [D][K] ----------------
__global__ __launch_bounds__(256) void conv_skipT(const float* __restrict__ in,
                                                  ushort_t* __restrict__ out) {
  int d = blockIdx.x * 256 + threadIdx.x;
  int k = blockIdx.y;
  if (d < 768) out[(size_t)d * 768 + k] = f2bf(in[(size_t)k * 768 + d]);
}

// ---------------- small bf16 GEMM (skip path): m97 structure ----------------
__global__ __launch_bounds__(256) void gemm_bt(const ushort_t* __restrict__ Ag,
                                               const ushort_t* __restrict__ Bg,
                                               float* __restrict__ Cg,
                                               const float* __restrict__ bias,
                                               int K, int ldc) {
  __shared__ __align__(16) char smem[34816];
  const int tid = threadIdx.x;
  const int lane = tid & 63, wid = tid >> 6;
  const int wr = wid >> 1, wc = wid & 1;
  const int lo = lane & 15, hi = lane >> 4;
  const int arow0 = blockIdx.y * 128, brow0 = blockIdx.x * 128;
  const int rr0 = (lane >> 2);
  const int kb = (lane & 3) * 8;
  f32x4 acc[4][4] = {};
  const int NT = K >> 5;
  for (int c = 0; c < 2; ++c) {
    int rr = (wid * 2 + c) * 16 + rr0;
    GLOAD16(Ag + (size_t)(arow0 + rr) * K + kb, smem + (wid * 2 + c) * 1024);
    GLOAD16(Bg + (size_t)(brow0 + rr) * K + kb, smem + 16384 + (wid * 2 + c) * 1024);
  }
  __syncthreads();
  for (int kt = 0; kt < NT; ++kt) {
    const int cur = (kt & 1) * 8192;
    const int nxt = 8192 - cur;
    if (kt + 1 < NT) {
      const int k0 = (kt + 1) << 5;
      for (int c = 0; c < 2; ++c) {
        int rr = (wid * 2 + c) * 16 + rr0;
        GLOAD16(Ag + (size_t)(arow0 + rr) * K + k0 + kb, smem + nxt + (wid * 2 + c) * 1024);
        GLOAD16(Bg + (size_t)(brow0 + rr) * K + k0 + kb, smem + 16384 + nxt + (wid * 2 + c) * 1024);
      }
    }
    const char* As = smem + cur;
    const char* Bs = smem + 16384 + cur;
    bf16x8 af[4], bfr[4];
#pragma unroll
    for (int m = 0; m < 4; ++m)
      af[m] = *(const bf16x8*)(As + ((wr * 64 + m * 16 + lo) * 64 + hi * 16));
#pragma unroll
    for (int n = 0; n < 4; ++n)
      bfr[n] = *(const bf16x8*)(Bs + ((wc * 64 + n * 16 + lo) * 64 + hi * 16));
#pragma unroll
    for (int m = 0; m < 4; ++m)
#pragma unroll
      for (int n = 0; n < 4; ++n)
        acc[m][n] = __builtin_amdgcn_mfma_f32_16x16x32_bf16(af[m], bfr[n], acc[m][n], 0, 0, 0);
    __syncthreads();
  }
#pragma unroll
  for (int n = 0; n < 4; ++n) {
    const int col = wc * 64 + n * 16 + lo;
    const float bv = bias[brow0 + col];
#pragma unroll
    for (int m = 0; m < 4; ++m)
#pragma unroll
      for (int r = 0; r < 4; ++r) {
        const int row = wr * 64 + m * 16 + hi * 4 + r;
        Cg[(size_t)(arow0 + row) * (size_t)ldc + brow0 + col] = acc[m][n][r] + bv;
      }
  }
}

// ---------------- 256x256 phase-pipelined bf16 GEMM (enc path) ----------------
// C[M,N] = A[M,K]*B[N,K]^T + bias, bf16 out. 512 thr = 8 waves (2M x 4N),
// per-wave 128x64. BK=64. Single 64KB LDS buffer, in-place region streaming:
// per K-tile 4 quadrant phases; each stages 2 gload_lds into a >=2-phase-dead
// region, counted vmcnt(4), raw barriers, setprio around 16-MFMA clusters.
// LDS XOR swizzle col16^=(row&7); gload sources pre-swizzled (linear dest).
#define STAGE(G, grow0, kcol, L, S0, SS) do { \
    const int r_ = tid >> 3; \
    const int row_ = (S0) + (r_ & 31) + ((r_ >> 5) * (SS)); \
    GLOAD16((G) + (size_t)((grow0) + row_) * K + (kcol) + ((((tid & 7) ^ (r_ & 7))) << 3), \
            (L) + row_ * 128 + ((tid & 7) << 4)); \
  } while (0)

#define RD_A(MH) do { \
    _Pragma("unroll") for (int m_ = 0; m_ < 4; ++m_) { \
      const int row_ = wr * 128 + (MH) * 64 + m_ * 16 + lo; \
      _Pragma("unroll") for (int ks_ = 0; ks_ < 2; ++ks_) \
        af[m_][ks_] = *(const bf16x8*)(As + row_ * 128 + (((ks_ * 4 + hi) ^ (lo & 7)) << 4)); \
    } } while (0)

#define RD_B(NH, DST) do { \
    _Pragma("unroll") for (int n_ = 0; n_ < 2; ++n_) { \
      const int row_ = wc * 64 + (NH) * 32 + n_ * 16 + lo; \
      _Pragma("unroll") for (int ks_ = 0; ks_ < 2; ++ks_) \
        DST[n_][ks_] = *(const bf16x8*)(Bs + row_ * 128 + (((ks_ * 4 + hi) ^ (lo & 7)) << 4)); \
    } } while (0)

#define MM(MB, NB, BF) do { \
    __builtin_amdgcn_s_setprio(1); \
    _Pragma("unroll") for (int m_ = 0; m_ < 4; ++m_) \
      _Pragma("unroll") for (int n_ = 0; n_ < 2; ++n_) { \
        acc[(MB) + m_][(NB) + n_] = __builtin_amdgcn_mfma_f32_16x16x32_bf16(af[m_][0], BF[n_][0], acc[(MB) + m_][(NB) + n_], 0, 0, 0); \
        acc[(MB) + m_][(NB) + n_] = __builtin_amdgcn_mfma_f32_16x16x32_bf16(af[m_][1], BF[n_][1], acc[(MB) + m_][(NB) + n_], 0, 0, 0); \
      } \
    __builtin_amdgcn_s_setprio(0); \
  } while (0)

__global__ __launch_bounds__(512) void gemm256(const ushort_t* __restrict__ Ag,
                                               const ushort_t* __restrict__ Bg,
                                               ushort_t* __restrict__ Cg,
                                               const float* __restrict__ bias,
                                               int K, int ldc, int nbc) {
  __shared__ __align__(16) char smem[69632];
  char* As = smem;             // [256][64] bf16, swizzled
  char* Bs = smem + 32768;     // [256][64] bf16, swizzled
  const int tid = threadIdx.x;
  const int lane = tid & 63, wid = tid >> 6;
  const int wr = wid >> 2, wc = wid & 3;
  const int lo = lane & 15, hi = lane >> 4;

  // bijective XCD swizzle (gridDim.x % 8 == 0)
  const int cpx = gridDim.x >> 3;
  const int wg = (blockIdx.x & 7) * cpx + (blockIdx.x >> 3);
  const int brow0 = (wg / nbc) * 256;
  const int bcol0 = (wg % nbc) * 256;

  const int NT = K >> 6;
  f32x4 acc[8][4] = {};
  bf16x8 af[4][2], b0[2][2], b1[2][2];

  // prologue: kt0's A-mh0, B-nh0, B-nh1 (6 units; A-mh1 staged in p1)
  STAGE(Ag, brow0, 0, As, 0, 32);   STAGE(Ag, brow0, 0, As, 128, 32);
  STAGE(Bg, bcol0, 0, Bs, 0, 64);   STAGE(Bg, bcol0, 0, Bs, 128, 64);
  STAGE(Bg, bcol0, 0, Bs, 32, 64);  STAGE(Bg, bcol0, 0, Bs, 160, 64);

  for (int kt = 0; kt < NT - 1; ++kt) {
    const int k0 = kt << 6, k1 = (kt + 1) << 6;
    // p1: stage own A-mh1 (region dead since prev kt's p3)
    STAGE(Ag, brow0, k0, As, 64, 32);  STAGE(Ag, brow0, k0, As, 192, 32);
    VMCNT4; BARX;
    RD_A(0); RD_B(0, b0);
    MM(0, 0, b0);
    BARX;
    // p2: stage next A-mh0 (dead after p1)
    STAGE(Ag, brow0, k1, As, 0, 32);   STAGE(Ag, brow0, k1, As, 128, 32);
    VMCNT4; BARX;
    RD_B(1, b1);
    MM(0, 2, b1);
    BARX;
    // p3: stage next B-nh0 (dead after p1)
    STAGE(Bg, bcol0, k1, Bs, 0, 64);   STAGE(Bg, bcol0, k1, Bs, 128, 64);
    VMCNT4; BARX;
    RD_A(1);
    MM(4, 0, b0);
    BARX;
    // p4: stage next B-nh1 (dead after p2); reg-only MFMA, no barrier
    STAGE(Bg, bcol0, k1, Bs, 32, 64);  STAGE(Bg, bcol0, k1, Bs, 160, 64);
    MM(4, 2, b1);
  }
  { // peeled last K-tile (drains allowed)
    const int k0 = (NT - 1) << 6;
    STAGE(Ag, brow0, k0, As, 64, 32);  STAGE(Ag, brow0, k0, As, 192, 32);
    VMCNT4; BARX;
    RD_A(0); RD_B(0, b0);
    MM(0, 0, b0);
    BARX;
    VMCNT2; BARX;
    RD_B(1, b1);
    MM(0, 2, b1);
    BARX;
    VMCNT0; BARX;
    RD_A(1);
    MM(4, 0, b0);
    MM(4, 2, b1);
  }
  BARX;

  // epilogue: two 128-row rounds through padded LDS, coalesced uint4 out
  ushort_t* rep = (ushort_t*)smem;
#pragma unroll
  for (int h = 0; h < 2; ++h) {
    if (wr == h) {
#pragma unroll
      for (int n = 0; n < 4; ++n) {
        const int cl = wc * 64 + n * 16 + lo;
        const float bv = bias[bcol0 + cl];
#pragma unroll
        for (int m = 0; m < 8; ++m)
#pragma unroll
          for (int r = 0; r < 4; ++r)
            rep[(m * 16 + hi * 4 + r) * 264 + cl] = f2bf(acc[m][n][r] + bv);
      }
    }
    LGKM0; BARX;
    {
      const int rl = tid >> 2;
      const int c0 = tid & 3;
      ushort_t* dst = Cg + (size_t)(brow0 + h * 128 + rl) * (size_t)ldc + bcol0;
#pragma unroll
      for (int p = 0; p < 8; ++p)
        *(uint4*)(dst + (c0 + p * 4) * 8) = *(const uint4*)(rep + rl * 264 + (c0 + p * 4) * 8);
    }
    LGKM0; BARX;
  }
}

// ---------------- top-k: exact top-32/top-128 sets via histogram select ----------------
#define EIDX(c, h) ((uint_t)(((c) >> 2) * 2048 + tid * 8 + (((c) & 3) << 1) + (h)))
#define HW(b) (((b) >> 4) * 17 + ((b) & 15))
__global__ __launch_bounds__(256) void topk_kernel(const ushort_t* __restrict__ pre,
                                                   int* __restrict__ oidx,
                                                   float* __restrict__ oval,
                                                   double* __restrict__ pS1,
                                                   double* __restrict__ pS2) {
  __shared__ uint_t hist[4352];
  __shared__ uint_t sub32[16], sub128[16];
  __shared__ uint_t list32[64], list128[64];
  __shared__ uint_t wtot[4];
  __shared__ int ctl[16];
  __shared__ float fred[8];
  const int tid = threadIdx.x;
  const int lane = tid & 63, wid = tid >> 6;
  const size_t row = blockIdx.x;
  const uint4* pr4 = (const uint4*)(pre + row * 12288);

  for (int i = tid; i < 4352; i += 256) hist[i] = 0;
  if (tid < 16) { sub32[tid] = 0; sub128[tid] = 0; ctl[tid] = 0; }
  __syncthreads();

  uint_t k2[24];
#pragma unroll
  for (int i = 0; i < 6; ++i) {
    uint4 q = pr4[i * 256 + tid];
    uint_t qq[4] = { q.x, q.y, q.z, q.w };
#pragma unroll
    for (int w = 0; w < 4; ++w) {
      uint_t u2 = qq[w];
      uint_t lo16 = u2 & 0xFFFFu, hi16 = u2 >> 16;
      uint_t klo = (lo16 & 0x8000u) ? (~lo16 & 0xFFFFu) : (lo16 | 0x8000u);
      uint_t khi = (hi16 & 0x8000u) ? (~hi16 & 0xFFFFu) : (hi16 | 0x8000u);
      k2[i * 4 + w] = klo | (khi << 16);
      atomicAdd(&hist[HW(klo >> 4)], 1u);
      atomicAdd(&hist[HW(khi >> 4)], 1u);
    }
  }
  __syncthreads();

  uint_t cs = 0;
#pragma unroll
  for (int b = 0; b < 16; ++b) cs += hist[tid * 17 + b];
  uint_t s = cs;
#pragma unroll
  for (int off = 1; off < 64; off <<= 1) {
    uint_t v = (uint_t)__shfl_down((int)s, off);
    if (lane + off < 64) s += v;
  }
  if (lane == 0) wtot[wid] = s;
  __syncthreads();
  uint_t above = 0;
  for (int w = wid + 1; w < 4; ++w) above += wtot[w];
  const uint_t Sg = s + above;
  const uint_t Snx = Sg - cs;
#pragma unroll
  for (int which = 0; which < 2; ++which) {
    const uint_t K = which ? 128u : 32u;
    if (Sg >= K && Snx < K) {
      uint_t running = Snx;
      for (int b = 15; b >= 0; --b) {
        uint_t c = hist[tid * 17 + b];
        if (running + c >= K) { ctl[which * 2] = tid * 16 + b; ctl[which * 2 + 1] = (int)running; break; }
        running += c;
      }
    }
  }
  __syncthreads();
  const uint_t b32 = (uint_t)ctl[0], b128 = (uint_t)ctl[2];

#pragma unroll
  for (int c = 0; c < 24; ++c) {
    uint_t kk = k2[c];
#pragma unroll
    for (int h = 0; h < 2; ++h) {
      uint_t key = (h ? (kk >> 16) : kk) & 0xFFFFu;
      uint_t bin = key >> 4;
      if (bin == b32) atomicAdd(&sub32[key & 15], 1u);
      if (bin == b128) atomicAdd(&sub128[key & 15], 1u);
    }
  }
  __syncthreads();

  if (tid < 2) {
    const uint_t* sub = tid ? sub128 : sub32;
    const uint_t K = tid ? 128u : 32u;
    const uint_t chi = (uint_t)ctl[tid * 2 + 1];
    const uint_t bK = (uint_t)ctl[tid * 2];
    const uint_t need = K - chi;
    uint_t running = 0;
    for (int sb = 15; sb >= 0; --sb) {
      uint_t c = sub[sb];
      if (running + c >= need) {
        ctl[4 + tid * 2] = (int)((bK << 4) | (uint_t)sb);
        ctl[5 + tid * 2] = (int)(need - running);
        break;
      }
      running += c;
    }
  }
  __syncthreads();
  const uint_t kt32 = (uint_t)ctl[4], kt128 = (uint_t)ctl[6];

#pragma unroll
  for (int c = 0; c < 24; ++c) {
    uint_t kk = k2[c];
#pragma unroll
    for (int h = 0; h < 2; ++h) {
      uint_t key = (h ? (kk >> 16) : kk) & 0xFFFFu;
      uint_t idx = EIDX(c, h);
      if (key == kt32) {
        uint_t p = atomicAdd((uint_t*)&ctl[8], 1u);
        if (p < 64) list32[p] = idx;
      }
      if (key == kt128) {
        uint_t p = atomicAdd((uint_t*)&ctl[9], 1u);
        if (p < 64) list128[p] = idx;
      }
    }
  }
  __syncthreads();

  if (wid < 2) {
    const int n = min(ctl[8 + wid], 64);
    const int r = ctl[5 + wid * 2];
    uint_t v = (lane < n) ? (wid ? list128[lane] : list32[lane]) : 0xFFFFFFFFu;
#pragma unroll
    for (int k = 2; k <= 64; k <<= 1) {
#pragma unroll
      for (int j = k >> 1; j > 0; j >>= 1) {
        uint_t p = (uint_t)__shfl_xor((int)v, j);
        bool asc = ((lane & k) == 0);
        bool lower = ((lane & j) == 0);
        v = (asc == lower) ? min(v, p) : max(v, p);
      }
    }
    uint_t idxt = (uint_t)__shfl((int)v, r - 1);
    if (lane == 0) ctl[10 + wid] = (int)idxt;
  }
  __syncthreads();
  const uint_t idxt32 = (uint_t)ctl[10], idxt128 = (uint_t)ctl[11];

  float s1 = 0.f, s2 = 0.f;
  int* rowIdx = oidx + row * 128;
  float* rowVal = oval + row * 128;
#pragma unroll
  for (int c = 0; c < 24; ++c) {
    uint_t kk = k2[c];
#pragma unroll
    for (int h = 0; h < 2; ++h) {
      uint_t key = (h ? (kk >> 16) : kk) & 0xFFFFu;
      uint_t idx = EIDX(c, h);
      bool in32 = (key > kt32) || (key == kt32 && idx <= idxt32);
      bool in128 = (key > kt128) || (key == kt128 && idx <= idxt128);
      if (in128) {
        uint_t ub = (key & 0x8000u) ? (key & 0x7FFFu) : (~key & 0xFFFFu);
        float v = fmaxf(__uint_as_float(ub << 16), 0.f);
        int slot;
        if (in32) { slot = (int)atomicAdd((uint_t*)&ctl[12], 1u); s1 += v; }
        else      { slot = 32 + (int)atomicAdd((uint_t*)&ctl[13], 1u); }
        s2 += v;
        rowIdx[slot] = (int)idx;
        rowVal[slot] = v;
      }
    }
  }
  for (int o = 32; o > 0; o >>= 1) { s1 += __shfl_down(s1, o); s2 += __shfl_down(s2, o); }
  if (lane == 0) { fred[wid] = s1; fred[4 + wid] = s2; }
  __syncthreads();
  if (tid == 0) {
    pS1[row] = (double)(fred[0] + fred[1] + fred[2] + fred[3]);
    pS2[row] = (double)(fred[4] + fred[5] + fred[6] + fred[7]);
  }
}

// ---------------- sparse decode + loss + means (fp8 W_dec, x16 scale) ----------------
__global__ __launch_bounds__(192) void decode_loss(const int* __restrict__ oidx,
                                                   const float* __restrict__ oval,
                                                   const float* __restrict__ skip,
                                                   const float* __restrict__ mlp,
                                                   const uint_t* __restrict__ Wd8,
                                                   double* __restrict__ pL1,
                                                   double* __restrict__ pL2,
                                                   double* __restrict__ pDS) {
  __shared__ int lidx[128];
  __shared__ float lval[128];
  __shared__ double wred[3][3];
  const int tid = threadIdx.x;
  const size_t row = blockIdx.x;
  if (tid < 128) {
    lidx[tid] = oidx[row * 128 + tid];
    lval[tid] = oval[row * 128 + tid];
  }
  __syncthreads();
  const float4 s4 = ((const float4*)(skip + row * 768))[tid];
  const float4 m4 = ((const float4*)(mlp + row * 768))[tid];
  const uint_t* Wt = Wd8 + tid;
  float a0 = 0.f, a1 = 0.f, a2 = 0.f, a3 = 0.f;
  float l1 = 0.f, dsum = 0.f;

#pragma unroll 1
  for (int g = 0; g < 16; ++g) {
    uint_t wb[8];
    float vv[8];
#pragma unroll
    for (int b = 0; b < 8; ++b) {
      wb[b] = Wt[(size_t)lidx[g * 8 + b] * 192];
      vv[b] = lval[g * 8 + b];
    }
#pragma unroll
    for (int b = 0; b < 8; ++b) {
      const float vs = vv[b] * 0.0625f;
      f32x2 lo = __builtin_amdgcn_cvt_pk_f32_fp8(wb[b], false);
      f32x2 hi = __builtin_amdgcn_cvt_pk_f32_fp8(wb[b], true);
      a0 = fmaf(vs, lo[0], a0);
      a1 = fmaf(vs, lo[1], a1);
      a2 = fmaf(vs, hi[0], a2);
      a3 = fmaf(vs, hi[1], a3);
    }
    if (g == 3) {
      float d0 = a0 + s4.x, d1 = a1 + s4.y, d2 = a2 + s4.z, d3 = a3 + s4.w;
      float e0 = m4.x - d0, e1 = m4.y - d1, e2 = m4.z - d2, e3 = m4.w - d3;
      l1 = e0 * e0 + e1 * e1 + e2 * e2 + e3 * e3;
      dsum = d0 + d1 + d2 + d3;
    }
  }
  float d0 = a0 + s4.x, d1 = a1 + s4.y, d2 = a2 + s4.z, d3 = a3 + s4.w;
  float e0 = m4.x - d0, e1 = m4.y - d1, e2 = m4.z - d2, e3 = m4.w - d3;
  float l2 = e0 * e0 + e1 * e1 + e2 * e2 + e3 * e3;
  dsum += d0 + d1 + d2 + d3;

  double r0 = (double)l1, r1 = (double)l2, r2 = (double)dsum;
  for (int o = 32; o > 0; o >>= 1) {
    r0 += __shfl_down(r0, o);
    r1 += __shfl_down(r1, o);
    r2 += __shfl_down(r2, o);
  }
  const int w = tid >> 6;
  if ((tid & 63) == 0) { wred[w][0] = r0; wred[w][1] = r1; wred[w][2] = r2; }
  __syncthreads();
  if (tid == 0) {
    pL1[row] = wred[0][0] + wred[1][0] + wred[2][0];
    pL2[row] = wred[0][1] + wred[1][1] + wred[2][1];
    pDS[row] = wred[0][2] + wred[1][2] + wred[2][2];
  }
}

// ---------------- finalize: reduce per-block partials ----------------
__global__ __launch_bounds__(256) void finalize_kernel(const double* __restrict__ accs,
                                                       const float* __restrict__ colsum,
                                                       const double* __restrict__ pL1,
                                                       const double* __restrict__ pL2,
                                                       const double* __restrict__ pDS,
                                                       const double* __restrict__ pS1,
                                                       const double* __restrict__ pS2,
                                                       float* __restrict__ out) {
  __shared__ double wred[4][6];
  const int tid = threadIdx.x;
  const int lane = tid & 63, wid = tid >> 6;
  double aL1 = 0, aL2 = 0, aDS = 0, aS1 = 0, aS2 = 0;
  for (int i = tid; i < 8192; i += 256) {
    aL1 += pL1[i]; aL2 += pL2[i]; aDS += pDS[i]; aS1 += pS1[i]; aS2 += pS2[i];
  }
  double c2 = 0.0;
  for (int i = tid; i < 768; i += 256) { double c = (double)colsum[i]; c2 += c * c; }
  for (int o = 32; o > 0; o >>= 1) {
    aL1 += __shfl_down(aL1, o);
    aL2 += __shfl_down(aL2, o);
    aDS += __shfl_down(aDS, o);
    aS1 += __shfl_down(aS1, o);
    aS2 += __shfl_down(aS2, o);
    c2  += __shfl_down(c2, o);
  }
  if (lane == 0) {
    wred[wid][0] = aL1; wred[wid][1] = aL2; wred[wid][2] = aDS;
    wred[wid][3] = aS1; wred[wid][4] = aS2; wred[wid][5] = c2;
  }
  __syncthreads();
  if (tid == 0) {
    double tL1 = 0, tL2 = 0, tDS = 0, tS1 = 0, tS2 = 0, csq = 0;
    for (int i = 0; i < 4; ++i) {
      tL1 += wred[i][0]; tL2 += wred[i][1]; tDS += wred[i][2];
      tS1 += wred[i][3]; tS2 += wred[i][4]; csq += wred[i][5];
    }
    double tv = accs[5] - csq / 8192.0;
    out[0] = (float)((tS1 + tS2) / (8192.0 * 12288.0));
    out[1] = (float)(tDS / (8192.0 * 768.0));
    out[2] = (float)(tL1 / tv + tL2 / (8.0 * tv));
  }
}

extern "C" void kernel_launch(void* const* d_in, const int* in_sizes, int n_in,
                              void* d_out, int out_size, void* d_ws, size_t ws_size,
                              hipStream_t stream) {
  const float* x    = (const float*)d_in[0];
  const float* mlp  = (const float*)d_in[1];
  const float* Wenc = (const float*)d_in[2];
  const float* benc = (const float*)d_in[3];
  const float* Wdec = (const float*)d_in[4];
  const float* bdec = (const float*)d_in[5];
  const float* Wskip= (const float*)d_in[6];

  char* ws = (char*)d_ws;
  const size_t OFF_COL  = 1024;
  const size_t OFF_XBF  = 8192;
  const size_t OFF_WENC = OFF_XBF  + (size_t)8192 * 768 * 2;
  const size_t OFF_WSK  = OFF_WENC + (size_t)12288 * 768 * 2;
  const size_t OFF_SKIP = OFF_WSK  + (size_t)768 * 768 * 2;
  const size_t OFF_TIDX = OFF_SKIP + (size_t)8192 * 768 * 4;
  const size_t OFF_TVAL = OFF_TIDX + (size_t)8192 * 128 * 4;
  const size_t OFF_PRE  = OFF_TVAL + (size_t)8192 * 128 * 4;

  double*   accs   = (double*)ws;
  float*    colsum = (float*)(ws + OFF_COL);
  ushort_t* xbf    = (ushort_t*)(ws + OFF_XBF);
  ushort_t* wencbf = (ushort_t*)(ws + OFF_WENC);
  ushort_t* wskT   = (ushort_t*)(ws + OFF_WSK);
  float*    skip   = (float*)(ws + OFF_SKIP);
  int*      tidx   = (int*)(ws + OFF_TIDX);
  float*    tval   = (float*)(ws + OFF_TVAL);
  ushort_t* pre    = (ushort_t*)(ws + OFF_PRE);

  double* pL1 = (double*)(ws + OFF_XBF);
  double* pL2 = pL1 + 8192;
  double* pDS = pL1 + 16384;
  double* pS1 = pL1 + 24576;
  double* pS2 = pL1 + 32768;

  (void)hipMemsetAsync(d_ws, 0, 8192, stream);

  prep_x<<<256, 256, 0, stream>>>(x, xbf, colsum, accs);
  conv_bf16<<<(12288 * 768 / 4) / 256, 256, 0, stream>>>(Wenc, wencbf, 12288 * 768);
  conv_skipT<<<dim3(3, 768), 256, 0, stream>>>(Wskip, wskT);

  // enc: 8192x12288x768 -> 32x48 = 1536 tiles of 256^2
  gemm256<<<1536, 512, 0, stream>>>(xbf, wencbf, pre, benc, 768, 12288, 48);
  gemm_bt<<<dim3(6, 64), 256, 0, stream>>>(xbf, wskT, skip, bdec, 768, 768);

  uint_t* wdec8 = (uint_t*)wencbf;
  conv_fp8<<<(12288 * 768 / 4 + 255) / 256, 256, 0, stream>>>(Wdec, wdec8, 12288 * 768 / 4);

  topk_kernel<<<8192, 256, 0, stream>>>(pre, tidx, tval, pS1, pS2);
  decode_loss<<<8192, 192, 0, stream>>>(tidx, tval, skip, mlp, wdec8, pL1, pL2, pDS);
  finalize_kernel<<<1, 256, 0, stream>>>(accs, colsum, pL1, pL2, pDS, pS1, pS2, (float*)d_out);
}

// Round 9
// 403.623 us; speedup vs baseline: 2.6273x; 1.2507x over previous
//
#include <hip/hip_runtime.h>

typedef unsigned short ushort_t;
typedef unsigned int uint_t;

typedef __attribute__((ext_vector_type(8))) short bf16x8;
typedef __attribute__((ext_vector_type(4))) float f32x4;
typedef __attribute__((ext_vector_type(2))) float f32x2;

#define GLOAD16(g, l) __builtin_amdgcn_global_load_lds( \
    (const __attribute__((address_space(1))) unsigned int*)(g), \
    (__attribute__((address_space(3))) unsigned int*)(l), 16, 0, 0)

#define VMCNT4 asm volatile("s_waitcnt vmcnt(4)" ::: "memory")
#define VMCNT2 asm volatile("s_waitcnt vmcnt(2)" ::: "memory")
#define VMCNT0 asm volatile("s_waitcnt vmcnt(0)" ::: "memory")
#define LGKM0  asm volatile("s_waitcnt lgkmcnt(0)" ::: "memory")
#define BARX   __builtin_amdgcn_s_barrier()

__device__ __forceinline__ ushort_t f2bf(float f) {
  union { float f; uint_t u; } c; c.f = f;
  uint_t u = c.u;
  return (ushort_t)((u + 0x7FFFu + ((u >> 16) & 1u)) >> 16);
}

// ---------------- prep: x -> bf16, colsum, sumsq ----------------
__global__ __launch_bounds__(256) void prep_x(const float* __restrict__ x,
                                              ushort_t* __restrict__ xbf,
                                              float* __restrict__ colsum,
                                              double* __restrict__ accs) {
  const int tid = threadIdx.x;
  const int r0 = blockIdx.x * 32;
  float cs0 = 0.f, cs1 = 0.f, cs2 = 0.f;
  double ss = 0.0;
  for (int r = 0; r < 32; ++r) {
    const float* xr = x + (size_t)(r0 + r) * 768;
    ushort_t* xo = xbf + (size_t)(r0 + r) * 768;
    float v0 = xr[tid], v1 = xr[tid + 256], v2 = xr[tid + 512];
    xo[tid] = f2bf(v0); xo[tid + 256] = f2bf(v1); xo[tid + 512] = f2bf(v2);
    cs0 += v0; cs1 += v1; cs2 += v2;
    ss += (double)v0 * v0 + (double)v1 * v1 + (double)v2 * v2;
  }
  atomicAdd(&colsum[tid], cs0);
  atomicAdd(&colsum[tid + 256], cs1);
  atomicAdd(&colsum[tid + 512], cs2);
  for (int o = 32; o > 0; o >>= 1) ss += __shfl_down(ss, o);
  __shared__ double wsum[4];
  if ((tid & 63) == 0) wsum[tid >> 6] = ss;
  __syncthreads();
  if (tid == 0) atomicAdd(&accs[5], wsum[0] + wsum[1] + wsum[2] + wsum[3]);
}

// ---------------- generic f32 -> bf16 convert ----------------
__global__ __launch_bounds__(256) void conv_bf16(const float* __restrict__ in,
                                                 ushort_t* __restrict__ out, int n) {
  int i = (blockIdx.x * 256 + threadIdx.x) * 4;
  if (i + 3 < n) {
    float4 v = *(const float4*)(in + i);
    uint_t a = (uint_t)f2bf(v.x) | ((uint_t)f2bf(v.y) << 16);
    uint_t b = (uint_t)f2bf(v.z) | ((uint_t)f2bf(v.w) << 16);
    *(uint2*)(out + i) = make_uint2(a, b);
  }
}

// ---------------- W_dec f32 -> fp8 e4m3 (x16 scale), 4 cols per uint ----------------
__global__ __launch_bounds__(256) void conv_fp8(const float* __restrict__ in,
                                                uint_t* __restrict__ out, int n4) {
  int i = blockIdx.x * 256 + threadIdx.x;
  if (i < n4) {
    float4 v = ((const float4*)in)[i];
    int w = 0;
    w = __builtin_amdgcn_cvt_pk_fp8_f32(v.x * 16.f, v.y * 16.f, w, false);
    w = __builtin_amdgcn_cvt_pk_fp8_f32(v.z * 16.f, v.w * 16.f, w, true);
    out[i] = (uint_t)w;
  }
}

// ---------------- W_skip transpose -> bf16 [D][K] ----------------
__global__ __launch_bounds__(256) void conv_skipT(const float* __restrict__ in,
                                                  ushort_t* __restrict__ out) {
  int d = blockIdx.x * 256 + threadIdx.x;
  int k = blockIdx.y;
  if (d < 768) out[(size_t)d * 768 + k] = f2bf(in[(size_t)k * 768 + d]);
}

// ---------------- small bf16 GEMM (skip path): m97 structure ----------------
__global__ __launch_bounds__(256) void gemm_bt(const ushort_t* __restrict__ Ag,
                                               const ushort_t* __restrict__ Bg,
                                               float* __restrict__ Cg,
                                               const float* __restrict__ bias,
                                               int K, int ldc) {
  __shared__ __align__(16) char smem[34816];
  const int tid = threadIdx.x;
  const int lane = tid & 63, wid = tid >> 6;
  const int wr = wid >> 1, wc = wid & 1;
  const int lo = lane & 15, hi = lane >> 4;
  const int arow0 = blockIdx.y * 128, brow0 = blockIdx.x * 128;
  const int rr0 = (lane >> 2);
  const int kb = (lane & 3) * 8;
  f32x4 acc[4][4] = {};
  const int NT = K >> 5;
  for (int c = 0; c < 2; ++c) {
    int rr = (wid * 2 + c) * 16 + rr0;
    GLOAD16(Ag + (size_t)(arow0 + rr) * K + kb, smem + (wid * 2 + c) * 1024);
    GLOAD16(Bg + (size_t)(brow0 + rr) * K + kb, smem + 16384 + (wid * 2 + c) * 1024);
  }
  __syncthreads();
  for (int kt = 0; kt < NT; ++kt) {
    const int cur = (kt & 1) * 8192;
    const int nxt = 8192 - cur;
    if (kt + 1 < NT) {
      const int k0 = (kt + 1) << 5;
      for (int c = 0; c < 2; ++c) {
        int rr = (wid * 2 + c) * 16 + rr0;
        GLOAD16(Ag + (size_t)(arow0 + rr) * K + k0 + kb, smem + nxt + (wid * 2 + c) * 1024);
        GLOAD16(Bg + (size_t)(brow0 + rr) * K + k0 + kb, smem + 16384 + nxt + (wid * 2 + c) * 1024);
      }
    }
    const char* As = smem + cur;
    const char* Bs = smem + 16384 + cur;
    bf16x8 af[4], bfr[4];
#pragma unroll
    for (int m = 0; m < 4; ++m)
      af[m] = *(const bf16x8*)(As + ((wr * 64 + m * 16 + lo) * 64 + hi * 16));
#pragma unroll
    for (int n = 0; n < 4; ++n)
      bfr[n] = *(const bf16x8*)(Bs + ((wc * 64 + n * 16 + lo) * 64 + hi * 16));
#pragma unroll
    for (int m = 0; m < 4; ++m)
#pragma unroll
      for (int n = 0; n < 4; ++n)
        acc[m][n] = __builtin_amdgcn_mfma_f32_16x16x32_bf16(af[m], bfr[n], acc[m][n], 0, 0, 0);
    __syncthreads();
  }
#pragma unroll
  for (int n = 0; n < 4; ++n) {
    const int col = wc * 64 + n * 16 + lo;
    const float bv = bias[brow0 + col];
#pragma unroll
    for (int m = 0; m < 4; ++m)
#pragma unroll
      for (int r = 0; r < 4; ++r) {
        const int row = wr * 64 + m * 16 + hi * 4 + r;
        Cg[(size_t)(arow0 + row) * (size_t)ldc + brow0 + col] = acc[m][n][r] + bv;
      }
  }
}

// ---------------- 256x256 phase-pipelined bf16 GEMM (enc path) ----------------
#define STAGE(G, grow0, kcol, L, S0, SS) do { \
    const int r_ = tid >> 3; \
    const int row_ = (S0) + (r_ & 31) + ((r_ >> 5) * (SS)); \
    GLOAD16((G) + (size_t)((grow0) + row_) * K + (kcol) + ((((tid & 7) ^ (r_ & 7))) << 3), \
            (L) + row_ * 128 + ((tid & 7) << 4)); \
  } while (0)

#define RD_A(MH) do { \
    _Pragma("unroll") for (int m_ = 0; m_ < 4; ++m_) { \
      const int row_ = wr * 128 + (MH) * 64 + m_ * 16 + lo; \
      _Pragma("unroll") for (int ks_ = 0; ks_ < 2; ++ks_) \
        af[m_][ks_] = *(const bf16x8*)(As + row_ * 128 + (((ks_ * 4 + hi) ^ (lo & 7)) << 4)); \
    } } while (0)

#define RD_B(NH, DST) do { \
    _Pragma("unroll") for (int n_ = 0; n_ < 2; ++n_) { \
      const int row_ = wc * 64 + (NH) * 32 + n_ * 16 + lo; \
      _Pragma("unroll") for (int ks_ = 0; ks_ < 2; ++ks_) \
        DST[n_][ks_] = *(const bf16x8*)(Bs + row_ * 128 + (((ks_ * 4 + hi) ^ (lo & 7)) << 4)); \
    } } while (0)

#define MM(MB, NB, BF) do { \
    __builtin_amdgcn_s_setprio(1); \
    _Pragma("unroll") for (int m_ = 0; m_ < 4; ++m_) \
      _Pragma("unroll") for (int n_ = 0; n_ < 2; ++n_) { \
        acc[(MB) + m_][(NB) + n_] = __builtin_amdgcn_mfma_f32_16x16x32_bf16(af[m_][0], BF[n_][0], acc[(MB) + m_][(NB) + n_], 0, 0, 0); \
        acc[(MB) + m_][(NB) + n_] = __builtin_amdgcn_mfma_f32_16x16x32_bf16(af[m_][1], BF[n_][1], acc[(MB) + m_][(NB) + n_], 0, 0, 0); \
      } \
    __builtin_amdgcn_s_setprio(0); \
  } while (0)

__global__ __launch_bounds__(512) void gemm256(const ushort_t* __restrict__ Ag,
                                               const ushort_t* __restrict__ Bg,
                                               ushort_t* __restrict__ Cg,
                                               const float* __restrict__ bias,
                                               int K, int ldc, int nbc) {
  __shared__ __align__(16) char smem[69632];
  char* As = smem;
  char* Bs = smem + 32768;
  const int tid = threadIdx.x;
  const int lane = tid & 63, wid = tid >> 6;
  const int wr = wid >> 2, wc = wid & 3;
  const int lo = lane & 15, hi = lane >> 4;

  const int cpx = gridDim.x >> 3;
  const int wg = (blockIdx.x & 7) * cpx + (blockIdx.x >> 3);
  const int brow0 = (wg / nbc) * 256;
  const int bcol0 = (wg % nbc) * 256;

  const int NT = K >> 6;
  f32x4 acc[8][4] = {};
  bf16x8 af[4][2], b0[2][2], b1[2][2];

  STAGE(Ag, brow0, 0, As, 0, 32);   STAGE(Ag, brow0, 0, As, 128, 32);
  STAGE(Bg, bcol0, 0, Bs, 0, 64);   STAGE(Bg, bcol0, 0, Bs, 128, 64);
  STAGE(Bg, bcol0, 0, Bs, 32, 64);  STAGE(Bg, bcol0, 0, Bs, 160, 64);

  for (int kt = 0; kt < NT - 1; ++kt) {
    const int k0 = kt << 6, k1 = (kt + 1) << 6;
    STAGE(Ag, brow0, k0, As, 64, 32);  STAGE(Ag, brow0, k0, As, 192, 32);
    VMCNT4; BARX;
    RD_A(0); RD_B(0, b0);
    MM(0, 0, b0);
    BARX;
    STAGE(Ag, brow0, k1, As, 0, 32);   STAGE(Ag, brow0, k1, As, 128, 32);
    VMCNT4; BARX;
    RD_B(1, b1);
    MM(0, 2, b1);
    BARX;
    STAGE(Bg, bcol0, k1, Bs, 0, 64);   STAGE(Bg, bcol0, k1, Bs, 128, 64);
    VMCNT4; BARX;
    RD_A(1);
    MM(4, 0, b0);
    BARX;
    STAGE(Bg, bcol0, k1, Bs, 32, 64);  STAGE(Bg, bcol0, k1, Bs, 160, 64);
    MM(4, 2, b1);
  }
  {
    const int k0 = (NT - 1) << 6;
    STAGE(Ag, brow0, k0, As, 64, 32);  STAGE(Ag, brow0, k0, As, 192, 32);
    VMCNT4; BARX;
    RD_A(0); RD_B(0, b0);
    MM(0, 0, b0);
    BARX;
    VMCNT2; BARX;
    RD_B(1, b1);
    MM(0, 2, b1);
    BARX;
    VMCNT0; BARX;
    RD_A(1);
    MM(4, 0, b0);
    MM(4, 2, b1);
  }
  BARX;

  ushort_t* rep = (ushort_t*)smem;
#pragma unroll
  for (int h = 0; h < 2; ++h) {
    if (wr == h) {
#pragma unroll
      for (int n = 0; n < 4; ++n) {
        const int cl = wc * 64 + n * 16 + lo;
        const float bv = bias[bcol0 + cl];
#pragma unroll
        for (int m = 0; m < 8; ++m)
#pragma unroll
          for (int r = 0; r < 4; ++r)
            rep[(m * 16 + hi * 4 + r) * 264 + cl] = f2bf(acc[m][n][r] + bv);
      }
    }
    LGKM0; BARX;
    {
      const int rl = tid >> 2;
      const int c0 = tid & 3;
      ushort_t* dst = Cg + (size_t)(brow0 + h * 128 + rl) * (size_t)ldc + bcol0;
#pragma unroll
      for (int p = 0; p < 8; ++p)
        *(uint4*)(dst + (c0 + p * 4) * 8) = *(const uint4*)(rep + rl * 264 + (c0 + p * 4) * 8);
    }
    LGKM0; BARX;
  }
}

// ---------------- top-k: histogram threshold -> candidate sort (1 wave) ----------------
// Exact top-32/top-128 in jax order: candidates (bin >= b128) packed as
// (0xFFFF-key)<<16|idx, single-wave 256-elem register bitonic sort.
#define EIDX(c, h) ((uint_t)(((c) >> 2) * 2048 + tid * 8 + (((c) & 3) << 1) + (h)))
#define HW(b) (((b) >> 4) * 17 + ((b) & 15))
__global__ __launch_bounds__(256) void topk_kernel(const ushort_t* __restrict__ pre,
                                                   int* __restrict__ oidx,
                                                   float* __restrict__ oval,
                                                   double* __restrict__ pS1,
                                                   double* __restrict__ pS2) {
  __shared__ uint_t hist[4352];
  __shared__ uint_t cand[256];
  __shared__ uint_t wtot[4];
  __shared__ uint_t ctl[4];
  const int tid = threadIdx.x;
  const int lane = tid & 63, wid = tid >> 6;
  const size_t row = blockIdx.x;
  const uint4* pr4 = (const uint4*)(pre + row * 12288);

  for (int i = tid; i < 4352; i += 256) hist[i] = 0;
  if (tid < 4) ctl[tid] = 0;
  __syncthreads();

  // pass 1: load row, packed dual-half monotone key transform, histogram
  uint_t k2[24];
#pragma unroll
  for (int i = 0; i < 6; ++i) {
    uint4 q = pr4[i * 256 + tid];
    uint_t qq[4] = { q.x, q.y, q.z, q.w };
#pragma unroll
    for (int w = 0; w < 4; ++w) {
      uint_t u2 = qq[w];
      uint_t m = ((u2 >> 15) & 0x00010001u) * 0x7FFFu;
      uint_t kk = u2 ^ (m | 0x80008000u);
      k2[i * 4 + w] = kk;
      atomicAdd(&hist[HW((kk & 0xFFFFu) >> 4)], 1u);
      atomicAdd(&hist[HW(kk >> 20)], 1u);
    }
  }
  __syncthreads();

  // chunk sums + wave suffix scan -> bin threshold for K=128
  uint_t cs = 0;
#pragma unroll
  for (int b = 0; b < 16; ++b) cs += hist[tid * 17 + b];
  uint_t s = cs;
#pragma unroll
  for (int off = 1; off < 64; off <<= 1) {
    uint_t v = (uint_t)__shfl_down((int)s, off);
    if (lane + off < 64) s += v;
  }
  if (lane == 0) wtot[wid] = s;
  __syncthreads();
  uint_t above = 0;
  for (int w = wid + 1; w < 4; ++w) above += wtot[w];
  const uint_t Sg = s + above;
  const uint_t Snx = Sg - cs;
  if (Sg >= 128u && Snx < 128u) {
    uint_t running = Snx;
    for (int b = 15; b >= 0; --b) {
      uint_t c = hist[tid * 17 + b];
      if (running + c >= 128u) { ctl[0] = (uint_t)(tid * 16 + b); break; }
      running += c;
    }
  }
  __syncthreads();
  const uint_t b128 = ctl[0];

  // pass 2: collect candidates (bin >= b128), packed (0xFFFF-key)<<16 | idx
#pragma unroll
  for (int c = 0; c < 24; ++c) {
    uint_t kk = k2[c];
    uint_t key0 = kk & 0xFFFFu, key1 = kk >> 16;
    if ((key0 >> 4) >= b128) {
      uint_t p = atomicAdd(&ctl[1], 1u);
      if (p < 256u) cand[p] = ((0xFFFFu - key0) << 16) | EIDX(c, 0);
    }
    if ((key1 >> 4) >= b128) {
      uint_t p = atomicAdd(&ctl[1], 1u);
      if (p < 256u) cand[p] = ((0xFFFFu - key1) << 16) | EIDX(c, 1);
    }
  }
  __syncthreads();

  // wave 0: 256-element in-register bitonic sort (4 elems/lane), write outputs
  if (wid == 0) {
    const int n = (int)min(ctl[1], 256u);
    uint_t v[4];
#pragma unroll
    for (int r = 0; r < 4; ++r)
      v[r] = (r * 64 + lane < n) ? cand[r * 64 + lane] : 0xFFFFFFFFu;
#pragma unroll
    for (int k = 2; k <= 256; k <<= 1) {
#pragma unroll
      for (int j = 128; j > 0; j >>= 1) {
        if (j >= k) continue;
        if (j >= 64) {
          const int js = j >> 6;
#pragma unroll
          for (int r = 0; r < 4; ++r) {
            if ((r & js) == 0) {
              const int r2 = r | js;
              const bool up = (((r << 6) & k) == 0);
              uint_t a = v[r], b = v[r2];
              uint_t mn = min(a, b), mx = max(a, b);
              v[r] = up ? mn : mx;
              v[r2] = up ? mx : mn;
            }
          }
        } else {
#pragma unroll
          for (int r = 0; r < 4; ++r) {
            uint_t p = (uint_t)__shfl_xor((int)v[r], j);
            const bool up = ((((r << 6) | lane) & k) == 0);
            const bool lower = ((lane & j) == 0);
            v[r] = (up == lower) ? min(v[r], p) : max(v[r], p);
          }
        }
      }
    }
    // elems 0..127 = v[0],v[1]: value-desc, idx-asc (jax order)
    int* rowIdx = oidx + row * 128;
    float* rowVal = oval + row * 128;
    float val[2];
#pragma unroll
    for (int r = 0; r < 2; ++r) {
      uint_t pk = v[r];
      uint_t idx = pk & 0xFFFFu;
      uint_t key = 0xFFFFu - (pk >> 16);
      uint_t ub = (key & 0x8000u) ? (key & 0x7FFFu) : (~key & 0xFFFFu);
      val[r] = fmaxf(__uint_as_float(ub << 16), 0.f);
      rowIdx[r * 64 + lane] = (int)idx;
      rowVal[r * 64 + lane] = val[r];
    }
    float s1 = (lane < 32) ? val[0] : 0.f;
    float s2 = val[0] + val[1];
    for (int o = 32; o > 0; o >>= 1) { s1 += __shfl_down(s1, o); s2 += __shfl_down(s2, o); }
    if (lane == 0) { pS1[row] = (double)s1; pS2[row] = (double)s2; }
  }
}

// ---------------- sparse decode + loss + means (fp8 W_dec, x16 scale) ----------------
__global__ __launch_bounds__(192) void decode_loss(const int* __restrict__ oidx,
                                                   const float* __restrict__ oval,
                                                   const float* __restrict__ skip,
                                                   const float* __restrict__ mlp,
                                                   const uint_t* __restrict__ Wd8,
                                                   double* __restrict__ pL1,
                                                   double* __restrict__ pL2,
                                                   double* __restrict__ pDS) {
  __shared__ int lidx[128];
  __shared__ float lval[128];
  __shared__ double wred[3][3];
  const int tid = threadIdx.x;
  const size_t row = blockIdx.x;
  if (tid < 128) {
    lidx[tid] = oidx[row * 128 + tid];
    lval[tid] = oval[row * 128 + tid];
  }
  __syncthreads();
  const float4 s4 = ((const float4*)(skip + row * 768))[tid];
  const float4 m4 = ((const float4*)(mlp + row * 768))[tid];
  const uint_t* Wt = Wd8 + tid;
  float a0 = 0.f, a1 = 0.f, a2 = 0.f, a3 = 0.f;
  float l1 = 0.f, dsum = 0.f;

#pragma unroll 1
  for (int g = 0; g < 16; ++g) {
    uint_t wb[8];
    float vv[8];
#pragma unroll
    for (int b = 0; b < 8; ++b) {
      wb[b] = Wt[(size_t)lidx[g * 8 + b] * 192];
      vv[b] = lval[g * 8 + b];
    }
#pragma unroll
    for (int b = 0; b < 8; ++b) {
      const float vs = vv[b] * 0.0625f;
      f32x2 lo = __builtin_amdgcn_cvt_pk_f32_fp8(wb[b], false);
      f32x2 hi = __builtin_amdgcn_cvt_pk_f32_fp8(wb[b], true);
      a0 = fmaf(vs, lo[0], a0);
      a1 = fmaf(vs, lo[1], a1);
      a2 = fmaf(vs, hi[0], a2);
      a3 = fmaf(vs, hi[1], a3);
    }
    if (g == 3) {
      float d0 = a0 + s4.x, d1 = a1 + s4.y, d2 = a2 + s4.z, d3 = a3 + s4.w;
      float e0 = m4.x - d0, e1 = m4.y - d1, e2 = m4.z - d2, e3 = m4.w - d3;
      l1 = e0 * e0 + e1 * e1 + e2 * e2 + e3 * e3;
      dsum = d0 + d1 + d2 + d3;
    }
  }
  float d0 = a0 + s4.x, d1 = a1 + s4.y, d2 = a2 + s4.z, d3 = a3 + s4.w;
  float e0 = m4.x - d0, e1 = m4.y - d1, e2 = m4.z - d2, e3 = m4.w - d3;
  float l2 = e0 * e0 + e1 * e1 + e2 * e2 + e3 * e3;
  dsum += d0 + d1 + d2 + d3;

  double r0 = (double)l1, r1 = (double)l2, r2 = (double)dsum;
  for (int o = 32; o > 0; o >>= 1) {
    r0 += __shfl_down(r0, o);
    r1 += __shfl_down(r1, o);
    r2 += __shfl_down(r2, o);
  }
  const int w = tid >> 6;
  if ((tid & 63) == 0) { wred[w][0] = r0; wred[w][1] = r1; wred[w][2] = r2; }
  __syncthreads();
  if (tid == 0) {
    pL1[row] = wred[0][0] + wred[1][0] + wred[2][0];
    pL2[row] = wred[0][1] + wred[1][1] + wred[2][1];
    pDS[row] = wred[0][2] + wred[1][2] + wred[2][2];
  }
}

// ---------------- finalize: reduce per-block partials ----------------
__global__ __launch_bounds__(256) void finalize_kernel(const double* __restrict__ accs,
                                                       const float* __restrict__ colsum,
                                                       const double* __restrict__ pL1,
                                                       const double* __restrict__ pL2,
                                                       const double* __restrict__ pDS,
                                                       const double* __restrict__ pS1,
                                                       const double* __restrict__ pS2,
                                                       float* __restrict__ out) {
  __shared__ double wred[4][6];
  const int tid = threadIdx.x;
  const int lane = tid & 63, wid = tid >> 6;
  double aL1 = 0, aL2 = 0, aDS = 0, aS1 = 0, aS2 = 0;
  for (int i = tid; i < 8192; i += 256) {
    aL1 += pL1[i]; aL2 += pL2[i]; aDS += pDS[i]; aS1 += pS1[i]; aS2 += pS2[i];
  }
  double c2 = 0.0;
  for (int i = tid; i < 768; i += 256) { double c = (double)colsum[i]; c2 += c * c; }
  for (int o = 32; o > 0; o >>= 1) {
    aL1 += __shfl_down(aL1, o);
    aL2 += __shfl_down(aL2, o);
    aDS += __shfl_down(aDS, o);
    aS1 += __shfl_down(aS1, o);
    aS2 += __shfl_down(aS2, o);
    c2  += __shfl_down(c2, o);
  }
  if (lane == 0) {
    wred[wid][0] = aL1; wred[wid][1] = aL2; wred[wid][2] = aDS;
    wred[wid][3] = aS1; wred[wid][4] = aS2; wred[wid][5] = c2;
  }
  __syncthreads();
  if (tid == 0) {
    double tL1 = 0, tL2 = 0, tDS = 0, tS1 = 0, tS2 = 0, csq = 0;
    for (int i = 0; i < 4; ++i) {
      tL1 += wred[i][0]; tL2 += wred[i][1]; tDS += wred[i][2];
      tS1 += wred[i][3]; tS2 += wred[i][4]; csq += wred[i][5];
    }
    double tv = accs[5] - csq / 8192.0;
    out[0] = (float)((tS1 + tS2) / (8192.0 * 12288.0));
    out[1] = (float)(tDS / (8192.0 * 768.0));
    out[2] = (float)(tL1 / tv + tL2 / (8.0 * tv));
  }
}

extern "C" void kernel_launch(void* const* d_in, const int* in_sizes, int n_in,
                              void* d_out, int out_size, void* d_ws, size_t ws_size,
                              hipStream_t stream) {
  const float* x    = (const float*)d_in[0];
  const float* mlp  = (const float*)d_in[1];
  const float* Wenc = (const float*)d_in[2];
  const float* benc = (const float*)d_in[3];
  const float* Wdec = (const float*)d_in[4];
  const float* bdec = (const float*)d_in[5];
  const float* Wskip= (const float*)d_in[6];

  char* ws = (char*)d_ws;
  const size_t OFF_COL  = 1024;
  const size_t OFF_XBF  = 8192;
  const size_t OFF_WENC = OFF_XBF  + (size_t)8192 * 768 * 2;
  const size_t OFF_WSK  = OFF_WENC + (size_t)12288 * 768 * 2;
  const size_t OFF_SKIP = OFF_WSK  + (size_t)768 * 768 * 2;
  const size_t OFF_TIDX = OFF_SKIP + (size_t)8192 * 768 * 4;
  const size_t OFF_TVAL = OFF_TIDX + (size_t)8192 * 128 * 4;
  const size_t OFF_PRE  = OFF_TVAL + (size_t)8192 * 128 * 4;

  double*   accs   = (double*)ws;
  float*    colsum = (float*)(ws + OFF_COL);
  ushort_t* xbf    = (ushort_t*)(ws + OFF_XBF);
  ushort_t* wencbf = (ushort_t*)(ws + OFF_WENC);
  ushort_t* wskT   = (ushort_t*)(ws + OFF_WSK);
  float*    skip   = (float*)(ws + OFF_SKIP);
  int*      tidx   = (int*)(ws + OFF_TIDX);
  float*    tval   = (float*)(ws + OFF_TVAL);
  ushort_t* pre    = (ushort_t*)(ws + OFF_PRE);

  double* pL1 = (double*)(ws + OFF_XBF);
  double* pL2 = pL1 + 8192;
  double* pDS = pL1 + 16384;
  double* pS1 = pL1 + 24576;
  double* pS2 = pL1 + 32768;

  (void)hipMemsetAsync(d_ws, 0, 8192, stream);

  prep_x<<<256, 256, 0, stream>>>(x, xbf, colsum, accs);
  conv_bf16<<<(12288 * 768 / 4) / 256, 256, 0, stream>>>(Wenc, wencbf, 12288 * 768);
  conv_skipT<<<dim3(3, 768), 256, 0, stream>>>(Wskip, wskT);

  gemm256<<<1536, 512, 0, stream>>>(xbf, wencbf, pre, benc, 768, 12288, 48);
  gemm_bt<<<dim3(6, 64), 256, 0, stream>>>(xbf, wskT, skip, bdec, 768, 768);

  uint_t* wdec8 = (uint_t*)wencbf;
  conv_fp8<<<(12288 * 768 / 4 + 255) / 256, 256, 0, stream>>>(Wdec, wdec8, 12288 * 768 / 4);

  topk_kernel<<<8192, 256, 0, stream>>>(pre, tidx, tval, pS1, pS2);
  decode_loss<<<8192, 192, 0, stream>>>(tidx, tval, skip, mlp, wdec8, pL1, pL2, pDS);
  finalize_kernel<<<1, 256, 0, stream>>>(accs, colsum, pL1, pL2, pDS, pS1, pS2, (float*)d_out);
}

// Round 10
// 399.993 us; speedup vs baseline: 2.6512x; 1.0091x over previous
//
#include <hip/hip_runtime.h>

typedef unsigned short ushort_t;
typedef unsigned int uint_t;

typedef __attribute__((ext_vector_type(8))) short bf16x8;
typedef __attribute__((ext_vector_type(4))) float f32x4;
typedef __attribute__((ext_vector_type(2))) float f32x2;

#define GLOAD16(g, l) __builtin_amdgcn_global_load_lds( \
    (const __attribute__((address_space(1))) unsigned int*)(g), \
    (__attribute__((address_space(3))) unsigned int*)(l), 16, 0, 0)

#define VMCNT4 asm volatile("s_waitcnt vmcnt(4)" ::: "memory")
#define VMCNT2 asm volatile("s_waitcnt vmcnt(2)" ::: "memory")
#define VMCNT0 asm volatile("s_waitcnt vmcnt(0)" ::: "memory")
#define LGKM0  asm volatile("s_waitcnt lgkmcnt(0)" ::: "memory")
#define BARX   __builtin_amdgcn_s_barrier()

__device__ __forceinline__ ushort_t f2bf(float f) {
  union { float f; uint_t u; } c; c.f = f;
  uint_t u = c.u;
  return (ushort_t)((u + 0x7FFFu + ((u >> 16) & 1u)) >> 16);
}

// ---------------- prep: x -> bf16, colsum, sumsq ----------------
__global__ __launch_bounds__(256) void prep_x(const float* __restrict__ x,
                                              ushort_t* __restrict__ xbf,
                                              float* __restrict__ colsum,
                                              double* __restrict__ accs) {
  const int tid = threadIdx.x;
  const int r0 = blockIdx.x * 32;
  float cs0 = 0.f, cs1 = 0.f, cs2 = 0.f;
  double ss = 0.0;
  for (int r = 0; r < 32; ++r) {
    const float* xr = x + (size_t)(r0 + r) * 768;
    ushort_t* xo = xbf + (size_t)(r0 + r) * 768;
    float v0 = xr[tid], v1 = xr[tid + 256], v2 = xr[tid + 512];
    xo[tid] = f2bf(v0); xo[tid + 256] = f2bf(v1); xo[tid + 512] = f2bf(v2);
    cs0 += v0; cs1 += v1; cs2 += v2;
    ss += (double)v0 * v0 + (double)v1 * v1 + (double)v2 * v2;
  }
  atomicAdd(&colsum[tid], cs0);
  atomicAdd(&colsum[tid + 256], cs1);
  atomicAdd(&colsum[tid + 512], cs2);
  for (int o = 32; o > 0; o >>= 1) ss += __shfl_down(ss, o);
  __shared__ double wsum[4];
  if ((tid & 63) == 0) wsum[tid >> 6] = ss;
  __syncthreads();
  if (tid == 0) atomicAdd(&accs[5], wsum[0] + wsum[1] + wsum[2] + wsum[3]);
}

// ---------------- generic f32 -> bf16 convert ----------------
__global__ __launch_bounds__(256) void conv_bf16(const float* __restrict__ in,
                                                 ushort_t* __restrict__ out, int n) {
  int i = (blockIdx.x * 256 + threadIdx.x) * 4;
  if (i + 3 < n) {
    float4 v = *(const float4*)(in + i);
    uint_t a = (uint_t)f2bf(v.x) | ((uint_t)f2bf(v.y) << 16);
    uint_t b = (uint_t)f2bf(v.z) | ((uint_t)f2bf(v.w) << 16);
    *(uint2*)(out + i) = make_uint2(a, b);
  }
}

// ---------------- W_dec f32 -> fp8 e4m3 (x16 scale), 4 cols per uint ----------------
__global__ __launch_bounds__(256) void conv_fp8(const float* __restrict__ in,
                                                uint_t* __restrict__ out, int n4) {
  int i = blockIdx.x * 256 + threadIdx.x;
  if (i < n4) {
    float4 v = ((const float4*)in)[i];
    int w = 0;
    w = __builtin_amdgcn_cvt_pk_fp8_f32(v.x * 16.f, v.y * 16.f, w, false);
    w = __builtin_amdgcn_cvt_pk_fp8_f32(v.z * 16.f, v.w * 16.f, w, true);
    out[i] = (uint_t)w;
  }
}

// ---------------- W_skip transpose -> bf16 [D][K] ----------------
__global__ __launch_bounds__(256) void conv_skipT(const float* __restrict__ in,
                                                  ushort_t* __restrict__ out) {
  int d = blockIdx.x * 256 + threadIdx.x;
  int k = blockIdx.y;
  if (d < 768) out[(size_t)d * 768 + k] = f2bf(in[(size_t)k * 768 + d]);
}

// ---------------- small bf16 GEMM (skip path): m97 structure ----------------
__global__ __launch_bounds__(256) void gemm_bt(const ushort_t* __restrict__ Ag,
                                               const ushort_t* __restrict__ Bg,
                                               float* __restrict__ Cg,
                                               const float* __restrict__ bias,
                                               int K, int ldc) {
  __shared__ __align__(16) char smem[34816];
  const int tid = threadIdx.x;
  const int lane = tid & 63, wid = tid >> 6;
  const int wr = wid >> 1, wc = wid & 1;
  const int lo = lane & 15, hi = lane >> 4;
  const int arow0 = blockIdx.y * 128, brow0 = blockIdx.x * 128;
  const int rr0 = (lane >> 2);
  const int kb = (lane & 3) * 8;
  f32x4 acc[4][4] = {};
  const int NT = K >> 5;
  for (int c = 0; c < 2; ++c) {
    int rr = (wid * 2 + c) * 16 + rr0;
    GLOAD16(Ag + (size_t)(arow0 + rr) * K + kb, smem + (wid * 2 + c) * 1024);
    GLOAD16(Bg + (size_t)(brow0 + rr) * K + kb, smem + 16384 + (wid * 2 + c) * 1024);
  }
  __syncthreads();
  for (int kt = 0; kt < NT; ++kt) {
    const int cur = (kt & 1) * 8192;
    const int nxt = 8192 - cur;
    if (kt + 1 < NT) {
      const int k0 = (kt + 1) << 5;
      for (int c = 0; c < 2; ++c) {
        int rr = (wid * 2 + c) * 16 + rr0;
        GLOAD16(Ag + (size_t)(arow0 + rr) * K + k0 + kb, smem + nxt + (wid * 2 + c) * 1024);
        GLOAD16(Bg + (size_t)(brow0 + rr) * K + k0 + kb, smem + 16384 + nxt + (wid * 2 + c) * 1024);
      }
    }
    const char* As = smem + cur;
    const char* Bs = smem + 16384 + cur;
    bf16x8 af[4], bfr[4];
#pragma unroll
    for (int m = 0; m < 4; ++m)
      af[m] = *(const bf16x8*)(As + ((wr * 64 + m * 16 + lo) * 64 + hi * 16));
#pragma unroll
    for (int n = 0; n < 4; ++n)
      bfr[n] = *(const bf16x8*)(Bs + ((wc * 64 + n * 16 + lo) * 64 + hi * 16));
#pragma unroll
    for (int m = 0; m < 4; ++m)
#pragma unroll
      for (int n = 0; n < 4; ++n)
        acc[m][n] = __builtin_amdgcn_mfma_f32_16x16x32_bf16(af[m], bfr[n], acc[m][n], 0, 0, 0);
    __syncthreads();
  }
#pragma unroll
  for (int n = 0; n < 4; ++n) {
    const int col = wc * 64 + n * 16 + lo;
    const float bv = bias[brow0 + col];
#pragma unroll
    for (int m = 0; m < 4; ++m)
#pragma unroll
      for (int r = 0; r < 4; ++r) {
        const int row = wr * 64 + m * 16 + hi * 4 + r;
        Cg[(size_t)(arow0 + row) * (size_t)ldc + brow0 + col] = acc[m][n][r] + bv;
      }
  }
}

// ---------------- 256x256 phase-pipelined bf16 GEMM (enc path) ----------------
#define STAGE(G, grow0, kcol, L, S0, SS) do { \
    const int r_ = tid >> 3; \
    const int row_ = (S0) + (r_ & 31) + ((r_ >> 5) * (SS)); \
    GLOAD16((G) + (size_t)((grow0) + row_) * K + (kcol) + ((((tid & 7) ^ (r_ & 7))) << 3), \
            (L) + row_ * 128 + ((tid & 7) << 4)); \
  } while (0)

#define RD_A(MH) do { \
    _Pragma("unroll") for (int m_ = 0; m_ < 4; ++m_) { \
      const int row_ = wr * 128 + (MH) * 64 + m_ * 16 + lo; \
      _Pragma("unroll") for (int ks_ = 0; ks_ < 2; ++ks_) \
        af[m_][ks_] = *(const bf16x8*)(As + row_ * 128 + (((ks_ * 4 + hi) ^ (lo & 7)) << 4)); \
    } } while (0)

#define RD_B(NH, DST) do { \
    _Pragma("unroll") for (int n_ = 0; n_ < 2; ++n_) { \
      const int row_ = wc * 64 + (NH) * 32 + n_ * 16 + lo; \
      _Pragma("unroll") for (int ks_ = 0; ks_ < 2; ++ks_) \
        DST[n_][ks_] = *(const bf16x8*)(Bs + row_ * 128 + (((ks_ * 4 + hi) ^ (lo & 7)) << 4)); \
    } } while (0)

#define MM(MB, NB, BF) do { \
    __builtin_amdgcn_s_setprio(1); \
    _Pragma("unroll") for (int m_ = 0; m_ < 4; ++m_) \
      _Pragma("unroll") for (int n_ = 0; n_ < 2; ++n_) { \
        acc[(MB) + m_][(NB) + n_] = __builtin_amdgcn_mfma_f32_16x16x32_bf16(af[m_][0], BF[n_][0], acc[(MB) + m_][(NB) + n_], 0, 0, 0); \
        acc[(MB) + m_][(NB) + n_] = __builtin_amdgcn_mfma_f32_16x16x32_bf16(af[m_][1], BF[n_][1], acc[(MB) + m_][(NB) + n_], 0, 0, 0); \
      } \
    __builtin_amdgcn_s_setprio(0); \
  } while (0)

__global__ __launch_bounds__(512) void gemm256(const ushort_t* __restrict__ Ag,
                                               const ushort_t* __restrict__ Bg,
                                               ushort_t* __restrict__ Cg,
                                               const float* __restrict__ bias,
                                               int K, int ldc) {
  __shared__ __align__(16) char smem[69632];
  char* As = smem;
  char* Bs = smem + 32768;
  const int tid = threadIdx.x;
  const int lane = tid & 63, wid = tid >> 6;
  const int wr = wid >> 2, wc = wid & 3;
  const int lo = lane & 15, hi = lane >> 4;

  // L2-aware 2D mapping: each XCD owns an 8-row x 24-col region (192 blocks),
  // traversed as three 8x8 super-tiles so the ~64-block concurrency window
  // touches 8 A-panels + 8 B-panels (~6.3 MB) instead of all of B.
  const int xcd = blockIdx.x & 7;
  const int idx = blockIdx.x >> 3;       // 0..191
  const int rg = xcd >> 1;               // 4 row-groups of 8
  const int cg = xcd & 1;                // 2 col-groups of 24
  const int st = idx >> 6;               // 3 super-tiles of 8x8
  const int wi = idx & 63;
  const int brow0 = (rg * 8 + (wi & 7)) * 256;
  const int bcol0 = (cg * 24 + st * 8 + (wi >> 3)) * 256;

  const int NT = K >> 6;
  f32x4 acc[8][4] = {};
  bf16x8 af[4][2], b0[2][2], b1[2][2];

  STAGE(Ag, brow0, 0, As, 0, 32);   STAGE(Ag, brow0, 0, As, 128, 32);
  STAGE(Bg, bcol0, 0, Bs, 0, 64);   STAGE(Bg, bcol0, 0, Bs, 128, 64);
  STAGE(Bg, bcol0, 0, Bs, 32, 64);  STAGE(Bg, bcol0, 0, Bs, 160, 64);

  for (int kt = 0; kt < NT - 1; ++kt) {
    const int k0 = kt << 6, k1 = (kt + 1) << 6;
    STAGE(Ag, brow0, k0, As, 64, 32);  STAGE(Ag, brow0, k0, As, 192, 32);
    VMCNT4; BARX;
    RD_A(0); RD_B(0, b0);
    MM(0, 0, b0);
    BARX;
    STAGE(Ag, brow0, k1, As, 0, 32);   STAGE(Ag, brow0, k1, As, 128, 32);
    VMCNT4; BARX;
    RD_B(1, b1);
    MM(0, 2, b1);
    BARX;
    STAGE(Bg, bcol0, k1, Bs, 0, 64);   STAGE(Bg, bcol0, k1, Bs, 128, 64);
    VMCNT4; BARX;
    RD_A(1);
    MM(4, 0, b0);
    BARX;
    STAGE(Bg, bcol0, k1, Bs, 32, 64);  STAGE(Bg, bcol0, k1, Bs, 160, 64);
    MM(4, 2, b1);
  }
  {
    const int k0 = (NT - 1) << 6;
    STAGE(Ag, brow0, k0, As, 64, 32);  STAGE(Ag, brow0, k0, As, 192, 32);
    VMCNT4; BARX;
    RD_A(0); RD_B(0, b0);
    MM(0, 0, b0);
    BARX;
    VMCNT2; BARX;
    RD_B(1, b1);
    MM(0, 2, b1);
    BARX;
    VMCNT0; BARX;
    RD_A(1);
    MM(4, 0, b0);
    MM(4, 2, b1);
  }
  BARX;

  ushort_t* rep = (ushort_t*)smem;
#pragma unroll
  for (int h = 0; h < 2; ++h) {
    if (wr == h) {
#pragma unroll
      for (int n = 0; n < 4; ++n) {
        const int cl = wc * 64 + n * 16 + lo;
        const float bv = bias[bcol0 + cl];
#pragma unroll
        for (int m = 0; m < 8; ++m)
#pragma unroll
          for (int r = 0; r < 4; ++r)
            rep[(m * 16 + hi * 4 + r) * 264 + cl] = f2bf(acc[m][n][r] + bv);
      }
    }
    LGKM0; BARX;
    {
      const int rl = tid >> 2;
      const int c0 = tid & 3;
      ushort_t* dst = Cg + (size_t)(brow0 + h * 128 + rl) * (size_t)ldc + bcol0;
#pragma unroll
      for (int p = 0; p < 8; ++p)
        *(uint4*)(dst + (c0 + p * 4) * 8) = *(const uint4*)(rep + rl * 264 + (c0 + p * 4) * 8);
    }
    LGKM0; BARX;
  }
}

// ---------------- top-k: histogram threshold -> candidate sort (1 wave) ----------------
#define EIDX(c, h) ((uint_t)(((c) >> 2) * 2048 + tid * 8 + (((c) & 3) << 1) + (h)))
#define HW(b) (((b) >> 4) * 17 + ((b) & 15))
__global__ __launch_bounds__(256) void topk_kernel(const ushort_t* __restrict__ pre,
                                                   int* __restrict__ oidx,
                                                   float* __restrict__ oval,
                                                   double* __restrict__ pS1,
                                                   double* __restrict__ pS2) {
  __shared__ uint_t hist[4352];
  __shared__ uint_t cand[256];
  __shared__ uint_t wtot[4];
  __shared__ uint_t ctl[4];
  const int tid = threadIdx.x;
  const int lane = tid & 63, wid = tid >> 6;
  const size_t row = blockIdx.x;
  const uint4* pr4 = (const uint4*)(pre + row * 12288);

  for (int i = tid; i < 4352; i += 256) hist[i] = 0;
  if (tid < 4) ctl[tid] = 0;
  __syncthreads();

  uint_t k2[24];
#pragma unroll
  for (int i = 0; i < 6; ++i) {
    uint4 q = pr4[i * 256 + tid];
    uint_t qq[4] = { q.x, q.y, q.z, q.w };
#pragma unroll
    for (int w = 0; w < 4; ++w) {
      uint_t u2 = qq[w];
      uint_t m = ((u2 >> 15) & 0x00010001u) * 0x7FFFu;
      uint_t kk = u2 ^ (m | 0x80008000u);
      k2[i * 4 + w] = kk;
      atomicAdd(&hist[HW((kk & 0xFFFFu) >> 4)], 1u);
      atomicAdd(&hist[HW(kk >> 20)], 1u);
    }
  }
  __syncthreads();

  uint_t cs = 0;
#pragma unroll
  for (int b = 0; b < 16; ++b) cs += hist[tid * 17 + b];
  uint_t s = cs;
#pragma unroll
  for (int off = 1; off < 64; off <<= 1) {
    uint_t v = (uint_t)__shfl_down((int)s, off);
    if (lane + off < 64) s += v;
  }
  if (lane == 0) wtot[wid] = s;
  __syncthreads();
  uint_t above = 0;
  for (int w = wid + 1; w < 4; ++w) above += wtot[w];
  const uint_t Sg = s + above;
  const uint_t Snx = Sg - cs;
  if (Sg >= 128u && Snx < 128u) {
    uint_t running = Snx;
    for (int b = 15; b >= 0; --b) {
      uint_t c = hist[tid * 17 + b];
      if (running + c >= 128u) { ctl[0] = (uint_t)(tid * 16 + b); break; }
      running += c;
    }
  }
  __syncthreads();
  const uint_t b128 = ctl[0];

#pragma unroll
  for (int c = 0; c < 24; ++c) {
    uint_t kk = k2[c];
    uint_t key0 = kk & 0xFFFFu, key1 = kk >> 16;
    if ((key0 >> 4) >= b128) {
      uint_t p = atomicAdd(&ctl[1], 1u);
      if (p < 256u) cand[p] = ((0xFFFFu - key0) << 16) | EIDX(c, 0);
    }
    if ((key1 >> 4) >= b128) {
      uint_t p = atomicAdd(&ctl[1], 1u);
      if (p < 256u) cand[p] = ((0xFFFFu - key1) << 16) | EIDX(c, 1);
    }
  }
  __syncthreads();

  if (wid == 0) {
    const int n = (int)min(ctl[1], 256u);
    uint_t v[4];
#pragma unroll
    for (int r = 0; r < 4; ++r)
      v[r] = (r * 64 + lane < n) ? cand[r * 64 + lane] : 0xFFFFFFFFu;
#pragma unroll
    for (int k = 2; k <= 256; k <<= 1) {
#pragma unroll
      for (int j = 128; j > 0; j >>= 1) {
        if (j >= k) continue;
        if (j >= 64) {
          const int js = j >> 6;
#pragma unroll
          for (int r = 0; r < 4; ++r) {
            if ((r & js) == 0) {
              const int r2 = r | js;
              const bool up = (((r << 6) & k) == 0);
              uint_t a = v[r], b = v[r2];
              uint_t mn = min(a, b), mx = max(a, b);
              v[r] = up ? mn : mx;
              v[r2] = up ? mx : mn;
            }
          }
        } else {
#pragma unroll
          for (int r = 0; r < 4; ++r) {
            uint_t p = (uint_t)__shfl_xor((int)v[r], j);
            const bool up = ((((r << 6) | lane) & k) == 0);
            const bool lower = ((lane & j) == 0);
            v[r] = (up == lower) ? min(v[r], p) : max(v[r], p);
          }
        }
      }
    }
    int* rowIdx = oidx + row * 128;
    float* rowVal = oval + row * 128;
    float val[2];
#pragma unroll
    for (int r = 0; r < 2; ++r) {
      uint_t pk = v[r];
      uint_t idx = pk & 0xFFFFu;
      uint_t key = 0xFFFFu - (pk >> 16);
      uint_t ub = (key & 0x8000u) ? (key & 0x7FFFu) : (~key & 0xFFFFu);
      val[r] = fmaxf(__uint_as_float(ub << 16), 0.f);
      rowIdx[r * 64 + lane] = (int)idx;
      rowVal[r * 64 + lane] = val[r];
    }
    float s1 = (lane < 32) ? val[0] : 0.f;
    float s2 = val[0] + val[1];
    for (int o = 32; o > 0; o >>= 1) { s1 += __shfl_down(s1, o); s2 += __shfl_down(s2, o); }
    if (lane == 0) { pS1[row] = (double)s1; pS2[row] = (double)s2; }
  }
}

// ---------------- sparse decode + loss + means (fp8 W_dec, x16 scale) ----------------
__global__ __launch_bounds__(192) void decode_loss(const int* __restrict__ oidx,
                                                   const float* __restrict__ oval,
                                                   const float* __restrict__ skip,
                                                   const float* __restrict__ mlp,
                                                   const uint_t* __restrict__ Wd8,
                                                   double* __restrict__ pL1,
                                                   double* __restrict__ pL2,
                                                   double* __restrict__ pDS) {
  __shared__ int lidx[128];
  __shared__ float lval[128];
  __shared__ double wred[3][3];
  const int tid = threadIdx.x;
  const size_t row = blockIdx.x;
  if (tid < 128) {
    lidx[tid] = oidx[row * 128 + tid];
    lval[tid] = oval[row * 128 + tid];
  }
  __syncthreads();
  const float4 s4 = ((const float4*)(skip + row * 768))[tid];
  const float4 m4 = ((const float4*)(mlp + row * 768))[tid];
  const uint_t* Wt = Wd8 + tid;
  float a0 = 0.f, a1 = 0.f, a2 = 0.f, a3 = 0.f;
  float l1 = 0.f, dsum = 0.f;

#pragma unroll 1
  for (int g = 0; g < 16; ++g) {
    uint_t wb[8];
    float vv[8];
#pragma unroll
    for (int b = 0; b < 8; ++b) {
      wb[b] = Wt[(size_t)lidx[g * 8 + b] * 192];
      vv[b] = lval[g * 8 + b];
    }
#pragma unroll
    for (int b = 0; b < 8; ++b) {
      const float vs = vv[b] * 0.0625f;
      f32x2 lo = __builtin_amdgcn_cvt_pk_f32_fp8(wb[b], false);
      f32x2 hi = __builtin_amdgcn_cvt_pk_f32_fp8(wb[b], true);
      a0 = fmaf(vs, lo[0], a0);
      a1 = fmaf(vs, lo[1], a1);
      a2 = fmaf(vs, hi[0], a2);
      a3 = fmaf(vs, hi[1], a3);
    }
    if (g == 3) {
      float d0 = a0 + s4.x, d1 = a1 + s4.y, d2 = a2 + s4.z, d3 = a3 + s4.w;
      float e0 = m4.x - d0, e1 = m4.y - d1, e2 = m4.z - d2, e3 = m4.w - d3;
      l1 = e0 * e0 + e1 * e1 + e2 * e2 + e3 * e3;
      dsum = d0 + d1 + d2 + d3;
    }
  }
  float d0 = a0 + s4.x, d1 = a1 + s4.y, d2 = a2 + s4.z, d3 = a3 + s4.w;
  float e0 = m4.x - d0, e1 = m4.y - d1, e2 = m4.z - d2, e3 = m4.w - d3;
  float l2 = e0 * e0 + e1 * e1 + e2 * e2 + e3 * e3;
  dsum += d0 + d1 + d2 + d3;

  double r0 = (double)l1, r1 = (double)l2, r2 = (double)dsum;
  for (int o = 32; o > 0; o >>= 1) {
    r0 += __shfl_down(r0, o);
    r1 += __shfl_down(r1, o);
    r2 += __shfl_down(r2, o);
  }
  const int w = tid >> 6;
  if ((tid & 63) == 0) { wred[w][0] = r0; wred[w][1] = r1; wred[w][2] = r2; }
  __syncthreads();
  if (tid == 0) {
    pL1[row] = wred[0][0] + wred[1][0] + wred[2][0];
    pL2[row] = wred[0][1] + wred[1][1] + wred[2][1];
    pDS[row] = wred[0][2] + wred[1][2] + wred[2][2];
  }
}

// ---------------- finalize: reduce per-block partials ----------------
__global__ __launch_bounds__(256) void finalize_kernel(const double* __restrict__ accs,
                                                       const float* __restrict__ colsum,
                                                       const double* __restrict__ pL1,
                                                       const double* __restrict__ pL2,
                                                       const double* __restrict__ pDS,
                                                       const double* __restrict__ pS1,
                                                       const double* __restrict__ pS2,
                                                       float* __restrict__ out) {
  __shared__ double wred[4][6];
  const int tid = threadIdx.x;
  const int lane = tid & 63, wid = tid >> 6;
  double aL1 = 0, aL2 = 0, aDS = 0, aS1 = 0, aS2 = 0;
  for (int i = tid; i < 8192; i += 256) {
    aL1 += pL1[i]; aL2 += pL2[i]; aDS += pDS[i]; aS1 += pS1[i]; aS2 += pS2[i];
  }
  double c2 = 0.0;
  for (int i = tid; i < 768; i += 256) { double c = (double)colsum[i]; c2 += c * c; }
  for (int o = 32; o > 0; o >>= 1) {
    aL1 += __shfl_down(aL1, o);
    aL2 += __shfl_down(aL2, o);
    aDS += __shfl_down(aDS, o);
    aS1 += __shfl_down(aS1, o);
    aS2 += __shfl_down(aS2, o);
    c2  += __shfl_down(c2, o);
  }
  if (lane == 0) {
    wred[wid][0] = aL1; wred[wid][1] = aL2; wred[wid][2] = aDS;
    wred[wid][3] = aS1; wred[wid][4] = aS2; wred[wid][5] = c2;
  }
  __syncthreads();
  if (tid == 0) {
    double tL1 = 0, tL2 = 0, tDS = 0, tS1 = 0, tS2 = 0, csq = 0;
    for (int i = 0; i < 4; ++i) {
      tL1 += wred[i][0]; tL2 += wred[i][1]; tDS += wred[i][2];
      tS1 += wred[i][3]; tS2 += wred[i][4]; csq += wred[i][5];
    }
    double tv = accs[5] - csq / 8192.0;
    out[0] = (float)((tS1 + tS2) / (8192.0 * 12288.0));
    out[1] = (float)(tDS / (8192.0 * 768.0));
    out[2] = (float)(tL1 / tv + tL2 / (8.0 * tv));
  }
}

extern "C" void kernel_launch(void* const* d_in, const int* in_sizes, int n_in,
                              void* d_out, int out_size, void* d_ws, size_t ws_size,
                              hipStream_t stream) {
  const float* x    = (const float*)d_in[0];
  const float* mlp  = (const float*)d_in[1];
  const float* Wenc = (const float*)d_in[2];
  const float* benc = (const float*)d_in[3];
  const float* Wdec = (const float*)d_in[4];
  const float* bdec = (const float*)d_in[5];
  const float* Wskip= (const float*)d_in[6];

  char* ws = (char*)d_ws;
  const size_t OFF_COL  = 1024;
  const size_t OFF_XBF  = 8192;
  const size_t OFF_WENC = OFF_XBF  + (size_t)8192 * 768 * 2;
  const size_t OFF_WSK  = OFF_WENC + (size_t)12288 * 768 * 2;
  const size_t OFF_SKIP = OFF_WSK  + (size_t)768 * 768 * 2;
  const size_t OFF_TIDX = OFF_SKIP + (size_t)8192 * 768 * 4;
  const size_t OFF_TVAL = OFF_TIDX + (size_t)8192 * 128 * 4;
  const size_t OFF_PRE  = OFF_TVAL + (size_t)8192 * 128 * 4;

  double*   accs   = (double*)ws;
  float*    colsum = (float*)(ws + OFF_COL);
  ushort_t* xbf    = (ushort_t*)(ws + OFF_XBF);
  ushort_t* wencbf = (ushort_t*)(ws + OFF_WENC);
  ushort_t* wskT   = (ushort_t*)(ws + OFF_WSK);
  float*    skip   = (float*)(ws + OFF_SKIP);
  int*      tidx   = (int*)(ws + OFF_TIDX);
  float*    tval   = (float*)(ws + OFF_TVAL);
  ushort_t* pre    = (ushort_t*)(ws + OFF_PRE);

  double* pL1 = (double*)(ws + OFF_XBF);
  double* pL2 = pL1 + 8192;
  double* pDS = pL1 + 16384;
  double* pS1 = pL1 + 24576;
  double* pS2 = pL1 + 32768;

  (void)hipMemsetAsync(d_ws, 0, 8192, stream);

  prep_x<<<256, 256, 0, stream>>>(x, xbf, colsum, accs);
  conv_bf16<<<(12288 * 768 / 4) / 256, 256, 0, stream>>>(Wenc, wencbf, 12288 * 768);
  conv_skipT<<<dim3(3, 768), 256, 0, stream>>>(Wskip, wskT);

  gemm256<<<1536, 512, 0, stream>>>(xbf, wencbf, pre, benc, 768, 12288);
  gemm_bt<<<dim3(6, 64), 256, 0, stream>>>(xbf, wskT, skip, bdec, 768, 768);

  uint_t* wdec8 = (uint_t*)wencbf;
  conv_fp8<<<(12288 * 768 / 4 + 255) / 256, 256, 0, stream>>>(Wdec, wdec8, 12288 * 768 / 4);

  topk_kernel<<<8192, 256, 0, stream>>>(pre, tidx, tval, pS1, pS2);
  decode_loss<<<8192, 192, 0, stream>>>(tidx, tval, skip, mlp, wdec8, pL1, pL2, pDS);
  finalize_kernel<<<1, 256, 0, stream>>>(accs, colsum, pL1, pL2, pDS, pS1, pS2, (float*)d_out);
}